// Round 1
// baseline (2843.318 us; speedup 1.0000x reference)
//
#include <hip/hip_runtime.h>
#include <math.h>

#define LL   4096
#define HH   8
#define DK_  64
#define DV_  64
#define KD_  512
#define NEXP 4

// ---------------------------------------------------------------------------
// Generic tiled f32 GEMM: C[M,N] = A[M,K] @ B[K,N].
// 64x64 tile, BK=16, 256 threads, 4x4 per thread. M %64==0, K %16==0, N guarded.
// ---------------------------------------------------------------------------
__global__ void gemm64(const float* __restrict__ A, const float* __restrict__ B,
                       float* __restrict__ C, int M, int N, int K)
{
    __shared__ float As[16][65];
    __shared__ float Bs[16][65];
    int tid = threadIdx.x;
    int n0 = blockIdx.x * 64;
    int m0 = blockIdx.y * 64;
    int tx = tid & 15, ty = tid >> 4;
    float acc[4][4] = {};
    for (int k0 = 0; k0 < K; k0 += 16) {
        {   // A tile: 64 rows x 16 cols, one float4 per thread
            int row = tid >> 2, q4 = tid & 3;
            const float4 a = *reinterpret_cast<const float4*>(&A[(size_t)(m0 + row) * K + k0 + q4 * 4]);
            As[q4 * 4 + 0][row] = a.x;
            As[q4 * 4 + 1][row] = a.y;
            As[q4 * 4 + 2][row] = a.z;
            As[q4 * 4 + 3][row] = a.w;
        }
        {   // B tile: 16 rows x 64 cols, scalar guarded
            #pragma unroll
            for (int j = 0; j < 4; ++j) {
                int lin = tid * 4 + j;
                int kr = lin >> 6, cc = lin & 63;
                int col = n0 + cc;
                Bs[kr][cc] = (col < N) ? B[(size_t)(k0 + kr) * N + col] : 0.f;
            }
        }
        __syncthreads();
        #pragma unroll
        for (int k = 0; k < 16; ++k) {
            float av[4], bv[4];
            #pragma unroll
            for (int i = 0; i < 4; ++i) av[i] = As[k][ty * 4 + i];
            #pragma unroll
            for (int j = 0; j < 4; ++j) bv[j] = Bs[k][tx * 4 + j];
            #pragma unroll
            for (int i = 0; i < 4; ++i)
                #pragma unroll
                for (int j = 0; j < 4; ++j)
                    acc[i][j] = fmaf(av[i], bv[j], acc[i][j]);
        }
        __syncthreads();
    }
    #pragma unroll
    for (int i = 0; i < 4; ++i) {
        int m = m0 + ty * 4 + i;
        #pragma unroll
        for (int j = 0; j < 4; ++j) {
            int n = n0 + tx * 4 + j;
            if (n < N) C[(size_t)m * N + n] = acc[i][j];
        }
    }
}

// ---------------------------------------------------------------------------
// Elementwise preprocessing: scale q1/q2, softmax k2 per head, logsigmoid gates,
// expert softmax + top-1 routing weights. One block per sequence position.
// ---------------------------------------------------------------------------
__device__ inline float logsig(float x) {
    return fminf(x, 0.f) - log1pf(expf(-fabsf(x)));
}

__global__ void elementwise_pre(float* __restrict__ q1, float* __restrict__ q2,
                                float* __restrict__ k2, float* __restrict__ gk1,
                                float* __restrict__ gk2,
                                const float* __restrict__ bg1, const float* __restrict__ bg2,
                                const float* __restrict__ elog, float* __restrict__ rw)
{
    int l = blockIdx.x;
    int tid = threadIdx.x;              // 512 threads: 8 waves, wave w = head w
    int w = tid >> 6, lane = tid & 63;
    int idx = l * KD_ + (w << 6) + lane;

    q1[idx] *= 0.125f;                  // DK^-0.5
    q2[idx] *= 0.125f;

    // softmax over the 64 dims of this head (wave-wide shuffle reduce)
    float kv = k2[idx];
    float m = kv;
    for (int s = 32; s >= 1; s >>= 1) m = fmaxf(m, __shfl_xor(m, s, 64));
    float ev = expf(kv - m);
    float ssum = ev;
    for (int s = 32; s >= 1; s >>= 1) ssum += __shfl_xor(ssum, s, 64);
    k2[idx] = ev / ssum;

    int bi = (w << 6) + lane;
    gk1[idx] = logsig(gk1[idx] + bg1[bi]) * (1.f / 16.f);
    gk2[idx] = logsig(gk2[idx] + bg2[bi]) * (1.f / 16.f);

    if (tid == 0) {
        float xs[4];
        float mm = -1e30f;
        for (int j = 0; j < 4; ++j) { xs[j] = elog[l * 4 + j]; mm = fmaxf(mm, xs[j]); }
        float s4 = 0.f;
        for (int j = 0; j < 4; ++j) { xs[j] = expf(xs[j] - mm); s4 += xs[j]; }
        for (int j = 0; j < 4; ++j) xs[j] /= s4;
        int arg = 0; float best = xs[0];
        for (int j = 1; j < 4; ++j) if (xs[j] > best) { best = xs[j]; arg = j; }
        for (int j = 0; j < 4; ++j) rw[l * 4 + j] = (j == arg) ? xs[j] : 0.f;
    }
}

// ---------------------------------------------------------------------------
// GLA intra-chunk: per (chunk, head, pass). pass 0 = dense (q1,k1,gk1),
// passes 1..4 = expert e-1 (q2*rw, k2*rw, gk2*mask).
// Computes cumsum g, qg, kg, A = tril(qg kg^T), o_intra = A v -> atomicAdd.
// ---------------------------------------------------------------------------
__global__ void gla_intra(const float* __restrict__ q1, const float* __restrict__ k1,
                          const float* __restrict__ v,  const float* __restrict__ gk1,
                          const float* __restrict__ q2, const float* __restrict__ k2,
                          const float* __restrict__ gk2, const float* __restrict__ rw,
                          float* __restrict__ o_acc)
{
    int c = blockIdx.x, h = blockIdx.y, p = blockIdx.z;
    const float* qp = (p == 0) ? q1 : q2;
    const float* kp = (p == 0) ? k1 : k2;
    const float* gp = (p == 0) ? gk1 : gk2;

    __shared__ float gA[64][65];    // g (cumsum), later reused as A^T (As[s][t])
    __shared__ float qgv[64][65];   // qg, later reused as v tile
    __shared__ float kgs[64][65];
    __shared__ float glast[64];
    __shared__ float wrow[64];

    int tid = threadIdx.x;

    if (tid < 64) {
        int lg = c * 64 + tid;
        wrow[tid] = (p == 0) ? 1.f : rw[lg * 4 + (p - 1)];
    }
    __syncthreads();

    if (tid < 64) {                 // cumsum of (masked) gk along t, per dim d
        int d = tid;
        float gs = 0.f;
        for (int t = 0; t < 64; ++t) {
            float xg = gp[(size_t)(c * 64 + t) * KD_ + (h << 6) + d];
            if (p > 0 && !(wrow[t] > 0.f)) xg = 0.f;
            gs += xg;
            gA[t][d] = gs;
        }
        glast[d] = gs;
    }
    __syncthreads();

    for (int i = 0; i < 16; ++i) {  // qg = q*w*exp(g), kg = k*w*exp(-g)
        int idx = tid + (i << 8);
        int t = idx >> 6, d = idx & 63;
        int l = c * 64 + t;
        float wv = wrow[t];
        float g = gA[t][d];
        qgv[t][d] = qp[(size_t)l * KD_ + (h << 6) + d] * wv * expf(g);
        kgs[t][d] = kp[(size_t)l * KD_ + (h << 6) + d] * wv * expf(-g);
    }
    __syncthreads();

    {   // A^T[s][t] = tril dot(qg[t], kg[s]) into gA
        int t = tid >> 2;
        for (int j = 0; j < 16; ++j) {
            int s = (tid & 3) + (j << 2);
            float acc = 0.f;
            if (s <= t) {
                for (int d = 0; d < 64; ++d) acc = fmaf(qgv[t][d], kgs[s][d], acc);
            }
            gA[s][t] = acc;
        }
    }
    __syncthreads();

    for (int i = 0; i < 16; ++i) {  // v tile into qgv
        int idx = tid + (i << 8);
        int t = idx >> 6, d = idx & 63;
        qgv[t][d] = v[(size_t)(c * 64 + t) * KD_ + (h << 6) + d];
    }
    __syncthreads();

    {   // o_intra[t][e] = sum_{s<=t} A[t][s] v[s][e]
        int t = tid >> 2;
        for (int j = 0; j < 16; ++j) {
            int e = (tid & 3) + (j << 2);
            float acc = 0.f;
            for (int s = 0; s <= t; ++s) acc = fmaf(gA[s][t], qgv[s][e], acc);
            atomicAdd(&o_acc[(size_t)(c * 64 + t) * KD_ + (h << 6) + e], acc);
        }
    }
}

// ---------------------------------------------------------------------------
// GLA inter-chunk scan: per (head, pass, e-slice of 16). Sequential over 64
// chunks: o_inter = qg @ S; S = exp(glast)*(S + kg^T v).
// ---------------------------------------------------------------------------
__global__ void gla_scan(const float* __restrict__ q1, const float* __restrict__ k1,
                         const float* __restrict__ v,  const float* __restrict__ gk1,
                         const float* __restrict__ q2, const float* __restrict__ k2,
                         const float* __restrict__ gk2, const float* __restrict__ rw,
                         float* __restrict__ o_acc)
{
    int h = blockIdx.x, p = blockIdx.y, es = blockIdx.z;
    int e0 = es * 16;
    const float* qp = (p == 0) ? q1 : q2;
    const float* kp = (p == 0) ? k1 : k2;
    const float* gp = (p == 0) ? gk1 : gk2;

    __shared__ float gbuf[64][65];
    __shared__ float qg[64][65];
    __shared__ float kg[64][65];
    __shared__ float vs[64][17];
    __shared__ float S[64][17];
    __shared__ float glast[64];
    __shared__ float wrow[64];

    int tid = threadIdx.x;
    for (int i = 0; i < 4; ++i) {
        int lin = tid + (i << 8);
        S[lin >> 4][lin & 15] = 0.f;
    }

    for (int c = 0; c < 64; ++c) {
        __syncthreads();            // prev-iteration S update done
        if (tid < 64) {
            int lg = c * 64 + tid;
            wrow[tid] = (p == 0) ? 1.f : rw[lg * 4 + (p - 1)];
        }
        __syncthreads();
        if (tid < 64) {
            int d = tid;
            float gs = 0.f;
            for (int t = 0; t < 64; ++t) {
                float xg = gp[(size_t)(c * 64 + t) * KD_ + (h << 6) + d];
                if (p > 0 && !(wrow[t] > 0.f)) xg = 0.f;
                gs += xg;
                gbuf[t][d] = gs;
            }
            glast[d] = gs;
        }
        __syncthreads();
        for (int i = 0; i < 16; ++i) {
            int idx = tid + (i << 8);
            int t = idx >> 6, d = idx & 63;
            int l = c * 64 + t;
            float wv = wrow[t];
            float g = gbuf[t][d];
            qg[t][d] = qp[(size_t)l * KD_ + (h << 6) + d] * wv * expf(g);
            kg[t][d] = kp[(size_t)l * KD_ + (h << 6) + d] * wv * expf(-g);
        }
        for (int i = 0; i < 4; ++i) {
            int lin = tid + (i << 8);
            int t = lin >> 4, e = lin & 15;
            vs[t][e] = v[(size_t)(c * 64 + t) * KD_ + (h << 6) + e0 + e];
        }
        __syncthreads();
        for (int i = 0; i < 4; ++i) {   // o_inter = qg @ S (S before update)
            int lin = tid + (i << 8);
            int t = lin >> 4, e = lin & 15;
            float acc = 0.f;
            for (int d = 0; d < 64; ++d) acc = fmaf(qg[t][d], S[d][e], acc);
            atomicAdd(&o_acc[(size_t)(c * 64 + t) * KD_ + (h << 6) + e0 + e], acc);
        }
        __syncthreads();
        for (int i = 0; i < 4; ++i) {   // S = exp(glast) * (S + kg^T v)
            int lin = tid + (i << 8);
            int d = lin >> 4, e = lin & 15;
            float acc = 0.f;
            for (int t = 0; t < 64; ++t) acc = fmaf(kg[t][d], vs[t][e], acc);
            S[d][e] = expf(glast[d]) * (S[d][e] + acc);
        }
    }
}

// ---------------------------------------------------------------------------
// Post: RMS-norm over DV per (l,h), * norm_w, * silu(g). 512 thr = 8 waves.
// ---------------------------------------------------------------------------
__global__ void postnorm(const float* __restrict__ o_acc, const float* __restrict__ gbuf,
                         const float* __restrict__ norm_w, float* __restrict__ og)
{
    int l = blockIdx.x;
    int tid = threadIdx.x;
    int w = tid >> 6, lane = tid & 63;
    int idx = l * KD_ + (w << 6) + lane;
    float o = o_acc[idx];
    float ss = o * o;
    for (int s = 32; s >= 1; s >>= 1) ss += __shfl_xor(ss, s, 64);
    float r = rsqrtf(ss * (1.f / 64.f) + 1e-5f);
    float val = o * r * norm_w[lane];
    float gv = gbuf[idx];
    val *= gv / (1.f + expf(-gv));
    og[idx] = val;
}

// ---------------------------------------------------------------------------
extern "C" void kernel_launch(void* const* d_in, const int* in_sizes, int n_in,
                              void* d_out, int out_size, void* d_ws, size_t ws_size,
                              hipStream_t stream)
{
    const float* x    = (const float*)d_in[0];
    const float* Wq   = (const float*)d_in[1];
    const float* Wk   = (const float*)d_in[2];
    const float* Wv   = (const float*)d_in[3];
    const float* Wqa  = (const float*)d_in[4];
    const float* Wqb  = (const float*)d_in[5];
    const float* Wka  = (const float*)d_in[6];
    const float* Wkb  = (const float*)d_in[7];
    const float* Wg1a = (const float*)d_in[8];
    const float* Wg1b = (const float*)d_in[9];
    const float* bg1  = (const float*)d_in[10];
    const float* Wg2a = (const float*)d_in[11];
    const float* Wg2b = (const float*)d_in[12];
    const float* bg2  = (const float*)d_in[13];
    const float* We   = (const float*)d_in[14];
    const float* Wga  = (const float*)d_in[15];
    const float* Wgb  = (const float*)d_in[16];
    const float* normw= (const float*)d_in[17];
    const float* Wo   = (const float*)d_in[18];

    float* ws = (float*)d_ws;
    const size_t LKD = (size_t)LL * KD_;   // 2M floats
    float* q1   = ws;
    float* k1   = q1 + LKD;
    float* v    = k1 + LKD;
    float* q2   = v  + LKD;
    float* k2   = q2 + LKD;
    float* gk1  = k2 + LKD;
    float* gk2  = gk1 + LKD;
    float* o_acc= gk2 + LKD;
    float* tqa  = o_acc + LKD;             // 4096*64
    float* tka  = tqa + (size_t)LL * 64;
    float* tg1  = tka + (size_t)LL * 64;   // 4096*16
    float* tg2  = tg1 + (size_t)LL * 16;
    float* elog = tg2 + (size_t)LL * 16;   // 4096*4
    float* rw   = elog + (size_t)LL * 4;
    float* gbuf = k1;                      // reuse after GLA
    float* tga  = tqa;                     // reuse after q2 GEMM
    float* og   = q1;                      // reuse after GLA

    dim3 blk(256);
    auto G = [](int M, int N) { return dim3((unsigned)((N + 63) / 64), (unsigned)(M / 64)); };

    hipMemsetAsync(o_acc, 0, LKD * sizeof(float), stream);

    gemm64<<<G(LL, KD_), blk, 0, stream>>>(x, Wq, q1, LL, KD_, 1024);
    gemm64<<<G(LL, KD_), blk, 0, stream>>>(x, Wk, k1, LL, KD_, 1024);
    gemm64<<<G(LL, KD_), blk, 0, stream>>>(x, Wv, v,  LL, KD_, 1024);
    gemm64<<<G(LL, 64),  blk, 0, stream>>>(x, Wqa, tqa, LL, 64, 1024);
    gemm64<<<G(LL, KD_), blk, 0, stream>>>(tqa, Wqb, q2, LL, KD_, 64);
    gemm64<<<G(LL, 64),  blk, 0, stream>>>(x, Wka, tka, LL, 64, 1024);
    gemm64<<<G(LL, KD_), blk, 0, stream>>>(tka, Wkb, k2, LL, KD_, 64);
    gemm64<<<G(LL, 16),  blk, 0, stream>>>(x, Wg1a, tg1, LL, 16, 1024);
    gemm64<<<G(LL, KD_), blk, 0, stream>>>(tg1, Wg1b, gk1, LL, KD_, 16);
    gemm64<<<G(LL, 16),  blk, 0, stream>>>(x, Wg2a, tg2, LL, 16, 1024);
    gemm64<<<G(LL, KD_), blk, 0, stream>>>(tg2, Wg2b, gk2, LL, KD_, 16);
    gemm64<<<G(LL, 4),   blk, 0, stream>>>(x, We, elog, LL, 4, 1024);

    elementwise_pre<<<LL, 512, 0, stream>>>(q1, q2, k2, gk1, gk2, bg1, bg2, elog, rw);

    gla_intra<<<dim3(64, 8, 5), 256, 0, stream>>>(q1, k1, v, gk1, q2, k2, gk2, rw, o_acc);
    gla_scan<<<dim3(8, 5, 4),  256, 0, stream>>>(q1, k1, v, gk1, q2, k2, gk2, rw, o_acc);

    // gating projection (reuses tqa for tga, k1 for gbuf — both free after GLA)
    gemm64<<<G(LL, 64),  blk, 0, stream>>>(x, Wga, tga, LL, 64, 1024);
    gemm64<<<G(LL, KD_), blk, 0, stream>>>(tga, Wgb, gbuf, LL, KD_, 64);

    postnorm<<<LL, 512, 0, stream>>>(o_acc, gbuf, normw, og);

    gemm64<<<G(LL, 1024), blk, 0, stream>>>(og, Wo, (float*)d_out, LL, 1024, KD_);
}

// Round 2
// 1612.201 us; speedup vs baseline: 1.7636x; 1.7636x over previous
//
#include <hip/hip_runtime.h>
#include <math.h>

#define LL   4096
#define HH   8
#define DK_  64
#define DV_  64
#define KD_  512
#define NEXP 4

// ---------------------------------------------------------------------------
// Generic tiled f32 GEMM: C[M,N] = A[M,K] @ B[K,N].
// 64x64 tile, BK=16, 256 threads, 4x4 per thread. M %64==0, K %16==0, N guarded.
// ---------------------------------------------------------------------------
__global__ void gemm64(const float* __restrict__ A, const float* __restrict__ B,
                       float* __restrict__ C, int M, int N, int K)
{
    __shared__ float As[16][65];
    __shared__ float Bs[16][65];
    int tid = threadIdx.x;
    int n0 = blockIdx.x * 64;
    int m0 = blockIdx.y * 64;
    int tx = tid & 15, ty = tid >> 4;
    float acc[4][4] = {};
    for (int k0 = 0; k0 < K; k0 += 16) {
        {   // A tile: 64 rows x 16 cols, one float4 per thread
            int row = tid >> 2, q4 = tid & 3;
            const float4 a = *reinterpret_cast<const float4*>(&A[(size_t)(m0 + row) * K + k0 + q4 * 4]);
            As[q4 * 4 + 0][row] = a.x;
            As[q4 * 4 + 1][row] = a.y;
            As[q4 * 4 + 2][row] = a.z;
            As[q4 * 4 + 3][row] = a.w;
        }
        {   // B tile: 16 rows x 64 cols, scalar guarded
            #pragma unroll
            for (int j = 0; j < 4; ++j) {
                int lin = tid * 4 + j;
                int kr = lin >> 6, cc = lin & 63;
                int col = n0 + cc;
                Bs[kr][cc] = (col < N) ? B[(size_t)(k0 + kr) * N + col] : 0.f;
            }
        }
        __syncthreads();
        #pragma unroll
        for (int k = 0; k < 16; ++k) {
            float av[4], bv[4];
            #pragma unroll
            for (int i = 0; i < 4; ++i) av[i] = As[k][ty * 4 + i];
            #pragma unroll
            for (int j = 0; j < 4; ++j) bv[j] = Bs[k][tx * 4 + j];
            #pragma unroll
            for (int i = 0; i < 4; ++i)
                #pragma unroll
                for (int j = 0; j < 4; ++j)
                    acc[i][j] = fmaf(av[i], bv[j], acc[i][j]);
        }
        __syncthreads();
    }
    #pragma unroll
    for (int i = 0; i < 4; ++i) {
        int m = m0 + ty * 4 + i;
        #pragma unroll
        for (int j = 0; j < 4; ++j) {
            int n = n0 + tx * 4 + j;
            if (n < N) C[(size_t)m * N + n] = acc[i][j];
        }
    }
}

// ---------------------------------------------------------------------------
__device__ inline float logsig(float x) {
    return fminf(x, 0.f) - log1pf(expf(-fabsf(x)));
}

__global__ void elementwise_pre(float* __restrict__ q1, float* __restrict__ q2,
                                float* __restrict__ k2, float* __restrict__ gk1,
                                float* __restrict__ gk2,
                                const float* __restrict__ bg1, const float* __restrict__ bg2,
                                const float* __restrict__ elog, float* __restrict__ rw)
{
    int l = blockIdx.x;
    int tid = threadIdx.x;              // 512 threads: 8 waves, wave w = head w
    int w = tid >> 6, lane = tid & 63;
    int idx = l * KD_ + (w << 6) + lane;

    q1[idx] *= 0.125f;                  // DK^-0.5
    q2[idx] *= 0.125f;

    // softmax over the 64 dims of this head (wave-wide shuffle reduce)
    float kv = k2[idx];
    float m = kv;
    for (int s = 32; s >= 1; s >>= 1) m = fmaxf(m, __shfl_xor(m, s, 64));
    float ev = expf(kv - m);
    float ssum = ev;
    for (int s = 32; s >= 1; s >>= 1) ssum += __shfl_xor(ssum, s, 64);
    k2[idx] = ev / ssum;

    int bi = (w << 6) + lane;
    gk1[idx] = logsig(gk1[idx] + bg1[bi]) * (1.f / 16.f);
    gk2[idx] = logsig(gk2[idx] + bg2[bi]) * (1.f / 16.f);

    if (tid == 0) {
        float xs[4];
        float mm = -1e30f;
        for (int j = 0; j < 4; ++j) { xs[j] = elog[l * 4 + j]; mm = fmaxf(mm, xs[j]); }
        float s4 = 0.f;
        for (int j = 0; j < 4; ++j) { xs[j] = expf(xs[j] - mm); s4 += xs[j]; }
        for (int j = 0; j < 4; ++j) xs[j] /= s4;
        int arg = 0; float best = xs[0];
        for (int j = 1; j < 4; ++j) if (xs[j] > best) { best = xs[j]; arg = j; }
        for (int j = 0; j < 4; ++j) rw[l * 4 + j] = (j == arg) ? xs[j] : 0.f;
    }
}

// ---------------------------------------------------------------------------
// GLA intra-chunk + per-chunk state contribution. Block = (chunk, head, pass).
// pass 0 = dense (q1,k1,gk1); passes 1..4 = expert e-1 (q2*rw, k2*rw, gk2*mask).
// Outputs: o_intra -> atomicAdd(o_acc); chunk_kv = exp(glast)*(kg^T v) and
// decay = exp(glast) for the inter-chunk scan.
// ---------------------------------------------------------------------------
__global__ void gla_intra(const float* __restrict__ q1, const float* __restrict__ k1,
                          const float* __restrict__ v,  const float* __restrict__ gk1,
                          const float* __restrict__ q2, const float* __restrict__ k2,
                          const float* __restrict__ gk2, const float* __restrict__ rw,
                          float* __restrict__ o_acc, float* __restrict__ kv_all,
                          float* __restrict__ decay_all)
{
    int c = blockIdx.x, h = blockIdx.y, p = blockIdx.z;
    const float* qp = (p == 0) ? q1 : q2;
    const float* kp = (p == 0) ? k1 : k2;
    const float* gp = (p == 0) ? gk1 : gk2;

    __shared__ float gA[64][65];    // gk tile -> cumsum g -> later A^T
    __shared__ float qgv[64][65];   // qg, later reused as v tile
    __shared__ float kgs[64][65];
    __shared__ float glast[64];
    __shared__ float wrow[64];

    int tid = threadIdx.x;

    if (tid < 64) {
        int lg = c * 64 + tid;
        wrow[tid] = (p == 0) ? 1.f : rw[lg * 4 + (p - 1)];
    }
    __syncthreads();

    for (int i = 0; i < 16; ++i) {  // coalesced gk tile load (masked)
        int idx = tid + (i << 8);
        int t = idx >> 6, d = idx & 63;
        float xg = gp[(size_t)(c * 64 + t) * KD_ + (h << 6) + d];
        if (p > 0 && !(wrow[t] > 0.f)) xg = 0.f;
        gA[t][d] = xg;
    }
    __syncthreads();

    if (tid < 64) {                 // cumsum along t, per dim d (LDS only)
        int d = tid;
        float gs = 0.f;
        for (int t = 0; t < 64; ++t) { gs += gA[t][d]; gA[t][d] = gs; }
        glast[d] = gs;
    }
    __syncthreads();

    for (int i = 0; i < 16; ++i) {  // qg = q*w*exp(g), kg = k*w*exp(-g)
        int idx = tid + (i << 8);
        int t = idx >> 6, d = idx & 63;
        int l = c * 64 + t;
        float wv = wrow[t];
        float g = gA[t][d];
        qgv[t][d] = qp[(size_t)l * KD_ + (h << 6) + d] * wv * expf(g);
        kgs[t][d] = kp[(size_t)l * KD_ + (h << 6) + d] * wv * expf(-g);
    }
    __syncthreads();

    {   // A^T[s][t] = tril dot(qg[t], kg[s]) into gA
        int t = tid >> 2;
        for (int j = 0; j < 16; ++j) {
            int s = (tid & 3) + (j << 2);
            float acc = 0.f;
            if (s <= t) {
                for (int d = 0; d < 64; ++d) acc = fmaf(qgv[t][d], kgs[s][d], acc);
            }
            gA[s][t] = acc;
        }
    }
    __syncthreads();

    for (int i = 0; i < 16; ++i) {  // v tile into qgv (qg no longer needed)
        int idx = tid + (i << 8);
        int t = idx >> 6, d = idx & 63;
        qgv[t][d] = v[(size_t)(c * 64 + t) * KD_ + (h << 6) + d];
    }
    __syncthreads();

    {   // o_intra[t][e] = sum_{s<=t} A[t][s] v[s][e]
        int t = tid >> 2;
        for (int j = 0; j < 16; ++j) {
            int e = (tid & 3) + (j << 2);
            float acc = 0.f;
            for (int s = 0; s <= t; ++s) acc = fmaf(gA[s][t], qgv[s][e], acc);
            atomicAdd(&o_acc[(size_t)(c * 64 + t) * KD_ + (h << 6) + e], acc);
        }
    }

    {   // chunk_kv[d][e] = exp(glast[d]) * sum_t kg[t][d] v[t][e]; decay = exp(glast)
        size_t base = (size_t)((c * 8 + h) * 5 + p) * 4096;
        int d = tid >> 2;
        float dec = expf(glast[d]);
        for (int j = 0; j < 16; ++j) {
            int e = (tid & 3) + (j << 2);
            float acc = 0.f;
            for (int t = 0; t < 64; ++t) acc = fmaf(kgs[t][d], qgv[t][e], acc);
            kv_all[base + d * 64 + e] = acc * dec;
        }
        if (tid < 64) decay_all[(size_t)((c * 8 + h) * 5 + p) * 64 + tid] = expf(glast[tid]);
    }
}

// ---------------------------------------------------------------------------
// Inter-chunk state scan, elementwise in (h,p,d,e): 64-step scalar recurrence
// in registers, IN PLACE over kv_all: read kv_c, write S_entering_c, update.
// ---------------------------------------------------------------------------
__global__ void gla_state_scan(float* __restrict__ kv, const float* __restrict__ decay)
{
    int gid = blockIdx.x * 256 + threadIdx.x;   // [0, 163840) = (h,p,d,e)
    int sub = gid >> 6;                         // (h,p,d) in [0,2560)
    const size_t stride = 8 * 5 * 64 * 64;      // per-chunk stride = 163840
    float S = 0.f;
    float kvv = kv[gid];                        // chunk 0
    for (int c = 0; c < 64; ++c) {
        size_t o = (size_t)c * stride + gid;
        float nxt = (c < 63) ? kv[o + stride] : 0.f;
        float dec = decay[c * 2560 + sub];
        kv[o] = S;                              // S entering chunk c
        S = fmaf(dec, S, kvv);
        kvv = nxt;
    }
}

// ---------------------------------------------------------------------------
// Inter-chunk output: o_inter[c] = qg_c @ S_entering_c. Block = (c,h,p).
// Recomputes qg from q/gk/rw (cheap; avoids a 40MB qg buffer).
// ---------------------------------------------------------------------------
__global__ void gla_inter(const float* __restrict__ q1, const float* __restrict__ q2,
                          const float* __restrict__ gk1, const float* __restrict__ gk2,
                          const float* __restrict__ rw, const float* __restrict__ Spre,
                          float* __restrict__ o_acc)
{
    int c = blockIdx.x, h = blockIdx.y, p = blockIdx.z;
    const float* qp = (p == 0) ? q1 : q2;
    const float* gp = (p == 0) ? gk1 : gk2;

    __shared__ float qg[64][65];    // gk tile -> cumsum -> qg (in place)
    __shared__ float Ss[64][65];
    __shared__ float wrow[64];

    int tid = threadIdx.x;
    if (tid < 64) {
        int lg = c * 64 + tid;
        wrow[tid] = (p == 0) ? 1.f : rw[lg * 4 + (p - 1)];
    }
    __syncthreads();

    for (int i = 0; i < 16; ++i) {
        int idx = tid + (i << 8);
        int t = idx >> 6, d = idx & 63;
        float xg = gp[(size_t)(c * 64 + t) * KD_ + (h << 6) + d];
        if (p > 0 && !(wrow[t] > 0.f)) xg = 0.f;
        qg[t][d] = xg;
    }
    size_t sbase = (size_t)((c * 8 + h) * 5 + p) * 4096;
    for (int i = 0; i < 16; ++i) {
        int idx = tid + (i << 8);
        Ss[idx >> 6][idx & 63] = Spre[sbase + idx];
    }
    __syncthreads();

    if (tid < 64) {                 // cumsum in place
        int d = tid;
        float gs = 0.f;
        for (int t = 0; t < 64; ++t) { gs += qg[t][d]; qg[t][d] = gs; }
    }
    __syncthreads();

    for (int i = 0; i < 16; ++i) {  // qg = q*w*exp(g) in place
        int idx = tid + (i << 8);
        int t = idx >> 6, d = idx & 63;
        int l = c * 64 + t;
        qg[t][d] = qp[(size_t)l * KD_ + (h << 6) + d] * wrow[t] * expf(qg[t][d]);
    }
    __syncthreads();

    {   // o_inter[t][e] = sum_d qg[t][d] * S[d][e]
        int t = tid >> 2;
        for (int j = 0; j < 16; ++j) {
            int e = (tid & 3) + (j << 2);
            float acc = 0.f;
            for (int d = 0; d < 64; ++d) acc = fmaf(qg[t][d], Ss[d][e], acc);
            atomicAdd(&o_acc[(size_t)(c * 64 + t) * KD_ + (h << 6) + e], acc);
        }
    }
}

// ---------------------------------------------------------------------------
// Post: RMS-norm over DV per (l,h), * norm_w, * silu(g). 512 thr = 8 waves.
// ---------------------------------------------------------------------------
__global__ void postnorm(const float* __restrict__ o_acc, const float* __restrict__ gbuf,
                         const float* __restrict__ norm_w, float* __restrict__ og)
{
    int l = blockIdx.x;
    int tid = threadIdx.x;
    int w = tid >> 6, lane = tid & 63;
    int idx = l * KD_ + (w << 6) + lane;
    float o = o_acc[idx];
    float ss = o * o;
    for (int s = 32; s >= 1; s >>= 1) ss += __shfl_xor(ss, s, 64);
    float r = rsqrtf(ss * (1.f / 64.f) + 1e-5f);
    float val = o * r * norm_w[lane];
    float gv = gbuf[idx];
    val *= gv / (1.f + expf(-gv));
    og[idx] = val;
}

// ---------------------------------------------------------------------------
extern "C" void kernel_launch(void* const* d_in, const int* in_sizes, int n_in,
                              void* d_out, int out_size, void* d_ws, size_t ws_size,
                              hipStream_t stream)
{
    const float* x    = (const float*)d_in[0];
    const float* Wq   = (const float*)d_in[1];
    const float* Wk   = (const float*)d_in[2];
    const float* Wv   = (const float*)d_in[3];
    const float* Wqa  = (const float*)d_in[4];
    const float* Wqb  = (const float*)d_in[5];
    const float* Wka  = (const float*)d_in[6];
    const float* Wkb  = (const float*)d_in[7];
    const float* Wg1a = (const float*)d_in[8];
    const float* Wg1b = (const float*)d_in[9];
    const float* bg1  = (const float*)d_in[10];
    const float* Wg2a = (const float*)d_in[11];
    const float* Wg2b = (const float*)d_in[12];
    const float* bg2  = (const float*)d_in[13];
    const float* We   = (const float*)d_in[14];
    const float* Wga  = (const float*)d_in[15];
    const float* Wgb  = (const float*)d_in[16];
    const float* normw= (const float*)d_in[17];
    const float* Wo   = (const float*)d_in[18];

    float* ws = (float*)d_ws;
    const size_t LKD = (size_t)LL * KD_;   // 2M floats
    float* q1   = ws;
    float* k1   = q1 + LKD;
    float* v    = k1 + LKD;
    float* q2   = v  + LKD;
    float* k2   = q2 + LKD;
    float* gk1  = k2 + LKD;
    float* gk2  = gk1 + LKD;
    float* o_acc= gk2 + LKD;
    float* tqa  = o_acc + LKD;             // 4096*64
    float* tka  = tqa + (size_t)LL * 64;
    float* tg1  = tka + (size_t)LL * 64;   // 4096*16
    float* tg2  = tg1 + (size_t)LL * 16;
    float* elog = tg2 + (size_t)LL * 16;   // 4096*4
    float* rw   = elog + (size_t)LL * 4;
    float* kv_all    = rw + (size_t)LL * 4;        // 64*8*5*64*64 = 10.5M floats
    float* decay_all = kv_all + (size_t)64 * 8 * 5 * 64 * 64;  // 163840 floats
    float* gbuf = k1;                      // reuse after GLA
    float* tga  = tqa;                     // reuse after q2 GEMM
    float* og   = q1;                      // reuse after GLA

    dim3 blk(256);
    auto G = [](int M, int N) { return dim3((unsigned)((N + 63) / 64), (unsigned)(M / 64)); };

    hipMemsetAsync(o_acc, 0, LKD * sizeof(float), stream);

    gemm64<<<G(LL, KD_), blk, 0, stream>>>(x, Wq, q1, LL, KD_, 1024);
    gemm64<<<G(LL, KD_), blk, 0, stream>>>(x, Wk, k1, LL, KD_, 1024);
    gemm64<<<G(LL, KD_), blk, 0, stream>>>(x, Wv, v,  LL, KD_, 1024);
    gemm64<<<G(LL, 64),  blk, 0, stream>>>(x, Wqa, tqa, LL, 64, 1024);
    gemm64<<<G(LL, KD_), blk, 0, stream>>>(tqa, Wqb, q2, LL, KD_, 64);
    gemm64<<<G(LL, 64),  blk, 0, stream>>>(x, Wka, tka, LL, 64, 1024);
    gemm64<<<G(LL, KD_), blk, 0, stream>>>(tka, Wkb, k2, LL, KD_, 64);
    gemm64<<<G(LL, 16),  blk, 0, stream>>>(x, Wg1a, tg1, LL, 16, 1024);
    gemm64<<<G(LL, KD_), blk, 0, stream>>>(tg1, Wg1b, gk1, LL, KD_, 16);
    gemm64<<<G(LL, 16),  blk, 0, stream>>>(x, Wg2a, tg2, LL, 16, 1024);
    gemm64<<<G(LL, KD_), blk, 0, stream>>>(tg2, Wg2b, gk2, LL, KD_, 16);
    gemm64<<<G(LL, 4),   blk, 0, stream>>>(x, We, elog, LL, 4, 1024);

    elementwise_pre<<<LL, 512, 0, stream>>>(q1, q2, k2, gk1, gk2, bg1, bg2, elog, rw);

    gla_intra<<<dim3(64, 8, 5), 256, 0, stream>>>(q1, k1, v, gk1, q2, k2, gk2, rw,
                                                  o_acc, kv_all, decay_all);
    gla_state_scan<<<dim3(640), 256, 0, stream>>>(kv_all, decay_all);
    gla_inter<<<dim3(64, 8, 5), 256, 0, stream>>>(q1, q2, gk1, gk2, rw, kv_all, o_acc);

    // gating projection (reuses tqa for tga, k1 for gbuf — both free after GLA)
    gemm64<<<G(LL, 64),  blk, 0, stream>>>(x, Wga, tga, LL, 64, 1024);
    gemm64<<<G(LL, KD_), blk, 0, stream>>>(tga, Wgb, gbuf, LL, KD_, 64);

    postnorm<<<LL, 512, 0, stream>>>(o_acc, gbuf, normw, og);

    gemm64<<<G(LL, 1024), blk, 0, stream>>>(og, Wo, (float*)d_out, LL, 1024, KD_);
}

// Round 3
// 1274.023 us; speedup vs baseline: 2.2318x; 1.2654x over previous
//
#include <hip/hip_runtime.h>
#include <math.h>

#define LL   4096
#define HH   8
#define DK_  64
#define DV_  64
#define KD_  512
#define NEXP 4

__device__ __forceinline__ float f4c(const float4& v, int i) {
    return i == 0 ? v.x : i == 1 ? v.y : i == 2 ? v.z : v.w;
}

// ---------------------------------------------------------------------------
// 128x128 tiled f32 GEMM, 256 threads, 8x8 per thread (split 4+4 to avoid
// bank conflicts). Up to 3 B/C pairs selected by blockIdx.z (QKV fusion).
// M%128==0, N%128==0, K%16==0.
// ---------------------------------------------------------------------------
__global__ void gemm128b(const float* __restrict__ A,
                         const float* __restrict__ B0, const float* __restrict__ B1,
                         const float* __restrict__ B2,
                         float* __restrict__ C0, float* __restrict__ C1, float* __restrict__ C2,
                         int M, int N, int K)
{
    const float* B = (blockIdx.z == 0) ? B0 : (blockIdx.z == 1) ? B1 : B2;
    float*       C = (blockIdx.z == 0) ? C0 : (blockIdx.z == 1) ? C1 : C2;

    __shared__ float As[16][132];   // row stride 528B = 33*16 -> float4-aligned
    __shared__ float Bs[16][132];
    int tid = threadIdx.x;
    int n0 = blockIdx.x * 128;
    int m0 = blockIdx.y * 128;
    int tx = tid & 15, ty = tid >> 4;
    float acc[8][8] = {};

    for (int k0 = 0; k0 < K; k0 += 16) {
        #pragma unroll
        for (int u = 0; u < 2; ++u) {           // A tile: 128 x 16, transposed store
            int lin = tid + (u << 8);
            int row = lin >> 2, q4 = lin & 3;
            float4 a = *reinterpret_cast<const float4*>(&A[(size_t)(m0 + row) * K + k0 + q4 * 4]);
            As[q4 * 4 + 0][row] = a.x;
            As[q4 * 4 + 1][row] = a.y;
            As[q4 * 4 + 2][row] = a.z;
            As[q4 * 4 + 3][row] = a.w;
        }
        #pragma unroll
        for (int u = 0; u < 2; ++u) {           // B tile: 16 x 128
            int lin = tid + (u << 8);
            int kr = lin >> 5, c4 = lin & 31;
            *reinterpret_cast<float4*>(&Bs[kr][c4 * 4]) =
                *reinterpret_cast<const float4*>(&B[(size_t)(k0 + kr) * N + n0 + c4 * 4]);
        }
        __syncthreads();
        #pragma unroll
        for (int k = 0; k < 16; ++k) {
            float4 a0 = *(const float4*)&As[k][ty * 4];
            float4 a1 = *(const float4*)&As[k][64 + ty * 4];
            float4 b0 = *(const float4*)&Bs[k][tx * 4];
            float4 b1 = *(const float4*)&Bs[k][64 + tx * 4];
            float av[8] = {a0.x, a0.y, a0.z, a0.w, a1.x, a1.y, a1.z, a1.w};
            float bv[8] = {b0.x, b0.y, b0.z, b0.w, b1.x, b1.y, b1.z, b1.w};
            #pragma unroll
            for (int i = 0; i < 8; ++i)
                #pragma unroll
                for (int j = 0; j < 8; ++j)
                    acc[i][j] = fmaf(av[i], bv[j], acc[i][j]);
        }
        __syncthreads();
    }
    #pragma unroll
    for (int i = 0; i < 8; ++i) {
        int m = m0 + ((i < 4) ? ty * 4 + i : 64 + ty * 4 + (i - 4));
        float4 c0 = make_float4(acc[i][0], acc[i][1], acc[i][2], acc[i][3]);
        float4 c1 = make_float4(acc[i][4], acc[i][5], acc[i][6], acc[i][7]);
        *reinterpret_cast<float4*>(&C[(size_t)m * N + n0 + tx * 4]) = c0;
        *reinterpret_cast<float4*>(&C[(size_t)m * N + n0 + 64 + tx * 4]) = c1;
    }
}

// ---------------------------------------------------------------------------
// Generic tiled f32 GEMM for small N: 64x64 tile, BK=16, 256 threads.
// ---------------------------------------------------------------------------
__global__ void gemm64(const float* __restrict__ A, const float* __restrict__ B,
                       float* __restrict__ C, int M, int N, int K)
{
    __shared__ float As[16][65];
    __shared__ float Bs[16][65];
    int tid = threadIdx.x;
    int n0 = blockIdx.x * 64;
    int m0 = blockIdx.y * 64;
    int tx = tid & 15, ty = tid >> 4;
    float acc[4][4] = {};
    for (int k0 = 0; k0 < K; k0 += 16) {
        {
            int row = tid >> 2, q4 = tid & 3;
            const float4 a = *reinterpret_cast<const float4*>(&A[(size_t)(m0 + row) * K + k0 + q4 * 4]);
            As[q4 * 4 + 0][row] = a.x;
            As[q4 * 4 + 1][row] = a.y;
            As[q4 * 4 + 2][row] = a.z;
            As[q4 * 4 + 3][row] = a.w;
        }
        {
            #pragma unroll
            for (int j = 0; j < 4; ++j) {
                int lin = tid * 4 + j;
                int kr = lin >> 6, cc = lin & 63;
                int col = n0 + cc;
                Bs[kr][cc] = (col < N) ? B[(size_t)(k0 + kr) * N + col] : 0.f;
            }
        }
        __syncthreads();
        #pragma unroll
        for (int k = 0; k < 16; ++k) {
            float av[4], bv[4];
            #pragma unroll
            for (int i = 0; i < 4; ++i) av[i] = As[k][ty * 4 + i];
            #pragma unroll
            for (int j = 0; j < 4; ++j) bv[j] = Bs[k][tx * 4 + j];
            #pragma unroll
            for (int i = 0; i < 4; ++i)
                #pragma unroll
                for (int j = 0; j < 4; ++j)
                    acc[i][j] = fmaf(av[i], bv[j], acc[i][j]);
        }
        __syncthreads();
    }
    #pragma unroll
    for (int i = 0; i < 4; ++i) {
        int m = m0 + ty * 4 + i;
        #pragma unroll
        for (int j = 0; j < 4; ++j) {
            int n = n0 + tx * 4 + j;
            if (n < N) C[(size_t)m * N + n] = acc[i][j];
        }
    }
}

// ---------------------------------------------------------------------------
__device__ inline float logsig(float x) {
    return fminf(x, 0.f) - log1pf(expf(-fabsf(x)));
}

__global__ void elementwise_pre(float* __restrict__ q1, float* __restrict__ q2,
                                float* __restrict__ k2, float* __restrict__ gk1,
                                float* __restrict__ gk2,
                                const float* __restrict__ bg1, const float* __restrict__ bg2,
                                const float* __restrict__ elog, float* __restrict__ rw)
{
    int l = blockIdx.x;
    int tid = threadIdx.x;
    int w = tid >> 6, lane = tid & 63;
    int idx = l * KD_ + (w << 6) + lane;

    q1[idx] *= 0.125f;
    q2[idx] *= 0.125f;

    float kv = k2[idx];
    float m = kv;
    for (int s = 32; s >= 1; s >>= 1) m = fmaxf(m, __shfl_xor(m, s, 64));
    float ev = expf(kv - m);
    float ssum = ev;
    for (int s = 32; s >= 1; s >>= 1) ssum += __shfl_xor(ssum, s, 64);
    k2[idx] = ev / ssum;

    int bi = (w << 6) + lane;
    gk1[idx] = logsig(gk1[idx] + bg1[bi]) * (1.f / 16.f);
    gk2[idx] = logsig(gk2[idx] + bg2[bi]) * (1.f / 16.f);

    if (tid == 0) {
        float xs[4];
        float mm = -1e30f;
        for (int j = 0; j < 4; ++j) { xs[j] = elog[l * 4 + j]; mm = fmaxf(mm, xs[j]); }
        float s4 = 0.f;
        for (int j = 0; j < 4; ++j) { xs[j] = expf(xs[j] - mm); s4 += xs[j]; }
        for (int j = 0; j < 4; ++j) xs[j] /= s4;
        int arg = 0; float best = xs[0];
        for (int j = 1; j < 4; ++j) if (xs[j] > best) { best = xs[j]; arg = j; }
        for (int j = 0; j < 4; ++j) rw[l * 4 + j] = (j == arg) ? xs[j] : 0.f;
    }
}

// ---------------------------------------------------------------------------
// GLA intra-chunk + per-chunk state contribution. Block = (chunk, head, pass).
// Register-blocked 4x4 inner products, float4 LDS reads, segmented cumsum.
// ---------------------------------------------------------------------------
__global__ void gla_intra(const float* __restrict__ q1, const float* __restrict__ k1,
                          const float* __restrict__ v,  const float* __restrict__ gk1,
                          const float* __restrict__ q2, const float* __restrict__ k2,
                          const float* __restrict__ gk2, const float* __restrict__ rw,
                          float* __restrict__ o_acc, float* __restrict__ kv_all,
                          float* __restrict__ decay_all)
{
    int c = blockIdx.x, h = blockIdx.y, p = blockIdx.z;
    const float* qp = (p == 0) ? q1 : q2;
    const float* kp = (p == 0) ? k1 : k2;
    const float* gp = (p == 0) ? gk1 : gk2;

    __shared__ float bufA[64][68];   // qg -> (later) v      row stride 272B
    __shared__ float bufB[64][68];   // kg
    __shared__ float bufC[64][68];   // gk -> g -> A
    __shared__ float glast[64];
    __shared__ float wrow[64];
    __shared__ float segsum[4][64];

    int tid = threadIdx.x;
    int tx = tid & 15, ty = tid >> 4;

    if (tid < 64) {
        int lg = c * 64 + tid;
        wrow[tid] = (p == 0) ? 1.f : rw[lg * 4 + (p - 1)];
    }
    __syncthreads();

    #pragma unroll
    for (int i = 0; i < 16; ++i) {      // masked gk tile -> bufC
        int idx = tid + (i << 8);
        int t = idx >> 6, d = idx & 63;
        float xg = gp[(size_t)(c * 64 + t) * KD_ + (h << 6) + d];
        if (p > 0 && !(wrow[t] > 0.f)) xg = 0.f;
        bufC[t][d] = xg;
    }
    __syncthreads();

    {   // segmented cumsum along t per dim d (critical path 16, all waves)
        int d = tid & 63, seg = tid >> 6;
        int tb = seg * 16;
        float s = 0.f;
        for (int t = tb; t < tb + 16; ++t) { s += bufC[t][d]; bufC[t][d] = s; }
        segsum[seg][d] = s;
        __syncthreads();
        float off = 0.f;
        for (int ss = 0; ss < seg; ++ss) off += segsum[ss][d];
        if (seg) for (int t = tb; t < tb + 16; ++t) bufC[t][d] += off;
        if (seg == 3) glast[d] = off + s;
    }
    __syncthreads();

    #pragma unroll
    for (int i = 0; i < 16; ++i) {      // qg -> bufA, kg -> bufB
        int idx = tid + (i << 8);
        int t = idx >> 6, d = idx & 63;
        int l = c * 64 + t;
        float wv = wrow[t];
        float g = bufC[t][d];
        bufA[t][d] = qp[(size_t)l * KD_ + (h << 6) + d] * wv * expf(g);
        bufB[t][d] = kp[(size_t)l * KD_ + (h << 6) + d] * wv * expf(-g);
    }
    __syncthreads();

    {   // A[t][s] = tril dot_d(qg[t], kg[s]) -> bufC, 4x4 blocks, float4 reads
        int t0 = ty * 4, s0 = tx * 4;
        if (s0 <= t0 + 3) {
            float acc[4][4] = {};
            for (int d0 = 0; d0 < 64; d0 += 4) {
                float4 a[4], b[4];
                #pragma unroll
                for (int i = 0; i < 4; ++i) a[i] = *(const float4*)&bufA[t0 + i][d0];
                #pragma unroll
                for (int j = 0; j < 4; ++j) b[j] = *(const float4*)&bufB[s0 + j][d0];
                #pragma unroll
                for (int i = 0; i < 4; ++i)
                    #pragma unroll
                    for (int j = 0; j < 4; ++j)
                        acc[i][j] = fmaf(a[i].x, b[j].x, fmaf(a[i].y, b[j].y,
                                    fmaf(a[i].z, b[j].z, fmaf(a[i].w, b[j].w, acc[i][j]))));
            }
            #pragma unroll
            for (int i = 0; i < 4; ++i)
                #pragma unroll
                for (int j = 0; j < 4; ++j)
                    bufC[t0 + i][s0 + j] = (s0 + j <= t0 + i) ? acc[i][j] : 0.f;
        }
    }
    __syncthreads();

    #pragma unroll
    for (int i = 0; i < 16; ++i) {      // v tile -> bufA (qg dead)
        int idx = tid + (i << 8);
        int t = idx >> 6, d = idx & 63;
        bufA[t][d] = v[(size_t)(c * 64 + t) * KD_ + (h << 6) + d];
    }
    __syncthreads();

    {   // o_intra[t][e] = sum_{s<=t} A[t][s] v[s][e]
        int t0 = ty * 4, e0 = tx * 4;
        float acc[4][4] = {};
        for (int s0 = 0; s0 <= t0 + 3; s0 += 4) {
            float4 a[4];
            #pragma unroll
            for (int i = 0; i < 4; ++i) a[i] = *(const float4*)&bufC[t0 + i][s0];
            #pragma unroll
            for (int ss = 0; ss < 4; ++ss) {
                float4 vv = *(const float4*)&bufA[s0 + ss][e0];
                #pragma unroll
                for (int i = 0; i < 4; ++i) {
                    float aa = f4c(a[i], ss);
                    acc[i][0] = fmaf(aa, vv.x, acc[i][0]);
                    acc[i][1] = fmaf(aa, vv.y, acc[i][1]);
                    acc[i][2] = fmaf(aa, vv.z, acc[i][2]);
                    acc[i][3] = fmaf(aa, vv.w, acc[i][3]);
                }
            }
        }
        #pragma unroll
        for (int i = 0; i < 4; ++i)
            #pragma unroll
            for (int j = 0; j < 4; ++j)
                atomicAdd(&o_acc[(size_t)(c * 64 + t0 + i) * KD_ + (h << 6) + e0 + j], acc[i][j]);
    }

    {   // chunk_kv[d][e] = exp(glast[d]) * sum_t kg[t][d] v[t][e]
        int d0 = ty * 4, e0 = tx * 4;
        float acc[4][4] = {};
        for (int t = 0; t < 64; ++t) {
            float4 kk = *(const float4*)&bufB[t][d0];
            float4 vv = *(const float4*)&bufA[t][e0];
            #pragma unroll
            for (int i = 0; i < 4; ++i) {
                float ki = f4c(kk, i);
                acc[i][0] = fmaf(ki, vv.x, acc[i][0]);
                acc[i][1] = fmaf(ki, vv.y, acc[i][1]);
                acc[i][2] = fmaf(ki, vv.z, acc[i][2]);
                acc[i][3] = fmaf(ki, vv.w, acc[i][3]);
            }
        }
        size_t base = (size_t)((c * 8 + h) * 5 + p) * 4096;
        #pragma unroll
        for (int i = 0; i < 4; ++i) {
            float dec = expf(glast[d0 + i]);
            #pragma unroll
            for (int j = 0; j < 4; ++j)
                kv_all[base + (d0 + i) * 64 + e0 + j] = acc[i][j] * dec;
        }
        if (tid < 64) decay_all[(size_t)((c * 8 + h) * 5 + p) * 64 + tid] = expf(glast[tid]);
    }
}

// ---------------------------------------------------------------------------
// Inter-chunk state scan: elementwise 64-step recurrence, in place over kv_all.
// ---------------------------------------------------------------------------
__global__ void gla_state_scan(float* __restrict__ kv, const float* __restrict__ decay)
{
    int gid = blockIdx.x * 256 + threadIdx.x;
    int sub = gid >> 6;
    const size_t stride = 8 * 5 * 64 * 64;
    float S = 0.f;
    float kvv = kv[gid];
    for (int c = 0; c < 64; ++c) {
        size_t o = (size_t)c * stride + gid;
        float nxt = (c < 63) ? kv[o + stride] : 0.f;
        float dec = decay[c * 2560 + sub];
        kv[o] = S;
        S = fmaf(dec, S, kvv);
        kvv = nxt;
    }
}

// ---------------------------------------------------------------------------
// Inter-chunk output: o_inter[c] = qg_c @ S_entering_c. Block = (c,h,p).
// ---------------------------------------------------------------------------
__global__ void gla_inter(const float* __restrict__ q1, const float* __restrict__ q2,
                          const float* __restrict__ gk1, const float* __restrict__ gk2,
                          const float* __restrict__ rw, const float* __restrict__ Spre,
                          float* __restrict__ o_acc)
{
    int c = blockIdx.x, h = blockIdx.y, p = blockIdx.z;
    const float* qp = (p == 0) ? q1 : q2;
    const float* gp = (p == 0) ? gk1 : gk2;

    __shared__ float bufQ[64][68];  // gk -> g -> qg (in place)
    __shared__ float bufS[64][68];
    __shared__ float wrow[64];
    __shared__ float segsum[4][64];

    int tid = threadIdx.x;
    int tx = tid & 15, ty = tid >> 4;

    if (tid < 64) {
        int lg = c * 64 + tid;
        wrow[tid] = (p == 0) ? 1.f : rw[lg * 4 + (p - 1)];
    }
    __syncthreads();

    #pragma unroll
    for (int i = 0; i < 16; ++i) {
        int idx = tid + (i << 8);
        int t = idx >> 6, d = idx & 63;
        float xg = gp[(size_t)(c * 64 + t) * KD_ + (h << 6) + d];
        if (p > 0 && !(wrow[t] > 0.f)) xg = 0.f;
        bufQ[t][d] = xg;
    }
    size_t sbase = (size_t)((c * 8 + h) * 5 + p) * 4096;
    #pragma unroll
    for (int i = 0; i < 16; ++i) {
        int idx = tid + (i << 8);
        bufS[idx >> 6][idx & 63] = Spre[sbase + idx];
    }
    __syncthreads();

    {   // segmented cumsum
        int d = tid & 63, seg = tid >> 6;
        int tb = seg * 16;
        float s = 0.f;
        for (int t = tb; t < tb + 16; ++t) { s += bufQ[t][d]; bufQ[t][d] = s; }
        segsum[seg][d] = s;
        __syncthreads();
        float off = 0.f;
        for (int ss = 0; ss < seg; ++ss) off += segsum[ss][d];
        if (seg) for (int t = tb; t < tb + 16; ++t) bufQ[t][d] += off;
    }
    __syncthreads();

    #pragma unroll
    for (int i = 0; i < 16; ++i) {      // qg in place
        int idx = tid + (i << 8);
        int t = idx >> 6, d = idx & 63;
        int l = c * 64 + t;
        bufQ[t][d] = qp[(size_t)l * KD_ + (h << 6) + d] * wrow[t] * expf(bufQ[t][d]);
    }
    __syncthreads();

    {   // o_inter[t][e] = sum_d qg[t][d] S[d][e]
        int t0 = ty * 4, e0 = tx * 4;
        float acc[4][4] = {};
        for (int d0 = 0; d0 < 64; d0 += 4) {
            float4 a[4];
            #pragma unroll
            for (int i = 0; i < 4; ++i) a[i] = *(const float4*)&bufQ[t0 + i][d0];
            #pragma unroll
            for (int dd = 0; dd < 4; ++dd) {
                float4 sv = *(const float4*)&bufS[d0 + dd][e0];
                #pragma unroll
                for (int i = 0; i < 4; ++i) {
                    float aa = f4c(a[i], dd);
                    acc[i][0] = fmaf(aa, sv.x, acc[i][0]);
                    acc[i][1] = fmaf(aa, sv.y, acc[i][1]);
                    acc[i][2] = fmaf(aa, sv.z, acc[i][2]);
                    acc[i][3] = fmaf(aa, sv.w, acc[i][3]);
                }
            }
        }
        #pragma unroll
        for (int i = 0; i < 4; ++i)
            #pragma unroll
            for (int j = 0; j < 4; ++j)
                atomicAdd(&o_acc[(size_t)(c * 64 + t0 + i) * KD_ + (h << 6) + e0 + j], acc[i][j]);
    }
}

// ---------------------------------------------------------------------------
__global__ void postnorm(const float* __restrict__ o_acc, const float* __restrict__ gbuf,
                         const float* __restrict__ norm_w, float* __restrict__ og)
{
    int l = blockIdx.x;
    int tid = threadIdx.x;
    int w = tid >> 6, lane = tid & 63;
    int idx = l * KD_ + (w << 6) + lane;
    float o = o_acc[idx];
    float ss = o * o;
    for (int s = 32; s >= 1; s >>= 1) ss += __shfl_xor(ss, s, 64);
    float r = rsqrtf(ss * (1.f / 64.f) + 1e-5f);
    float val = o * r * norm_w[lane];
    float gv = gbuf[idx];
    val *= gv / (1.f + expf(-gv));
    og[idx] = val;
}

// ---------------------------------------------------------------------------
extern "C" void kernel_launch(void* const* d_in, const int* in_sizes, int n_in,
                              void* d_out, int out_size, void* d_ws, size_t ws_size,
                              hipStream_t stream)
{
    const float* x    = (const float*)d_in[0];
    const float* Wq   = (const float*)d_in[1];
    const float* Wk   = (const float*)d_in[2];
    const float* Wv   = (const float*)d_in[3];
    const float* Wqa  = (const float*)d_in[4];
    const float* Wqb  = (const float*)d_in[5];
    const float* Wka  = (const float*)d_in[6];
    const float* Wkb  = (const float*)d_in[7];
    const float* Wg1a = (const float*)d_in[8];
    const float* Wg1b = (const float*)d_in[9];
    const float* bg1  = (const float*)d_in[10];
    const float* Wg2a = (const float*)d_in[11];
    const float* Wg2b = (const float*)d_in[12];
    const float* bg2  = (const float*)d_in[13];
    const float* We   = (const float*)d_in[14];
    const float* Wga  = (const float*)d_in[15];
    const float* Wgb  = (const float*)d_in[16];
    const float* normw= (const float*)d_in[17];
    const float* Wo   = (const float*)d_in[18];

    float* ws = (float*)d_ws;
    const size_t LKD = (size_t)LL * KD_;
    float* q1   = ws;
    float* k1   = q1 + LKD;
    float* v    = k1 + LKD;
    float* q2   = v  + LKD;
    float* k2   = q2 + LKD;
    float* gk1  = k2 + LKD;
    float* gk2  = gk1 + LKD;
    float* o_acc= gk2 + LKD;
    float* tqa  = o_acc + LKD;
    float* tka  = tqa + (size_t)LL * 64;
    float* tg1  = tka + (size_t)LL * 64;
    float* tg2  = tg1 + (size_t)LL * 16;
    float* elog = tg2 + (size_t)LL * 16;
    float* rw   = elog + (size_t)LL * 4;
    float* kv_all    = rw + (size_t)LL * 4;
    float* decay_all = kv_all + (size_t)64 * 8 * 5 * 64 * 64;
    float* gbuf = k1;
    float* tga  = tqa;
    float* og   = q1;

    dim3 blk(256);
    auto G  = [](int M, int N) { return dim3((unsigned)((N + 63) / 64), (unsigned)(M / 64)); };

    hipMemsetAsync(o_acc, 0, LKD * sizeof(float), stream);

    // fused QKV projection (384 blocks)
    gemm128b<<<dim3(4, 32, 3), blk, 0, stream>>>(x, Wq, Wk, Wv, q1, k1, v, LL, KD_, 1024);

    gemm64<<<G(LL, 64), blk, 0, stream>>>(x, Wqa, tqa, LL, 64, 1024);
    gemm128b<<<dim3(4, 32, 1), blk, 0, stream>>>(tqa, Wqb, Wqb, Wqb, q2, q2, q2, LL, KD_, 64);
    gemm64<<<G(LL, 64), blk, 0, stream>>>(x, Wka, tka, LL, 64, 1024);
    gemm128b<<<dim3(4, 32, 1), blk, 0, stream>>>(tka, Wkb, Wkb, Wkb, k2, k2, k2, LL, KD_, 64);
    gemm64<<<G(LL, 16), blk, 0, stream>>>(x, Wg1a, tg1, LL, 16, 1024);
    gemm128b<<<dim3(4, 32, 1), blk, 0, stream>>>(tg1, Wg1b, Wg1b, Wg1b, gk1, gk1, gk1, LL, KD_, 16);
    gemm64<<<G(LL, 16), blk, 0, stream>>>(x, Wg2a, tg2, LL, 16, 1024);
    gemm128b<<<dim3(4, 32, 1), blk, 0, stream>>>(tg2, Wg2b, Wg2b, Wg2b, gk2, gk2, gk2, LL, KD_, 16);
    gemm64<<<G(LL, 4), blk, 0, stream>>>(x, We, elog, LL, 4, 1024);

    elementwise_pre<<<LL, 512, 0, stream>>>(q1, q2, k2, gk1, gk2, bg1, bg2, elog, rw);

    gla_intra<<<dim3(64, 8, 5), blk, 0, stream>>>(q1, k1, v, gk1, q2, k2, gk2, rw,
                                                  o_acc, kv_all, decay_all);
    gla_state_scan<<<dim3(640), blk, 0, stream>>>(kv_all, decay_all);
    gla_inter<<<dim3(64, 8, 5), blk, 0, stream>>>(q1, q2, gk1, gk2, rw, kv_all, o_acc);

    gemm64<<<G(LL, 64), blk, 0, stream>>>(x, Wga, tga, LL, 64, 1024);
    gemm128b<<<dim3(4, 32, 1), blk, 0, stream>>>(tga, Wgb, Wgb, Wgb, gbuf, gbuf, gbuf, LL, KD_, 64);

    postnorm<<<LL, 512, 0, stream>>>(o_acc, gbuf, normw, og);

    gemm128b<<<dim3(8, 32, 1), blk, 0, stream>>>(og, Wo, Wo, Wo,
                                                 (float*)d_out, (float*)d_out, (float*)d_out,
                                                 LL, 1024, KD_);
}

// Round 5
// 789.818 us; speedup vs baseline: 3.6000x; 1.6131x over previous
//
#include <hip/hip_runtime.h>
#include <math.h>

#define LL   4096
#define HH   8
#define DK_  64
#define DV_  64
#define KD_  512
#define NEXP 4

typedef __attribute__((ext_vector_type(8))) short  s16x8;
typedef __attribute__((ext_vector_type(4))) float  f32x4;

__device__ __forceinline__ float f4c(const float4& v, int i) {
    return i == 0 ? v.x : i == 1 ? v.y : i == 2 ? v.z : v.w;
}

__device__ __forceinline__ unsigned short f2bf(float f) {   // RNE f32->bf16
    unsigned u = __float_as_uint(f);
    u += 0x7FFFu + ((u >> 16) & 1u);
    return (unsigned short)(u >> 16);
}

__device__ __forceinline__ void split2(float v, unsigned short& h, unsigned short& l) {
    h = f2bf(v);
    float hf = __uint_as_float((unsigned)h << 16);
    l = f2bf(v - hf);
}

// ---------------------------------------------------------------------------
// f32 [M][K] -> split-bf16 A layout [M][3K] = [hi | lo | hi]. K = 2^kshift.
// ---------------------------------------------------------------------------
__global__ void cvt_splitA(const float* __restrict__ in, unsigned short* __restrict__ out,
                           int n, int kshift)
{
    int i = blockIdx.x * 256 + threadIdx.x;
    if (i >= n) return;
    unsigned short h, l;
    split2(in[i], h, l);
    int K = 1 << kshift;
    int m = i >> kshift, k = i & (K - 1);
    size_t ro = (size_t)m * 3 * K;
    out[ro + k]         = h;
    out[ro + K + k]     = l;
    out[ro + 2 * K + k] = h;
}

// ---------------------------------------------------------------------------
// f32 [K][N] -> split-bf16 B layout [N][3K] = [hi | hi | lo] (transposed).
// Grid (N/32, K/32), block (32,8).
// ---------------------------------------------------------------------------
__global__ void cvtT_split(const float* __restrict__ W, unsigned short* __restrict__ WT,
                           int K, int N)
{
    __shared__ float t[32][33];
    int bx = blockIdx.x * 32;   // n
    int by = blockIdx.y * 32;   // k
    int x = threadIdx.x, y = threadIdx.y;
    #pragma unroll
    for (int i = 0; i < 4; ++i)
        t[y + 8 * i][x] = W[(size_t)(by + y + 8 * i) * N + bx + x];
    __syncthreads();
    #pragma unroll
    for (int i = 0; i < 4; ++i) {
        unsigned short h, l;
        split2(t[x][y + 8 * i], h, l);
        size_t ro = (size_t)(bx + y + 8 * i) * 3 * K + (by + x);
        WT[ro]         = h;
        WT[ro + K]     = h;
        WT[ro + 2 * K] = l;
    }
}

// ---------------------------------------------------------------------------
// bf16 MFMA GEMM: C[M][N]f32 = A[M][K']bf16 @ Bt[N][K']bf16^T.
// 128x128 tile, BK=64, 4 waves (each 64x64), 16x16x32 MFMA.
// With split layouts (A=[hi|lo|hi], B=[hi|hi|lo], K'=3K) computes
// ah*bh + al*bh + ah*bl ~= f32-accurate product. z selects (A,B,C).
// ---------------------------------------------------------------------------
__global__ __launch_bounds__(256) void gemm_mfma(
    const unsigned short* __restrict__ A0, const unsigned short* __restrict__ A1,
    const unsigned short* __restrict__ A2,
    const unsigned short* __restrict__ B0, const unsigned short* __restrict__ B1,
    const unsigned short* __restrict__ B2,
    float* __restrict__ C0, float* __restrict__ C1, float* __restrict__ C2,
    int M, int N, int K)
{
    const unsigned short* A = (blockIdx.z == 0) ? A0 : (blockIdx.z == 1) ? A1 : A2;
    const unsigned short* B = (blockIdx.z == 0) ? B0 : (blockIdx.z == 1) ? B1 : B2;
    float*                C = (blockIdx.z == 0) ? C0 : (blockIdx.z == 1) ? C1 : C2;

    __shared__ __align__(16) unsigned short sm[2 * 128 * 64];
    unsigned short* As = sm;
    unsigned short* Bs = sm + 128 * 64;

    int tid  = threadIdx.x;
    int lane = tid & 63;
    int w    = tid >> 6;
    int m0 = blockIdx.y * 128, n0 = blockIdx.x * 128;
    int wr = w >> 1, wc = w & 1;

    f32x4 acc[4][4];
    #pragma unroll
    for (int i = 0; i < 4; ++i)
        #pragma unroll
        for (int j = 0; j < 4; ++j)
            acc[i][j] = (f32x4){0.f, 0.f, 0.f, 0.f};

    const int srow = (lane >> 3);
    const int scb  = ((lane & 7) * 16) ^ (srow << 4);   // pre-swizzled source col-byte

    for (int kt = 0; kt < K; kt += 64) {
        __syncthreads();
        #pragma unroll
        for (int q = 0; q < 4; ++q) {
            int r = w * 32 + q * 8 + srow;
            const char* ga = (const char*)A + ((size_t)(m0 + r) * K + kt) * 2 + scb;
            const char* gb = (const char*)B + ((size_t)(n0 + r) * K + kt) * 2 + scb;
            __builtin_amdgcn_global_load_lds(
                (const __attribute__((address_space(1))) void*)ga,
                (__attribute__((address_space(3))) void*)((char*)As + (w * 32 + q * 8) * 128),
                16, 0, 0);
            __builtin_amdgcn_global_load_lds(
                (const __attribute__((address_space(1))) void*)gb,
                (__attribute__((address_space(3))) void*)((char*)Bs + (w * 32 + q * 8) * 128),
                16, 0, 0);
        }
        __syncthreads();

        #pragma unroll
        for (int kk = 0; kk < 2; ++kk) {
            int kb = kk * 64 + (lane >> 4) * 16;
            s16x8 af[4], bfr[4];
            #pragma unroll
            for (int mi = 0; mi < 4; ++mi) {
                int r = wr * 64 + mi * 16 + (lane & 15);
                af[mi] = *(const s16x8*)((const char*)As + r * 128 + (kb ^ ((r & 7) << 4)));
            }
            #pragma unroll
            for (int ni = 0; ni < 4; ++ni) {
                int r = wc * 64 + ni * 16 + (lane & 15);
                bfr[ni] = *(const s16x8*)((const char*)Bs + r * 128 + (kb ^ ((r & 7) << 4)));
            }
            #pragma unroll
            for (int mi = 0; mi < 4; ++mi)
                #pragma unroll
                for (int ni = 0; ni < 4; ++ni)
                    acc[mi][ni] = __builtin_amdgcn_mfma_f32_16x16x32_bf16(
                        af[mi], bfr[ni], acc[mi][ni], 0, 0, 0);
        }
    }

    #pragma unroll
    for (int mi = 0; mi < 4; ++mi)
        #pragma unroll
        for (int ni = 0; ni < 4; ++ni) {
            int col = n0 + wc * 64 + ni * 16 + (lane & 15);
            int rb  = m0 + wr * 64 + mi * 16 + (lane >> 4) * 4;
            #pragma unroll
            for (int j = 0; j < 4; ++j)
                C[(size_t)(rb + j) * N + col] = acc[mi][ni][j];
        }
}

// ---------------------------------------------------------------------------
// Small-N f32 GEMM (64x64 tile), fused over blockIdx.z (3 A/B/C triples).
// ---------------------------------------------------------------------------
__global__ void gemm64f(const float* __restrict__ A0, const float* __restrict__ A1,
                        const float* __restrict__ A2,
                        const float* __restrict__ B0, const float* __restrict__ B1,
                        const float* __restrict__ B2,
                        float* __restrict__ C0, float* __restrict__ C1, float* __restrict__ C2,
                        int M, int N, int K)
{
    const float* A = (blockIdx.z == 0) ? A0 : (blockIdx.z == 1) ? A1 : A2;
    const float* B = (blockIdx.z == 0) ? B0 : (blockIdx.z == 1) ? B1 : B2;
    float*       C = (blockIdx.z == 0) ? C0 : (blockIdx.z == 1) ? C1 : C2;

    __shared__ float As[16][65];
    __shared__ float Bs[16][65];
    int tid = threadIdx.x;
    int n0 = blockIdx.x * 64;
    int m0 = blockIdx.y * 64;
    int tx = tid & 15, ty = tid >> 4;
    float acc[4][4] = {};
    for (int k0 = 0; k0 < K; k0 += 16) {
        {
            int row = tid >> 2, q4 = tid & 3;
            const float4 a = *reinterpret_cast<const float4*>(&A[(size_t)(m0 + row) * K + k0 + q4 * 4]);
            As[q4 * 4 + 0][row] = a.x;
            As[q4 * 4 + 1][row] = a.y;
            As[q4 * 4 + 2][row] = a.z;
            As[q4 * 4 + 3][row] = a.w;
        }
        #pragma unroll
        for (int j = 0; j < 4; ++j) {
            int lin = tid * 4 + j;
            int kr = lin >> 6, cc = lin & 63;
            int col = n0 + cc;
            Bs[kr][cc] = (col < N) ? B[(size_t)(k0 + kr) * N + col] : 0.f;
        }
        __syncthreads();
        #pragma unroll
        for (int k = 0; k < 16; ++k) {
            float av[4], bv[4];
            #pragma unroll
            for (int i = 0; i < 4; ++i) av[i] = As[k][ty * 4 + i];
            #pragma unroll
            for (int j = 0; j < 4; ++j) bv[j] = Bs[k][tx * 4 + j];
            #pragma unroll
            for (int i = 0; i < 4; ++i)
                #pragma unroll
                for (int j = 0; j < 4; ++j)
                    acc[i][j] = fmaf(av[i], bv[j], acc[i][j]);
        }
        __syncthreads();
    }
    #pragma unroll
    for (int i = 0; i < 4; ++i) {
        int m = m0 + ty * 4 + i;
        #pragma unroll
        for (int j = 0; j < 4; ++j) {
            int n = n0 + tx * 4 + j;
            if (n < N) C[(size_t)m * N + n] = acc[i][j];
        }
    }
}

// ---------------------------------------------------------------------------
// 128x128 f32 GEMM, fused over z (2 A/B/C triples) — used for gate-b (K=16).
// ---------------------------------------------------------------------------
__global__ void gemm128b(const float* __restrict__ A0, const float* __restrict__ A1,
                         const float* __restrict__ B0, const float* __restrict__ B1,
                         float* __restrict__ C0, float* __restrict__ C1,
                         int M, int N, int K)
{
    const float* A = (blockIdx.z == 0) ? A0 : A1;
    const float* B = (blockIdx.z == 0) ? B0 : B1;
    float*       C = (blockIdx.z == 0) ? C0 : C1;

    __shared__ float As[16][132];
    __shared__ float Bs[16][132];
    int tid = threadIdx.x;
    int n0 = blockIdx.x * 128;
    int m0 = blockIdx.y * 128;
    int tx = tid & 15, ty = tid >> 4;
    float acc[8][8] = {};

    for (int k0 = 0; k0 < K; k0 += 16) {
        #pragma unroll
        for (int u = 0; u < 2; ++u) {
            int lin = tid + (u << 8);
            int row = lin >> 2, q4 = lin & 3;
            float4 a = *reinterpret_cast<const float4*>(&A[(size_t)(m0 + row) * K + k0 + q4 * 4]);
            As[q4 * 4 + 0][row] = a.x;
            As[q4 * 4 + 1][row] = a.y;
            As[q4 * 4 + 2][row] = a.z;
            As[q4 * 4 + 3][row] = a.w;
        }
        #pragma unroll
        for (int u = 0; u < 2; ++u) {
            int lin = tid + (u << 8);
            int kr = lin >> 5, c4 = lin & 31;
            *reinterpret_cast<float4*>(&Bs[kr][c4 * 4]) =
                *reinterpret_cast<const float4*>(&B[(size_t)(k0 + kr) * N + n0 + c4 * 4]);
        }
        __syncthreads();
        #pragma unroll
        for (int k = 0; k < 16; ++k) {
            float4 a0 = *(const float4*)&As[k][ty * 4];
            float4 a1 = *(const float4*)&As[k][64 + ty * 4];
            float4 b0 = *(const float4*)&Bs[k][tx * 4];
            float4 b1 = *(const float4*)&Bs[k][64 + tx * 4];
            float av[8] = {a0.x, a0.y, a0.z, a0.w, a1.x, a1.y, a1.z, a1.w};
            float bv[8] = {b0.x, b0.y, b0.z, b0.w, b1.x, b1.y, b1.z, b1.w};
            #pragma unroll
            for (int i = 0; i < 8; ++i)
                #pragma unroll
                for (int j = 0; j < 8; ++j)
                    acc[i][j] = fmaf(av[i], bv[j], acc[i][j]);
        }
        __syncthreads();
    }
    #pragma unroll
    for (int i = 0; i < 8; ++i) {
        int m = m0 + ((i < 4) ? ty * 4 + i : 64 + ty * 4 + (i - 4));
        float4 c0 = make_float4(acc[i][0], acc[i][1], acc[i][2], acc[i][3]);
        float4 c1 = make_float4(acc[i][4], acc[i][5], acc[i][6], acc[i][7]);
        *reinterpret_cast<float4*>(&C[(size_t)m * N + n0 + tx * 4]) = c0;
        *reinterpret_cast<float4*>(&C[(size_t)m * N + n0 + 64 + tx * 4]) = c1;
    }
}

// ---------------------------------------------------------------------------
__device__ inline float logsig(float x) {
    return fminf(x, 0.f) - log1pf(expf(-fabsf(x)));
}

__global__ void elementwise_pre(float* __restrict__ q1, float* __restrict__ q2,
                                float* __restrict__ k2, float* __restrict__ gk1,
                                float* __restrict__ gk2,
                                const float* __restrict__ bg1, const float* __restrict__ bg2,
                                const float* __restrict__ elog, float* __restrict__ rw)
{
    int l = blockIdx.x;
    int tid = threadIdx.x;
    int w = tid >> 6, lane = tid & 63;
    int idx = l * KD_ + (w << 6) + lane;

    q1[idx] *= 0.125f;
    q2[idx] *= 0.125f;

    float kv = k2[idx];
    float m = kv;
    for (int s = 32; s >= 1; s >>= 1) m = fmaxf(m, __shfl_xor(m, s, 64));
    float ev = expf(kv - m);
    float ssum = ev;
    for (int s = 32; s >= 1; s >>= 1) ssum += __shfl_xor(ssum, s, 64);
    k2[idx] = ev / ssum;

    int bi = (w << 6) + lane;
    gk1[idx] = logsig(gk1[idx] + bg1[bi]) * (1.f / 16.f);
    gk2[idx] = logsig(gk2[idx] + bg2[bi]) * (1.f / 16.f);

    if (tid == 0) {
        float xs[4];
        float mm = -1e30f;
        for (int j = 0; j < 4; ++j) { xs[j] = elog[l * 4 + j]; mm = fmaxf(mm, xs[j]); }
        float s4 = 0.f;
        for (int j = 0; j < 4; ++j) { xs[j] = expf(xs[j] - mm); s4 += xs[j]; }
        for (int j = 0; j < 4; ++j) xs[j] /= s4;
        int arg = 0; float best = xs[0];
        for (int j = 1; j < 4; ++j) if (xs[j] > best) { best = xs[j]; arg = j; }
        for (int j = 0; j < 4; ++j) rw[l * 4 + j] = (j == arg) ? xs[j] : 0.f;
    }
}

// ---------------------------------------------------------------------------
// GLA intra-chunk + per-chunk state. Block = (chunk, head, pass).
// kg stored transposed [d][t] so all float4 LDS reads are 2-way (free).
// ---------------------------------------------------------------------------
__global__ void gla_intra(const float* __restrict__ q1, const float* __restrict__ k1,
                          const float* __restrict__ v,  const float* __restrict__ gk1,
                          const float* __restrict__ q2, const float* __restrict__ k2,
                          const float* __restrict__ gk2, const float* __restrict__ rw,
                          float* __restrict__ o_acc, float* __restrict__ kv_all,
                          float* __restrict__ decay_all)
{
    int c = blockIdx.x, h = blockIdx.y, p = blockIdx.z;
    const float* qp = (p == 0) ? q1 : q2;
    const float* kp = (p == 0) ? k1 : k2;
    const float* gp = (p == 0) ? gk1 : gk2;

    __shared__ float bufA[64][68];   // qg -> later v
    __shared__ float bufB[64][68];   // kg TRANSPOSED: [d][t]
    __shared__ float bufC[64][68];   // gk -> g -> A[t][s]
    __shared__ float glast[64];
    __shared__ float wrow[64];
    __shared__ float segsum[4][64];

    int tid = threadIdx.x;
    int tx = tid & 15, ty = tid >> 4;

    if (tid < 64) {
        int lg = c * 64 + tid;
        wrow[tid] = (p == 0) ? 1.f : rw[lg * 4 + (p - 1)];
    }
    __syncthreads();

    #pragma unroll
    for (int i = 0; i < 16; ++i) {
        int idx = tid + (i << 8);
        int t = idx >> 6, d = idx & 63;
        float xg = gp[(size_t)(c * 64 + t) * KD_ + (h << 6) + d];
        if (p > 0 && !(wrow[t] > 0.f)) xg = 0.f;
        bufC[t][d] = xg;
    }
    __syncthreads();

    {   // segmented cumsum along t per dim d
        int d = tid & 63, seg = tid >> 6;
        int tb = seg * 16;
        float s = 0.f;
        for (int t = tb; t < tb + 16; ++t) { s += bufC[t][d]; bufC[t][d] = s; }
        segsum[seg][d] = s;
        __syncthreads();
        float off = 0.f;
        for (int ss = 0; ss < seg; ++ss) off += segsum[ss][d];
        if (seg) for (int t = tb; t < tb + 16; ++t) bufC[t][d] += off;
        if (seg == 3) glast[d] = off + s;
    }
    __syncthreads();

    #pragma unroll
    for (int i = 0; i < 16; ++i) {      // qg -> bufA[t][d], kg -> bufB[d][t]
        int idx = tid + (i << 8);
        int t = idx >> 6, d = idx & 63;
        int l = c * 64 + t;
        float wv = wrow[t];
        float g = bufC[t][d];
        bufA[t][d] = qp[(size_t)l * KD_ + (h << 6) + d] * wv * expf(g);
        bufB[d][t] = kp[(size_t)l * KD_ + (h << 6) + d] * wv * expf(-g);
    }
    __syncthreads();

    {   // A[t][s] = tril dot_d(qg[t], kg[s]) -> bufC
        int t0 = ty * 4, s0 = tx * 4;
        if (s0 <= t0 + 3) {
            float acc[4][4] = {};
            for (int d0 = 0; d0 < 64; d0 += 4) {
                float4 a[4];
                #pragma unroll
                for (int i = 0; i < 4; ++i) a[i] = *(const float4*)&bufA[t0 + i][d0];
                #pragma unroll
                for (int dd = 0; dd < 4; ++dd) {
                    float4 bv = *(const float4*)&bufB[d0 + dd][s0];
                    #pragma unroll
                    for (int i = 0; i < 4; ++i) {
                        float aa = f4c(a[i], dd);
                        acc[i][0] = fmaf(aa, bv.x, acc[i][0]);
                        acc[i][1] = fmaf(aa, bv.y, acc[i][1]);
                        acc[i][2] = fmaf(aa, bv.z, acc[i][2]);
                        acc[i][3] = fmaf(aa, bv.w, acc[i][3]);
                    }
                }
            }
            #pragma unroll
            for (int i = 0; i < 4; ++i)
                #pragma unroll
                for (int j = 0; j < 4; ++j)
                    bufC[t0 + i][s0 + j] = (s0 + j <= t0 + i) ? acc[i][j] : 0.f;
        }
    }
    __syncthreads();

    #pragma unroll
    for (int i = 0; i < 16; ++i) {      // v tile -> bufA
        int idx = tid + (i << 8);
        int t = idx >> 6, d = idx & 63;
        bufA[t][d] = v[(size_t)(c * 64 + t) * KD_ + (h << 6) + d];
    }
    __syncthreads();

    {   // o_intra[t][e] = sum_{s<=t} A[t][s] v[s][e]
        int t0 = ty * 4, e0 = tx * 4;
        float acc[4][4] = {};
        for (int s0 = 0; s0 <= t0 + 3; s0 += 4) {
            float4 a[4];
            #pragma unroll
            for (int i = 0; i < 4; ++i) a[i] = *(const float4*)&bufC[t0 + i][s0];
            #pragma unroll
            for (int ss = 0; ss < 4; ++ss) {
                float4 vv = *(const float4*)&bufA[s0 + ss][e0];
                #pragma unroll
                for (int i = 0; i < 4; ++i) {
                    float aa = f4c(a[i], ss);
                    acc[i][0] = fmaf(aa, vv.x, acc[i][0]);
                    acc[i][1] = fmaf(aa, vv.y, acc[i][1]);
                    acc[i][2] = fmaf(aa, vv.z, acc[i][2]);
                    acc[i][3] = fmaf(aa, vv.w, acc[i][3]);
                }
            }
        }
        #pragma unroll
        for (int i = 0; i < 4; ++i)
            #pragma unroll
            for (int j = 0; j < 4; ++j)
                atomicAdd(&o_acc[(size_t)(c * 64 + t0 + i) * KD_ + (h << 6) + e0 + j], acc[i][j]);
    }

    {   // chunk_kv[d][e] = exp(glast[d]) * sum_t kg[t][d] v[t][e]
        int e0 = tx * 4;
        float acc[4][4] = {};
        for (int t0v = 0; t0v < 64; t0v += 4) {
            float4 kk[4];
            #pragma unroll
            for (int i = 0; i < 4; ++i) kk[i] = *(const float4*)&bufB[ty + 16 * i][t0v];
            #pragma unroll
            for (int ss = 0; ss < 4; ++ss) {
                float4 vv = *(const float4*)&bufA[t0v + ss][e0];
                #pragma unroll
                for (int i = 0; i < 4; ++i) {
                    float ki = f4c(kk[i], ss);
                    acc[i][0] = fmaf(ki, vv.x, acc[i][0]);
                    acc[i][1] = fmaf(ki, vv.y, acc[i][1]);
                    acc[i][2] = fmaf(ki, vv.z, acc[i][2]);
                    acc[i][3] = fmaf(ki, vv.w, acc[i][3]);
                }
            }
        }
        size_t base = (size_t)((c * 8 + h) * 5 + p) * 4096;
        #pragma unroll
        for (int i = 0; i < 4; ++i) {
            int d = ty + 16 * i;
            float dec = expf(glast[d]);
            #pragma unroll
            for (int j = 0; j < 4; ++j)
                kv_all[base + d * 64 + e0 + j] = acc[i][j] * dec;
        }
        if (tid < 64) decay_all[(size_t)((c * 8 + h) * 5 + p) * 64 + tid] = expf(glast[tid]);
    }
}

// ---------------------------------------------------------------------------
__global__ void gla_state_scan(float* __restrict__ kv, const float* __restrict__ decay)
{
    int gid = blockIdx.x * 256 + threadIdx.x;
    int sub = gid >> 6;
    const size_t stride = 8 * 5 * 64 * 64;
    float S = 0.f;
    float kvv = kv[gid];
    for (int c = 0; c < 64; ++c) {
        size_t o = (size_t)c * stride + gid;
        float nxt = (c < 63) ? kv[o + stride] : 0.f;
        float dec = decay[c * 2560 + sub];
        kv[o] = S;
        S = fmaf(dec, S, kvv);
        kvv = nxt;
    }
}

// ---------------------------------------------------------------------------
__global__ void gla_inter(const float* __restrict__ q1, const float* __restrict__ q2,
                          const float* __restrict__ gk1, const float* __restrict__ gk2,
                          const float* __restrict__ rw, const float* __restrict__ Spre,
                          float* __restrict__ o_acc)
{
    int c = blockIdx.x, h = blockIdx.y, p = blockIdx.z;
    const float* qp = (p == 0) ? q1 : q2;
    const float* gp = (p == 0) ? gk1 : gk2;

    __shared__ float bufQ[64][68];
    __shared__ float bufS[64][68];
    __shared__ float wrow[64];
    __shared__ float segsum[4][64];

    int tid = threadIdx.x;
    int tx = tid & 15, ty = tid >> 4;

    if (tid < 64) {
        int lg = c * 64 + tid;
        wrow[tid] = (p == 0) ? 1.f : rw[lg * 4 + (p - 1)];
    }
    __syncthreads();

    #pragma unroll
    for (int i = 0; i < 16; ++i) {
        int idx = tid + (i << 8);
        int t = idx >> 6, d = idx & 63;
        float xg = gp[(size_t)(c * 64 + t) * KD_ + (h << 6) + d];
        if (p > 0 && !(wrow[t] > 0.f)) xg = 0.f;
        bufQ[t][d] = xg;
    }
    size_t sbase = (size_t)((c * 8 + h) * 5 + p) * 4096;
    #pragma unroll
    for (int i = 0; i < 16; ++i) {
        int idx = tid + (i << 8);
        bufS[idx >> 6][idx & 63] = Spre[sbase + idx];
    }
    __syncthreads();

    {
        int d = tid & 63, seg = tid >> 6;
        int tb = seg * 16;
        float s = 0.f;
        for (int t = tb; t < tb + 16; ++t) { s += bufQ[t][d]; bufQ[t][d] = s; }
        segsum[seg][d] = s;
        __syncthreads();
        float off = 0.f;
        for (int ss = 0; ss < seg; ++ss) off += segsum[ss][d];
        if (seg) for (int t = tb; t < tb + 16; ++t) bufQ[t][d] += off;
    }
    __syncthreads();

    #pragma unroll
    for (int i = 0; i < 16; ++i) {
        int idx = tid + (i << 8);
        int t = idx >> 6, d = idx & 63;
        int l = c * 64 + t;
        bufQ[t][d] = qp[(size_t)l * KD_ + (h << 6) + d] * wrow[t] * expf(bufQ[t][d]);
    }
    __syncthreads();

    {
        int t0 = ty * 4, e0 = tx * 4;
        float acc[4][4] = {};
        for (int d0 = 0; d0 < 64; d0 += 4) {
            float4 a[4];
            #pragma unroll
            for (int i = 0; i < 4; ++i) a[i] = *(const float4*)&bufQ[t0 + i][d0];
            #pragma unroll
            for (int dd = 0; dd < 4; ++dd) {
                float4 sv = *(const float4*)&bufS[d0 + dd][e0];
                #pragma unroll
                for (int i = 0; i < 4; ++i) {
                    float aa = f4c(a[i], dd);
                    acc[i][0] = fmaf(aa, sv.x, acc[i][0]);
                    acc[i][1] = fmaf(aa, sv.y, acc[i][1]);
                    acc[i][2] = fmaf(aa, sv.z, acc[i][2]);
                    acc[i][3] = fmaf(aa, sv.w, acc[i][3]);
                }
            }
        }
        #pragma unroll
        for (int i = 0; i < 4; ++i)
            #pragma unroll
            for (int j = 0; j < 4; ++j)
                atomicAdd(&o_acc[(size_t)(c * 64 + t0 + i) * KD_ + (h << 6) + e0 + j], acc[i][j]);
    }
}

// ---------------------------------------------------------------------------
// Post: RMS-norm, * norm_w, * silu(g); emits split-bf16 A layout [hi|lo|hi]
// with row length 3*KD_ for the final MFMA GEMM.
// ---------------------------------------------------------------------------
__global__ void postnorm(const float* __restrict__ o_acc, const float* __restrict__ gbuf,
                         const float* __restrict__ norm_w, unsigned short* __restrict__ og2)
{
    int l = blockIdx.x;
    int tid = threadIdx.x;
    int w = tid >> 6, lane = tid & 63;
    int bi = (w << 6) + lane;
    int idx = l * KD_ + bi;
    float o = o_acc[idx];
    float ss = o * o;
    for (int s = 32; s >= 1; s >>= 1) ss += __shfl_xor(ss, s, 64);
    float r = rsqrtf(ss * (1.f / 64.f) + 1e-5f);
    float val = o * r * norm_w[lane];
    float gv = gbuf[idx];
    val *= gv / (1.f + expf(-gv));
    unsigned short h, lo;
    split2(val, h, lo);
    size_t ro = (size_t)l * (3 * KD_) + bi;
    og2[ro]           = h;
    og2[ro + KD_]     = lo;
    og2[ro + 2 * KD_] = h;
}

// ---------------------------------------------------------------------------
extern "C" void kernel_launch(void* const* d_in, const int* in_sizes, int n_in,
                              void* d_out, int out_size, void* d_ws, size_t ws_size,
                              hipStream_t stream)
{
    const float* x    = (const float*)d_in[0];
    const float* Wq   = (const float*)d_in[1];
    const float* Wk   = (const float*)d_in[2];
    const float* Wv   = (const float*)d_in[3];
    const float* Wqa  = (const float*)d_in[4];
    const float* Wqb  = (const float*)d_in[5];
    const float* Wka  = (const float*)d_in[6];
    const float* Wkb  = (const float*)d_in[7];
    const float* Wg1a = (const float*)d_in[8];
    const float* Wg1b = (const float*)d_in[9];
    const float* bg1  = (const float*)d_in[10];
    const float* Wg2a = (const float*)d_in[11];
    const float* Wg2b = (const float*)d_in[12];
    const float* bg2  = (const float*)d_in[13];
    const float* We   = (const float*)d_in[14];
    const float* Wga  = (const float*)d_in[15];
    const float* Wgb  = (const float*)d_in[16];
    const float* normw= (const float*)d_in[17];
    const float* Wo   = (const float*)d_in[18];

    float* ws = (float*)d_ws;
    const size_t LKD = (size_t)LL * KD_;   // 2M floats
    float* q1   = ws;
    float* k1   = q1 + LKD;
    float* v    = k1 + LKD;
    float* q2   = v  + LKD;
    float* k2   = q2 + LKD;
    float* gk1  = k2 + LKD;
    float* gk2  = gk1 + LKD;
    float* o_acc= gk2 + LKD;
    float* tqa  = o_acc + LKD;                 // 4096*64 f32
    float* tka  = tqa + (size_t)LL * 64;
    float* tga  = tka + (size_t)LL * 64;
    float* tg1  = tga + (size_t)LL * 64;       // 4096*16
    float* tg2  = tg1 + (size_t)LL * 16;
    float* elog = tg2 + (size_t)LL * 16;       // 4096*4
    float* rw   = elog + (size_t)LL * 4;
    float* kv_all    = rw + (size_t)LL * 4;                    // 10.49M f32
    float* decay_all = kv_all + (size_t)64 * 8 * 5 * 64 * 64;  // 163840 f32

    unsigned short* bp = (unsigned short*)(decay_all + 163840);
    unsigned short* WqT2  = bp; bp += (size_t)512 * 3072;
    unsigned short* WkT2  = bp; bp += (size_t)512 * 3072;
    unsigned short* WvT2  = bp; bp += (size_t)512 * 3072;
    unsigned short* WoT2  = bp; bp += (size_t)1024 * 1536;
    unsigned short* WqbT2 = bp; bp += (size_t)512 * 192;
    unsigned short* WkbT2 = bp; bp += (size_t)512 * 192;
    unsigned short* WgbT2 = bp; bp += (size_t)512 * 192;
    unsigned short* tqab2 = bp; bp += (size_t)LL * 192;
    unsigned short* tkab2 = bp; bp += (size_t)LL * 192;
    unsigned short* tgab2 = bp; bp += (size_t)LL * 192;

    // time-multiplexed aliases of kv_all (disjoint lifetimes):
    unsigned short* xb2 = (unsigned short*)kv_all;   // [4096][3072]; dead before gla_intra
    unsigned short* og2 = (unsigned short*)kv_all;   // [4096][1536]; live after gla_inter
    float* gbuf = k1;                                // reuse after GLA

    dim3 blk(256);
    dim3 tblk(32, 8);

    // ---- split conversions ----
    cvt_splitA<<<dim3((LL * 1024 + 255) / 256), blk, 0, stream>>>(x, xb2, LL * 1024, 10);
    cvtT_split<<<dim3(16, 32), tblk, 0, stream>>>(Wq, WqT2, 1024, 512);
    cvtT_split<<<dim3(16, 32), tblk, 0, stream>>>(Wk, WkT2, 1024, 512);
    cvtT_split<<<dim3(16, 32), tblk, 0, stream>>>(Wv, WvT2, 1024, 512);
    cvtT_split<<<dim3(32, 16), tblk, 0, stream>>>(Wo, WoT2, 512, 1024);
    cvtT_split<<<dim3(16, 2),  tblk, 0, stream>>>(Wqb, WqbT2, 64, 512);
    cvtT_split<<<dim3(16, 2),  tblk, 0, stream>>>(Wkb, WkbT2, 64, 512);
    cvtT_split<<<dim3(16, 2),  tblk, 0, stream>>>(Wgb, WgbT2, 64, 512);

    hipMemsetAsync(o_acc, 0, LKD * sizeof(float), stream);

    // ---- QKV (split MFMA, K'=3072, fused) ----
    gemm_mfma<<<dim3(4, 32, 3), blk, 0, stream>>>(xb2, xb2, xb2, WqT2, WkT2, WvT2,
                                                  q1, k1, v, LL, KD_, 3072);

    // ---- LoRA-a / gate-a / router (f32, fused) ----
    gemm64f<<<dim3(1, 64, 3), blk, 0, stream>>>(x, x, x, Wqa, Wka, Wga,
                                                tqa, tka, tga, LL, 64, 1024);
    gemm64f<<<dim3(1, 64, 2), blk, 0, stream>>>(x, x, x, Wg1a, Wg2a, Wg2a,
                                                tg1, tg2, tg2, LL, 16, 1024);
    gemm64f<<<dim3(1, 64, 1), blk, 0, stream>>>(x, x, x, We, We, We,
                                                elog, elog, elog, LL, 4, 1024);

    // ---- split LoRA intermediates ----
    cvt_splitA<<<dim3((LL * 64 + 255) / 256), blk, 0, stream>>>(tqa, tqab2, LL * 64, 6);
    cvt_splitA<<<dim3((LL * 64 + 255) / 256), blk, 0, stream>>>(tka, tkab2, LL * 64, 6);
    cvt_splitA<<<dim3((LL * 64 + 255) / 256), blk, 0, stream>>>(tga, tgab2, LL * 64, 6);

    // ---- LoRA-b q2,k2 (split MFMA, K'=192) ----
    gemm_mfma<<<dim3(4, 32, 2), blk, 0, stream>>>(tqab2, tkab2, tkab2, WqbT2, WkbT2, WkbT2,
                                                  q2, k2, k2, LL, KD_, 192);
    // ---- gate-b (f32, K=16, fused z=2) ----
    gemm128b<<<dim3(4, 32, 2), blk, 0, stream>>>(tg1, tg2, Wg1b, Wg2b, gk1, gk2, LL, KD_, 16);

    elementwise_pre<<<LL, 512, 0, stream>>>(q1, q2, k2, gk1, gk2, bg1, bg2, elog, rw);

    gla_intra<<<dim3(64, 8, 5), blk, 0, stream>>>(q1, k1, v, gk1, q2, k2, gk2, rw,
                                                  o_acc, kv_all, decay_all);
    gla_state_scan<<<dim3(640), blk, 0, stream>>>(kv_all, decay_all);
    gla_inter<<<dim3(64, 8, 5), blk, 0, stream>>>(q1, q2, gk1, gk2, rw, kv_all, o_acc);

    // ---- gating projection (split MFMA) ----
    gemm_mfma<<<dim3(4, 32, 1), blk, 0, stream>>>(tgab2, tgab2, tgab2, WgbT2, WgbT2, WgbT2,
                                                  gbuf, gbuf, gbuf, LL, KD_, 192);

    postnorm<<<LL, 512, 0, stream>>>(o_acc, gbuf, normw, og2);

    // ---- output projection (split MFMA, K'=1536) ----
    gemm_mfma<<<dim3(8, 32, 1), blk, 0, stream>>>(og2, og2, og2, WoT2, WoT2, WoT2,
                                                  (float*)d_out, (float*)d_out, (float*)d_out,
                                                  LL, 1024, 1536);
}

// Round 6
// 701.846 us; speedup vs baseline: 4.0512x; 1.1253x over previous
//
#include <hip/hip_runtime.h>
#include <math.h>

#define LL   4096
#define HH   8
#define DK_  64
#define DV_  64
#define KD_  512
#define NEXP 4

typedef __attribute__((ext_vector_type(8))) short  s16x8;
typedef __attribute__((ext_vector_type(4))) float  f32x4;

__device__ __forceinline__ float f4c(const float4& v, int i) {
    return i == 0 ? v.x : i == 1 ? v.y : i == 2 ? v.z : v.w;
}

__device__ __forceinline__ unsigned short f2bf(float f) {   // RNE f32->bf16
    unsigned u = __float_as_uint(f);
    u += 0x7FFFu + ((u >> 16) & 1u);
    return (unsigned short)(u >> 16);
}

__device__ __forceinline__ void split2(float v, unsigned short& h, unsigned short& l) {
    h = f2bf(v);
    float hf = __uint_as_float((unsigned)h << 16);
    l = f2bf(v - hf);
}

// ---------------------------------------------------------------------------
// f32 [M][K] -> split-bf16 A layout [M][3K] = [hi | lo | hi]. K = 2^kshift.
// ---------------------------------------------------------------------------
__global__ void cvt_splitA(const float* __restrict__ in, unsigned short* __restrict__ out,
                           int n, int kshift)
{
    int i = blockIdx.x * 256 + threadIdx.x;
    if (i >= n) return;
    unsigned short h, l;
    split2(in[i], h, l);
    int K = 1 << kshift;
    int m = i >> kshift, k = i & (K - 1);
    size_t ro = (size_t)m * 3 * K;
    out[ro + k]         = h;
    out[ro + K + k]     = l;
    out[ro + 2 * K + k] = h;
}

// ---------------------------------------------------------------------------
// f32 [K][N] -> split-bf16 B layout [N][3K] = [hi | hi | lo] (transposed).
// Grid (N/32, K/32), block (32,8).
// ---------------------------------------------------------------------------
__global__ void cvtT_split(const float* __restrict__ W, unsigned short* __restrict__ WT,
                           int K, int N)
{
    __shared__ float t[32][33];
    int bx = blockIdx.x * 32;   // n
    int by = blockIdx.y * 32;   // k
    int x = threadIdx.x, y = threadIdx.y;
    #pragma unroll
    for (int i = 0; i < 4; ++i)
        t[y + 8 * i][x] = W[(size_t)(by + y + 8 * i) * N + bx + x];
    __syncthreads();
    #pragma unroll
    for (int i = 0; i < 4; ++i) {
        unsigned short h, l;
        split2(t[x][y + 8 * i], h, l);
        size_t ro = (size_t)(bx + y + 8 * i) * 3 * K + (by + x);
        WT[ro]         = h;
        WT[ro + K]     = h;
        WT[ro + 2 * K] = l;
    }
}

// ---------------------------------------------------------------------------
// bf16 MFMA GEMM: C[M][N]f32 = A[M][K']bf16 @ Bt[N][K']bf16^T.
// 128x128 tile, BK=64, 4 waves, 16x16x32 MFMA, global_load_lds w16 + XOR swizzle.
// Split layouts (A=[hi|lo|hi], B=[hi|hi|lo], K'=3K) -> f32-accurate product.
// ---------------------------------------------------------------------------
__global__ __launch_bounds__(256) void gemm_mfma(
    const unsigned short* __restrict__ A0, const unsigned short* __restrict__ A1,
    const unsigned short* __restrict__ A2,
    const unsigned short* __restrict__ B0, const unsigned short* __restrict__ B1,
    const unsigned short* __restrict__ B2,
    float* __restrict__ C0, float* __restrict__ C1, float* __restrict__ C2,
    int M, int N, int K)
{
    const unsigned short* A = (blockIdx.z == 0) ? A0 : (blockIdx.z == 1) ? A1 : A2;
    const unsigned short* B = (blockIdx.z == 0) ? B0 : (blockIdx.z == 1) ? B1 : B2;
    float*                C = (blockIdx.z == 0) ? C0 : (blockIdx.z == 1) ? C1 : C2;

    __shared__ __align__(16) unsigned short sm[2 * 128 * 64];
    unsigned short* As = sm;
    unsigned short* Bs = sm + 128 * 64;

    int tid  = threadIdx.x;
    int lane = tid & 63;
    int w    = tid >> 6;
    int m0 = blockIdx.y * 128, n0 = blockIdx.x * 128;
    int wr = w >> 1, wc = w & 1;

    f32x4 acc[4][4];
    #pragma unroll
    for (int i = 0; i < 4; ++i)
        #pragma unroll
        for (int j = 0; j < 4; ++j)
            acc[i][j] = (f32x4){0.f, 0.f, 0.f, 0.f};

    const int srow = (lane >> 3);
    const int scb  = ((lane & 7) * 16) ^ (srow << 4);

    for (int kt = 0; kt < K; kt += 64) {
        __syncthreads();
        #pragma unroll
        for (int q = 0; q < 4; ++q) {
            int r = w * 32 + q * 8 + srow;
            const char* ga = (const char*)A + ((size_t)(m0 + r) * K + kt) * 2 + scb;
            const char* gb = (const char*)B + ((size_t)(n0 + r) * K + kt) * 2 + scb;
            __builtin_amdgcn_global_load_lds(
                (const __attribute__((address_space(1))) void*)ga,
                (__attribute__((address_space(3))) void*)((char*)As + (w * 32 + q * 8) * 128),
                16, 0, 0);
            __builtin_amdgcn_global_load_lds(
                (const __attribute__((address_space(1))) void*)gb,
                (__attribute__((address_space(3))) void*)((char*)Bs + (w * 32 + q * 8) * 128),
                16, 0, 0);
        }
        __syncthreads();

        #pragma unroll
        for (int kk = 0; kk < 2; ++kk) {
            int kb = kk * 64 + (lane >> 4) * 16;
            s16x8 af[4], bfr[4];
            #pragma unroll
            for (int mi = 0; mi < 4; ++mi) {
                int r = wr * 64 + mi * 16 + (lane & 15);
                af[mi] = *(const s16x8*)((const char*)As + r * 128 + (kb ^ ((r & 7) << 4)));
            }
            #pragma unroll
            for (int ni = 0; ni < 4; ++ni) {
                int r = wc * 64 + ni * 16 + (lane & 15);
                bfr[ni] = *(const s16x8*)((const char*)Bs + r * 128 + (kb ^ ((r & 7) << 4)));
            }
            #pragma unroll
            for (int mi = 0; mi < 4; ++mi)
                #pragma unroll
                for (int ni = 0; ni < 4; ++ni)
                    acc[mi][ni] = __builtin_amdgcn_mfma_f32_16x16x32_bf16(
                        af[mi], bfr[ni], acc[mi][ni], 0, 0, 0);
        }
    }

    #pragma unroll
    for (int mi = 0; mi < 4; ++mi)
        #pragma unroll
        for (int ni = 0; ni < 4; ++ni) {
            int col = n0 + wc * 64 + ni * 16 + (lane & 15);
            int rb  = m0 + wr * 64 + mi * 16 + (lane >> 4) * 4;
            #pragma unroll
            for (int j = 0; j < 4; ++j)
                C[(size_t)(rb + j) * N + col] = acc[mi][ni][j];
        }
}

// ---------------------------------------------------------------------------
// Small-N f32 GEMM (64x64 tile), 6-way fused over blockIdx.z; A = x for all.
// z: 0..2 -> N=64 (Wqa,Wka,Wga); 3..4 -> N=16 (Wg1a,Wg2a); 5 -> N=4 (We).
// ---------------------------------------------------------------------------
__global__ void gemm64x(const float* __restrict__ A,
                        const float* __restrict__ B0, const float* __restrict__ B1,
                        const float* __restrict__ B2, const float* __restrict__ B3,
                        const float* __restrict__ B4, const float* __restrict__ B5,
                        float* __restrict__ C0, float* __restrict__ C1,
                        float* __restrict__ C2, float* __restrict__ C3,
                        float* __restrict__ C4, float* __restrict__ C5,
                        int M, int K)
{
    int z = blockIdx.z;
    const float* B = (z == 0) ? B0 : (z == 1) ? B1 : (z == 2) ? B2 :
                     (z == 3) ? B3 : (z == 4) ? B4 : B5;
    float*       C = (z == 0) ? C0 : (z == 1) ? C1 : (z == 2) ? C2 :
                     (z == 3) ? C3 : (z == 4) ? C4 : C5;
    int N = (z < 3) ? 64 : (z < 5) ? 16 : 4;

    __shared__ float As[16][65];
    __shared__ float Bs[16][65];
    int tid = threadIdx.x;
    int m0 = blockIdx.y * 64;
    int tx = tid & 15, ty = tid >> 4;
    float acc[4][4] = {};
    for (int k0 = 0; k0 < K; k0 += 16) {
        {
            int row = tid >> 2, q4 = tid & 3;
            const float4 a = *reinterpret_cast<const float4*>(&A[(size_t)(m0 + row) * K + k0 + q4 * 4]);
            As[q4 * 4 + 0][row] = a.x;
            As[q4 * 4 + 1][row] = a.y;
            As[q4 * 4 + 2][row] = a.z;
            As[q4 * 4 + 3][row] = a.w;
        }
        #pragma unroll
        for (int j = 0; j < 4; ++j) {
            int lin = tid * 4 + j;
            int kr = lin >> 6, cc = lin & 63;
            Bs[kr][cc] = (cc < N) ? B[(size_t)(k0 + kr) * N + cc] : 0.f;
        }
        __syncthreads();
        #pragma unroll
        for (int k = 0; k < 16; ++k) {
            float av[4], bv[4];
            #pragma unroll
            for (int i = 0; i < 4; ++i) av[i] = As[k][ty * 4 + i];
            #pragma unroll
            for (int j = 0; j < 4; ++j) bv[j] = Bs[k][tx * 4 + j];
            #pragma unroll
            for (int i = 0; i < 4; ++i)
                #pragma unroll
                for (int j = 0; j < 4; ++j)
                    acc[i][j] = fmaf(av[i], bv[j], acc[i][j]);
        }
        __syncthreads();
    }
    #pragma unroll
    for (int i = 0; i < 4; ++i) {
        int m = m0 + ty * 4 + i;
        #pragma unroll
        for (int j = 0; j < 4; ++j) {
            int n = tx * 4 + j;
            if (n < N) C[(size_t)m * N + n] = acc[i][j];
        }
    }
}

// ---------------------------------------------------------------------------
// 128x128 f32 GEMM, fused over z (2 A/B/C triples) — used for gate-b (K=16).
// ---------------------------------------------------------------------------
__global__ void gemm128b(const float* __restrict__ A0, const float* __restrict__ A1,
                         const float* __restrict__ B0, const float* __restrict__ B1,
                         float* __restrict__ C0, float* __restrict__ C1,
                         int M, int N, int K)
{
    const float* A = (blockIdx.z == 0) ? A0 : A1;
    const float* B = (blockIdx.z == 0) ? B0 : B1;
    float*       C = (blockIdx.z == 0) ? C0 : C1;

    __shared__ float As[16][132];
    __shared__ float Bs[16][132];
    int tid = threadIdx.x;
    int n0 = blockIdx.x * 128;
    int m0 = blockIdx.y * 128;
    int tx = tid & 15, ty = tid >> 4;
    float acc[8][8] = {};

    for (int k0 = 0; k0 < K; k0 += 16) {
        #pragma unroll
        for (int u = 0; u < 2; ++u) {
            int lin = tid + (u << 8);
            int row = lin >> 2, q4 = lin & 3;
            float4 a = *reinterpret_cast<const float4*>(&A[(size_t)(m0 + row) * K + k0 + q4 * 4]);
            As[q4 * 4 + 0][row] = a.x;
            As[q4 * 4 + 1][row] = a.y;
            As[q4 * 4 + 2][row] = a.z;
            As[q4 * 4 + 3][row] = a.w;
        }
        #pragma unroll
        for (int u = 0; u < 2; ++u) {
            int lin = tid + (u << 8);
            int kr = lin >> 5, c4 = lin & 31;
            *reinterpret_cast<float4*>(&Bs[kr][c4 * 4]) =
                *reinterpret_cast<const float4*>(&B[(size_t)(k0 + kr) * N + n0 + c4 * 4]);
        }
        __syncthreads();
        #pragma unroll
        for (int k = 0; k < 16; ++k) {
            float4 a0 = *(const float4*)&As[k][ty * 4];
            float4 a1 = *(const float4*)&As[k][64 + ty * 4];
            float4 b0 = *(const float4*)&Bs[k][tx * 4];
            float4 b1 = *(const float4*)&Bs[k][64 + tx * 4];
            float av[8] = {a0.x, a0.y, a0.z, a0.w, a1.x, a1.y, a1.z, a1.w};
            float bv[8] = {b0.x, b0.y, b0.z, b0.w, b1.x, b1.y, b1.z, b1.w};
            #pragma unroll
            for (int i = 0; i < 8; ++i)
                #pragma unroll
                for (int j = 0; j < 8; ++j)
                    acc[i][j] = fmaf(av[i], bv[j], acc[i][j]);
        }
        __syncthreads();
    }
    #pragma unroll
    for (int i = 0; i < 8; ++i) {
        int m = m0 + ((i < 4) ? ty * 4 + i : 64 + ty * 4 + (i - 4));
        float4 c0 = make_float4(acc[i][0], acc[i][1], acc[i][2], acc[i][3]);
        float4 c1 = make_float4(acc[i][4], acc[i][5], acc[i][6], acc[i][7]);
        *reinterpret_cast<float4*>(&C[(size_t)m * N + n0 + tx * 4]) = c0;
        *reinterpret_cast<float4*>(&C[(size_t)m * N + n0 + 64 + tx * 4]) = c1;
    }
}

// ---------------------------------------------------------------------------
__device__ inline float logsig(float x) {
    return fminf(x, 0.f) - log1pf(expf(-fabsf(x)));
}

__global__ void elementwise_pre(float* __restrict__ q1, float* __restrict__ q2,
                                float* __restrict__ k2, float* __restrict__ gk1,
                                float* __restrict__ gk2,
                                const float* __restrict__ bg1, const float* __restrict__ bg2,
                                const float* __restrict__ elog, float* __restrict__ rw)
{
    int l = blockIdx.x;
    int tid = threadIdx.x;
    int w = tid >> 6, lane = tid & 63;
    int idx = l * KD_ + (w << 6) + lane;

    q1[idx] *= 0.125f;
    q2[idx] *= 0.125f;

    float kv = k2[idx];
    float m = kv;
    for (int s = 32; s >= 1; s >>= 1) m = fmaxf(m, __shfl_xor(m, s, 64));
    float ev = expf(kv - m);
    float ssum = ev;
    for (int s = 32; s >= 1; s >>= 1) ssum += __shfl_xor(ssum, s, 64);
    k2[idx] = ev / ssum;

    int bi = (w << 6) + lane;
    gk1[idx] = logsig(gk1[idx] + bg1[bi]) * (1.f / 16.f);
    gk2[idx] = logsig(gk2[idx] + bg2[bi]) * (1.f / 16.f);

    if (tid == 0) {
        float xs[4];
        float mm = -1e30f;
        for (int j = 0; j < 4; ++j) { xs[j] = elog[l * 4 + j]; mm = fmaxf(mm, xs[j]); }
        float s4 = 0.f;
        for (int j = 0; j < 4; ++j) { xs[j] = expf(xs[j] - mm); s4 += xs[j]; }
        for (int j = 0; j < 4; ++j) xs[j] /= s4;
        int arg = 0; float best = xs[0];
        for (int j = 1; j < 4; ++j) if (xs[j] > best) { best = xs[j]; arg = j; }
        for (int j = 0; j < 4; ++j) rw[l * 4 + j] = (j == arg) ? xs[j] : 0.f;
    }
}

// ---------------------------------------------------------------------------
// GLA intra-chunk + per-chunk state, ALL 5 PASSES per block. Block = (c,h).
// o accumulated in registers across passes -> single plain store (no atomics).
// kg stored transposed [d][t] so all float4 LDS reads are 2-way (free).
// ---------------------------------------------------------------------------
__global__ void gla_intra(const float* __restrict__ q1, const float* __restrict__ k1,
                          const float* __restrict__ v,  const float* __restrict__ gk1,
                          const float* __restrict__ q2, const float* __restrict__ k2,
                          const float* __restrict__ gk2, const float* __restrict__ rw,
                          float* __restrict__ o_acc, float* __restrict__ kv_all,
                          float* __restrict__ decay_all)
{
    int c = blockIdx.x, h = blockIdx.y;

    __shared__ float bufA[64][68];   // qg -> later v
    __shared__ float bufB[64][68];   // kg TRANSPOSED: [d][t]
    __shared__ float bufC[64][68];   // gk -> g -> A[t][s]
    __shared__ float glast[64];
    __shared__ float wrow[64];
    __shared__ float segsum[4][64];

    int tid = threadIdx.x;
    int tx = tid & 15, ty = tid >> 4;
    int t0 = ty * 4, e0 = tx * 4;

    float acc_o[4][4] = {};          // persistent across the 5 passes

    for (int p = 0; p < 5; ++p) {
        const float* qp = (p == 0) ? q1 : q2;
        const float* kp = (p == 0) ? k1 : k2;
        const float* gp = (p == 0) ? gk1 : gk2;

        __syncthreads();             // prior pass finished reading LDS

        if (tid < 64) {
            int lg = c * 64 + tid;
            wrow[tid] = (p == 0) ? 1.f : rw[lg * 4 + (p - 1)];
        }
        __syncthreads();

        #pragma unroll
        for (int i = 0; i < 16; ++i) {      // masked gk tile -> bufC
            int idx = tid + (i << 8);
            int t = idx >> 6, d = idx & 63;
            float xg = gp[(size_t)(c * 64 + t) * KD_ + (h << 6) + d];
            if (p > 0 && !(wrow[t] > 0.f)) xg = 0.f;
            bufC[t][d] = xg;
        }
        __syncthreads();

        {   // segmented cumsum along t per dim d
            int d = tid & 63, seg = tid >> 6;
            int tb = seg * 16;
            float s = 0.f;
            for (int t = tb; t < tb + 16; ++t) { s += bufC[t][d]; bufC[t][d] = s; }
            segsum[seg][d] = s;
            __syncthreads();
            float off = 0.f;
            for (int ss = 0; ss < seg; ++ss) off += segsum[ss][d];
            if (seg) for (int t = tb; t < tb + 16; ++t) bufC[t][d] += off;
            if (seg == 3) glast[d] = off + s;
        }
        __syncthreads();

        #pragma unroll
        for (int i = 0; i < 16; ++i) {      // qg -> bufA[t][d], kg -> bufB[d][t]
            int idx = tid + (i << 8);
            int t = idx >> 6, d = idx & 63;
            int l = c * 64 + t;
            float wv = wrow[t];
            float g = bufC[t][d];
            bufA[t][d] = qp[(size_t)l * KD_ + (h << 6) + d] * wv * expf(g);
            bufB[d][t] = kp[(size_t)l * KD_ + (h << 6) + d] * wv * expf(-g);
        }
        __syncthreads();

        {   // A[t][s] = tril dot_d(qg[t], kg[s]) -> bufC
            if (e0 <= t0 + 3) {             // e0 plays s0 here
                float acc[4][4] = {};
                for (int d0 = 0; d0 < 64; d0 += 4) {
                    float4 a[4];
                    #pragma unroll
                    for (int i = 0; i < 4; ++i) a[i] = *(const float4*)&bufA[t0 + i][d0];
                    #pragma unroll
                    for (int dd = 0; dd < 4; ++dd) {
                        float4 bv = *(const float4*)&bufB[d0 + dd][e0];
                        #pragma unroll
                        for (int i = 0; i < 4; ++i) {
                            float aa = f4c(a[i], dd);
                            acc[i][0] = fmaf(aa, bv.x, acc[i][0]);
                            acc[i][1] = fmaf(aa, bv.y, acc[i][1]);
                            acc[i][2] = fmaf(aa, bv.z, acc[i][2]);
                            acc[i][3] = fmaf(aa, bv.w, acc[i][3]);
                        }
                    }
                }
                #pragma unroll
                for (int i = 0; i < 4; ++i)
                    #pragma unroll
                    for (int j = 0; j < 4; ++j)
                        bufC[t0 + i][e0 + j] = (e0 + j <= t0 + i) ? acc[i][j] : 0.f;
            }
        }
        __syncthreads();

        #pragma unroll
        for (int i = 0; i < 16; ++i) {      // v tile -> bufA (qg dead)
            int idx = tid + (i << 8);
            int t = idx >> 6, d = idx & 63;
            bufA[t][d] = v[(size_t)(c * 64 + t) * KD_ + (h << 6) + d];
        }
        __syncthreads();

        {   // o_intra[t][e] += sum_{s<=t} A[t][s] v[s][e]  (register accumulate)
            for (int s0 = 0; s0 <= t0 + 3; s0 += 4) {
                float4 a[4];
                #pragma unroll
                for (int i = 0; i < 4; ++i) a[i] = *(const float4*)&bufC[t0 + i][s0];
                #pragma unroll
                for (int ss = 0; ss < 4; ++ss) {
                    float4 vv = *(const float4*)&bufA[s0 + ss][e0];
                    #pragma unroll
                    for (int i = 0; i < 4; ++i) {
                        float aa = f4c(a[i], ss);
                        acc_o[i][0] = fmaf(aa, vv.x, acc_o[i][0]);
                        acc_o[i][1] = fmaf(aa, vv.y, acc_o[i][1]);
                        acc_o[i][2] = fmaf(aa, vv.z, acc_o[i][2]);
                        acc_o[i][3] = fmaf(aa, vv.w, acc_o[i][3]);
                    }
                }
            }
        }

        {   // chunk_kv[d][e] = exp(glast[d]) * sum_t kg[t][d] v[t][e]
            float acc[4][4] = {};
            for (int t0v = 0; t0v < 64; t0v += 4) {
                float4 kk[4];
                #pragma unroll
                for (int i = 0; i < 4; ++i) kk[i] = *(const float4*)&bufB[ty + 16 * i][t0v];
                #pragma unroll
                for (int ss = 0; ss < 4; ++ss) {
                    float4 vv = *(const float4*)&bufA[t0v + ss][e0];
                    #pragma unroll
                    for (int i = 0; i < 4; ++i) {
                        float ki = f4c(kk[i], ss);
                        acc[i][0] = fmaf(ki, vv.x, acc[i][0]);
                        acc[i][1] = fmaf(ki, vv.y, acc[i][1]);
                        acc[i][2] = fmaf(ki, vv.z, acc[i][2]);
                        acc[i][3] = fmaf(ki, vv.w, acc[i][3]);
                    }
                }
            }
            size_t base = (size_t)((c * 8 + h) * 5 + p) * 4096;
            #pragma unroll
            for (int i = 0; i < 4; ++i) {
                int d = ty + 16 * i;
                float dec = expf(glast[d]);
                #pragma unroll
                for (int j = 0; j < 4; ++j)
                    kv_all[base + d * 64 + e0 + j] = acc[i][j] * dec;
            }
            if (tid < 64) decay_all[(size_t)((c * 8 + h) * 5 + p) * 64 + tid] = expf(glast[tid]);
        }
    }

    // single plain store of the summed intra output
    #pragma unroll
    for (int i = 0; i < 4; ++i)
        #pragma unroll
        for (int j = 0; j < 4; ++j)
            o_acc[(size_t)(c * 64 + t0 + i) * KD_ + (h << 6) + e0 + j] = acc_o[i][j];
}

// ---------------------------------------------------------------------------
__global__ void gla_state_scan(float* __restrict__ kv, const float* __restrict__ decay)
{
    int gid = blockIdx.x * 256 + threadIdx.x;
    int sub = gid >> 6;
    const size_t stride = 8 * 5 * 64 * 64;
    float S = 0.f;
    float kvv = kv[gid];
    for (int c = 0; c < 64; ++c) {
        size_t o = (size_t)c * stride + gid;
        float nxt = (c < 63) ? kv[o + stride] : 0.f;
        float dec = decay[c * 2560 + sub];
        kv[o] = S;
        S = fmaf(dec, S, kvv);
        kvv = nxt;
    }
}

// ---------------------------------------------------------------------------
// Inter-chunk output, ALL 5 PASSES per block. Block = (c,h).
// Accumulates in registers, then o_acc += acc (plain read-modify-write;
// this block exclusively owns its (c,h) tile).
// ---------------------------------------------------------------------------
__global__ void gla_inter(const float* __restrict__ q1, const float* __restrict__ q2,
                          const float* __restrict__ gk1, const float* __restrict__ gk2,
                          const float* __restrict__ rw, const float* __restrict__ Spre,
                          float* __restrict__ o_acc)
{
    int c = blockIdx.x, h = blockIdx.y;

    __shared__ float bufQ[64][68];
    __shared__ float bufS[64][68];
    __shared__ float wrow[64];
    __shared__ float segsum[4][64];

    int tid = threadIdx.x;
    int tx = tid & 15, ty = tid >> 4;
    int t0 = ty * 4, e0 = tx * 4;

    float acc_o[4][4] = {};

    for (int p = 0; p < 5; ++p) {
        const float* qp = (p == 0) ? q1 : q2;
        const float* gp = (p == 0) ? gk1 : gk2;

        __syncthreads();

        if (tid < 64) {
            int lg = c * 64 + tid;
            wrow[tid] = (p == 0) ? 1.f : rw[lg * 4 + (p - 1)];
        }
        __syncthreads();

        #pragma unroll
        for (int i = 0; i < 16; ++i) {
            int idx = tid + (i << 8);
            int t = idx >> 6, d = idx & 63;
            float xg = gp[(size_t)(c * 64 + t) * KD_ + (h << 6) + d];
            if (p > 0 && !(wrow[t] > 0.f)) xg = 0.f;
            bufQ[t][d] = xg;
        }
        size_t sbase = (size_t)((c * 8 + h) * 5 + p) * 4096;
        #pragma unroll
        for (int i = 0; i < 16; ++i) {
            int idx = tid + (i << 8);
            bufS[idx >> 6][idx & 63] = Spre[sbase + idx];
        }
        __syncthreads();

        {   // segmented cumsum
            int d = tid & 63, seg = tid >> 6;
            int tb = seg * 16;
            float s = 0.f;
            for (int t = tb; t < tb + 16; ++t) { s += bufQ[t][d]; bufQ[t][d] = s; }
            segsum[seg][d] = s;
            __syncthreads();
            float off = 0.f;
            for (int ss = 0; ss < seg; ++ss) off += segsum[ss][d];
            if (seg) for (int t = tb; t < tb + 16; ++t) bufQ[t][d] += off;
        }
        __syncthreads();

        #pragma unroll
        for (int i = 0; i < 16; ++i) {      // qg in place
            int idx = tid + (i << 8);
            int t = idx >> 6, d = idx & 63;
            int l = c * 64 + t;
            bufQ[t][d] = qp[(size_t)l * KD_ + (h << 6) + d] * wrow[t] * expf(bufQ[t][d]);
        }
        __syncthreads();

        {   // o_inter[t][e] += sum_d qg[t][d] S[d][e]
            for (int d0 = 0; d0 < 64; d0 += 4) {
                float4 a[4];
                #pragma unroll
                for (int i = 0; i < 4; ++i) a[i] = *(const float4*)&bufQ[t0 + i][d0];
                #pragma unroll
                for (int dd = 0; dd < 4; ++dd) {
                    float4 sv = *(const float4*)&bufS[d0 + dd][e0];
                    #pragma unroll
                    for (int i = 0; i < 4; ++i) {
                        float aa = f4c(a[i], dd);
                        acc_o[i][0] = fmaf(aa, sv.x, acc_o[i][0]);
                        acc_o[i][1] = fmaf(aa, sv.y, acc_o[i][1]);
                        acc_o[i][2] = fmaf(aa, sv.z, acc_o[i][2]);
                        acc_o[i][3] = fmaf(aa, sv.w, acc_o[i][3]);
                    }
                }
            }
        }
    }

    #pragma unroll
    for (int i = 0; i < 4; ++i)
        #pragma unroll
        for (int j = 0; j < 4; ++j) {
            size_t idx = (size_t)(c * 64 + t0 + i) * KD_ + (h << 6) + e0 + j;
            o_acc[idx] += acc_o[i][j];
        }
}

// ---------------------------------------------------------------------------
// Post: RMS-norm, * norm_w, * silu(g); emits split-bf16 A layout [hi|lo|hi].
// ---------------------------------------------------------------------------
__global__ void postnorm(const float* __restrict__ o_acc, const float* __restrict__ gbuf,
                         const float* __restrict__ norm_w, unsigned short* __restrict__ og2)
{
    int l = blockIdx.x;
    int tid = threadIdx.x;
    int w = tid >> 6, lane = tid & 63;
    int bi = (w << 6) + lane;
    int idx = l * KD_ + bi;
    float o = o_acc[idx];
    float ss = o * o;
    for (int s = 32; s >= 1; s >>= 1) ss += __shfl_xor(ss, s, 64);
    float r = rsqrtf(ss * (1.f / 64.f) + 1e-5f);
    float val = o * r * norm_w[lane];
    float gv = gbuf[idx];
    val *= gv / (1.f + expf(-gv));
    unsigned short h, lo;
    split2(val, h, lo);
    size_t ro = (size_t)l * (3 * KD_) + bi;
    og2[ro]           = h;
    og2[ro + KD_]     = lo;
    og2[ro + 2 * KD_] = h;
}

// ---------------------------------------------------------------------------
extern "C" void kernel_launch(void* const* d_in, const int* in_sizes, int n_in,
                              void* d_out, int out_size, void* d_ws, size_t ws_size,
                              hipStream_t stream)
{
    const float* x    = (const float*)d_in[0];
    const float* Wq   = (const float*)d_in[1];
    const float* Wk   = (const float*)d_in[2];
    const float* Wv   = (const float*)d_in[3];
    const float* Wqa  = (const float*)d_in[4];
    const float* Wqb  = (const float*)d_in[5];
    const float* Wka  = (const float*)d_in[6];
    const float* Wkb  = (const float*)d_in[7];
    const float* Wg1a = (const float*)d_in[8];
    const float* Wg1b = (const float*)d_in[9];
    const float* bg1  = (const float*)d_in[10];
    const float* Wg2a = (const float*)d_in[11];
    const float* Wg2b = (const float*)d_in[12];
    const float* bg2  = (const float*)d_in[13];
    const float* We   = (const float*)d_in[14];
    const float* Wga  = (const float*)d_in[15];
    const float* Wgb  = (const float*)d_in[16];
    const float* normw= (const float*)d_in[17];
    const float* Wo   = (const float*)d_in[18];

    float* ws = (float*)d_ws;
    const size_t LKD = (size_t)LL * KD_;   // 2M floats
    float* q1   = ws;
    float* k1   = q1 + LKD;
    float* v    = k1 + LKD;
    float* q2   = v  + LKD;
    float* k2   = q2 + LKD;
    float* gk1  = k2 + LKD;
    float* gk2  = gk1 + LKD;
    float* o_acc= gk2 + LKD;
    float* tqa  = o_acc + LKD;                 // 4096*64 f32
    float* tka  = tqa + (size_t)LL * 64;
    float* tga  = tka + (size_t)LL * 64;
    float* tg1  = tga + (size_t)LL * 64;       // 4096*16
    float* tg2  = tg1 + (size_t)LL * 16;
    float* elog = tg2 + (size_t)LL * 16;       // 4096*4
    float* rw   = elog + (size_t)LL * 4;
    float* kv_all    = rw + (size_t)LL * 4;                    // 10.49M f32
    float* decay_all = kv_all + (size_t)64 * 8 * 5 * 64 * 64;  // 163840 f32

    unsigned short* bp = (unsigned short*)(decay_all + 163840);
    unsigned short* WqT2  = bp; bp += (size_t)512 * 3072;
    unsigned short* WkT2  = bp; bp += (size_t)512 * 3072;
    unsigned short* WvT2  = bp; bp += (size_t)512 * 3072;
    unsigned short* WoT2  = bp; bp += (size_t)1024 * 1536;
    unsigned short* WqbT2 = bp; bp += (size_t)512 * 192;
    unsigned short* WkbT2 = bp; bp += (size_t)512 * 192;
    unsigned short* WgbT2 = bp; bp += (size_t)512 * 192;
    unsigned short* tqab2 = bp; bp += (size_t)LL * 192;
    unsigned short* tkab2 = bp; bp += (size_t)LL * 192;
    unsigned short* tgab2 = bp; bp += (size_t)LL * 192;

    // time-multiplexed aliases of kv_all (disjoint lifetimes):
    unsigned short* xb2 = (unsigned short*)kv_all;   // [4096][3072]; dead before gla_intra
    unsigned short* og2 = (unsigned short*)kv_all;   // [4096][1536]; live after gla_inter
    float* gbuf = k1;                                // reuse after GLA

    dim3 blk(256);
    dim3 tblk(32, 8);

    // ---- split conversions ----
    cvt_splitA<<<dim3((LL * 1024 + 255) / 256), blk, 0, stream>>>(x, xb2, LL * 1024, 10);
    cvtT_split<<<dim3(16, 32), tblk, 0, stream>>>(Wq, WqT2, 1024, 512);
    cvtT_split<<<dim3(16, 32), tblk, 0, stream>>>(Wk, WkT2, 1024, 512);
    cvtT_split<<<dim3(16, 32), tblk, 0, stream>>>(Wv, WvT2, 1024, 512);
    cvtT_split<<<dim3(32, 16), tblk, 0, stream>>>(Wo, WoT2, 512, 1024);
    cvtT_split<<<dim3(16, 2),  tblk, 0, stream>>>(Wqb, WqbT2, 64, 512);
    cvtT_split<<<dim3(16, 2),  tblk, 0, stream>>>(Wkb, WkbT2, 64, 512);
    cvtT_split<<<dim3(16, 2),  tblk, 0, stream>>>(Wgb, WgbT2, 64, 512);

    // ---- QKV (split MFMA, K'=3072, fused) ----
    gemm_mfma<<<dim3(4, 32, 3), blk, 0, stream>>>(xb2, xb2, xb2, WqT2, WkT2, WvT2,
                                                  q1, k1, v, LL, KD_, 3072);

    // ---- LoRA-a / gate-a / router (f32, 6-way fused) ----
    gemm64x<<<dim3(1, 64, 6), blk, 0, stream>>>(x, Wqa, Wka, Wga, Wg1a, Wg2a, We,
                                                tqa, tka, tga, tg1, tg2, elog, LL, 1024);

    // ---- split LoRA intermediates ----
    cvt_splitA<<<dim3((LL * 64 + 255) / 256), blk, 0, stream>>>(tqa, tqab2, LL * 64, 6);
    cvt_splitA<<<dim3((LL * 64 + 255) / 256), blk, 0, stream>>>(tka, tkab2, LL * 64, 6);
    cvt_splitA<<<dim3((LL * 64 + 255) / 256), blk, 0, stream>>>(tga, tgab2, LL * 64, 6);

    // ---- LoRA-b q2,k2 (split MFMA, K'=192) ----
    gemm_mfma<<<dim3(4, 32, 2), blk, 0, stream>>>(tqab2, tkab2, tkab2, WqbT2, WkbT2, WkbT2,
                                                  q2, k2, k2, LL, KD_, 192);
    // ---- gate-b (f32, K=16, fused z=2) ----
    gemm128b<<<dim3(4, 32, 2), blk, 0, stream>>>(tg1, tg2, Wg1b, Wg2b, gk1, gk2, LL, KD_, 16);

    elementwise_pre<<<LL, 512, 0, stream>>>(q1, q2, k2, gk1, gk2, bg1, bg2, elog, rw);

    gla_intra<<<dim3(64, 8), blk, 0, stream>>>(q1, k1, v, gk1, q2, k2, gk2, rw,
                                               o_acc, kv_all, decay_all);
    gla_state_scan<<<dim3(640), blk, 0, stream>>>(kv_all, decay_all);
    gla_inter<<<dim3(64, 8), blk, 0, stream>>>(q1, q2, gk1, gk2, rw, kv_all, o_acc);

    // ---- gating projection (split MFMA; k1 free after GLA) ----
    gemm_mfma<<<dim3(4, 32, 1), blk, 0, stream>>>(tgab2, tgab2, tgab2, WgbT2, WgbT2, WgbT2,
                                                  gbuf, gbuf, gbuf, LL, KD_, 192);

    postnorm<<<LL, 512, 0, stream>>>(o_acc, gbuf, normw, og2);

    // ---- output projection (split MFMA, K'=1536) ----
    gemm_mfma<<<dim3(8, 32, 1), blk, 0, stream>>>(og2, og2, og2, WoT2, WoT2, WoT2,
                                                  (float*)d_out, (float*)d_out, (float*)d_out,
                                                  LL, 1024, 1536);
}

// Round 7
// 472.821 us; speedup vs baseline: 6.0135x; 1.4844x over previous
//
#include <hip/hip_runtime.h>
#include <math.h>

#define LL   4096
#define HH   8
#define DK_  64
#define DV_  64
#define KD_  512
#define NEXP 4

typedef __attribute__((ext_vector_type(8))) short  s16x8;
typedef __attribute__((ext_vector_type(4))) float  f32x4;

__device__ __forceinline__ float f4c(const float4& v, int i) {
    return i == 0 ? v.x : i == 1 ? v.y : i == 2 ? v.z : v.w;
}

__device__ __forceinline__ unsigned short f2bf(float f) {   // RNE f32->bf16
    unsigned u = __float_as_uint(f);
    u += 0x7FFFu + ((u >> 16) & 1u);
    return (unsigned short)(u >> 16);
}

__device__ __forceinline__ void split2(float v, unsigned short& h, unsigned short& l) {
    h = f2bf(v);
    float hf = __uint_as_float((unsigned)h << 16);
    l = f2bf(v - hf);
}

// ---------------------------------------------------------------------------
// f32 [M][K] -> split-bf16 A layout [M][3K] = [hi | lo | hi]. K = 2^kshift.
// ---------------------------------------------------------------------------
__global__ void cvt_splitA(const float* __restrict__ in, unsigned short* __restrict__ out,
                           int n, int kshift)
{
    int i = blockIdx.x * 256 + threadIdx.x;
    if (i >= n) return;
    unsigned short h, l;
    split2(in[i], h, l);
    int K = 1 << kshift;
    int m = i >> kshift, k = i & (K - 1);
    size_t ro = (size_t)m * 3 * K;
    out[ro + k]         = h;
    out[ro + K + k]     = l;
    out[ro + 2 * K + k] = h;
}

// ---------------------------------------------------------------------------
// f32 [K][N] -> split-bf16 B layout [N][3K] = [hi | hi | lo] (transposed).
// ---------------------------------------------------------------------------
__global__ void cvtT_split(const float* __restrict__ W, unsigned short* __restrict__ WT,
                           int K, int N)
{
    __shared__ float t[32][33];
    int bx = blockIdx.x * 32;   // n
    int by = blockIdx.y * 32;   // k
    int x = threadIdx.x, y = threadIdx.y;
    #pragma unroll
    for (int i = 0; i < 4; ++i)
        t[y + 8 * i][x] = W[(size_t)(by + y + 8 * i) * N + bx + x];
    __syncthreads();
    #pragma unroll
    for (int i = 0; i < 4; ++i) {
        unsigned short h, l;
        split2(t[x][y + 8 * i], h, l);
        size_t ro = (size_t)(bx + y + 8 * i) * 3 * K + (by + x);
        WT[ro]         = h;
        WT[ro + K]     = h;
        WT[ro + 2 * K] = l;
    }
}

// ---------------------------------------------------------------------------
// bf16 MFMA GEMM (split-bf16 accurate): 128x128 tile, BK=64, 4 waves.
// ---------------------------------------------------------------------------
__global__ __launch_bounds__(256) void gemm_mfma(
    const unsigned short* __restrict__ A0, const unsigned short* __restrict__ A1,
    const unsigned short* __restrict__ A2,
    const unsigned short* __restrict__ B0, const unsigned short* __restrict__ B1,
    const unsigned short* __restrict__ B2,
    float* __restrict__ C0, float* __restrict__ C1, float* __restrict__ C2,
    int M, int N, int K)
{
    const unsigned short* A = (blockIdx.z == 0) ? A0 : (blockIdx.z == 1) ? A1 : A2;
    const unsigned short* B = (blockIdx.z == 0) ? B0 : (blockIdx.z == 1) ? B1 : B2;
    float*                C = (blockIdx.z == 0) ? C0 : (blockIdx.z == 1) ? C1 : C2;

    __shared__ __align__(16) unsigned short sm[2 * 128 * 64];
    unsigned short* As = sm;
    unsigned short* Bs = sm + 128 * 64;

    int tid  = threadIdx.x;
    int lane = tid & 63;
    int w    = tid >> 6;
    int m0 = blockIdx.y * 128, n0 = blockIdx.x * 128;
    int wr = w >> 1, wc = w & 1;

    f32x4 acc[4][4];
    #pragma unroll
    for (int i = 0; i < 4; ++i)
        #pragma unroll
        for (int j = 0; j < 4; ++j)
            acc[i][j] = (f32x4){0.f, 0.f, 0.f, 0.f};

    const int srow = (lane >> 3);
    const int scb  = ((lane & 7) * 16) ^ (srow << 4);

    for (int kt = 0; kt < K; kt += 64) {
        __syncthreads();
        #pragma unroll
        for (int q = 0; q < 4; ++q) {
            int r = w * 32 + q * 8 + srow;
            const char* ga = (const char*)A + ((size_t)(m0 + r) * K + kt) * 2 + scb;
            const char* gb = (const char*)B + ((size_t)(n0 + r) * K + kt) * 2 + scb;
            __builtin_amdgcn_global_load_lds(
                (const __attribute__((address_space(1))) void*)ga,
                (__attribute__((address_space(3))) void*)((char*)As + (w * 32 + q * 8) * 128),
                16, 0, 0);
            __builtin_amdgcn_global_load_lds(
                (const __attribute__((address_space(1))) void*)gb,
                (__attribute__((address_space(3))) void*)((char*)Bs + (w * 32 + q * 8) * 128),
                16, 0, 0);
        }
        __syncthreads();

        #pragma unroll
        for (int kk = 0; kk < 2; ++kk) {
            int kb = kk * 64 + (lane >> 4) * 16;
            s16x8 af[4], bfr[4];
            #pragma unroll
            for (int mi = 0; mi < 4; ++mi) {
                int r = wr * 64 + mi * 16 + (lane & 15);
                af[mi] = *(const s16x8*)((const char*)As + r * 128 + (kb ^ ((r & 7) << 4)));
            }
            #pragma unroll
            for (int ni = 0; ni < 4; ++ni) {
                int r = wc * 64 + ni * 16 + (lane & 15);
                bfr[ni] = *(const s16x8*)((const char*)Bs + r * 128 + (kb ^ ((r & 7) << 4)));
            }
            #pragma unroll
            for (int mi = 0; mi < 4; ++mi)
                #pragma unroll
                for (int ni = 0; ni < 4; ++ni)
                    acc[mi][ni] = __builtin_amdgcn_mfma_f32_16x16x32_bf16(
                        af[mi], bfr[ni], acc[mi][ni], 0, 0, 0);
        }
    }

    #pragma unroll
    for (int mi = 0; mi < 4; ++mi)
        #pragma unroll
        for (int ni = 0; ni < 4; ++ni) {
            int col = n0 + wc * 64 + ni * 16 + (lane & 15);
            int rb  = m0 + wr * 64 + mi * 16 + (lane >> 4) * 4;
            #pragma unroll
            for (int j = 0; j < 4; ++j)
                C[(size_t)(rb + j) * N + col] = acc[mi][ni][j];
        }
}

// ---------------------------------------------------------------------------
// Small-N f32 GEMM (64x64 tile), 6-way fused over blockIdx.z; A = x for all.
// ---------------------------------------------------------------------------
__global__ void gemm64x(const float* __restrict__ A,
                        const float* __restrict__ B0, const float* __restrict__ B1,
                        const float* __restrict__ B2, const float* __restrict__ B3,
                        const float* __restrict__ B4, const float* __restrict__ B5,
                        float* __restrict__ C0, float* __restrict__ C1,
                        float* __restrict__ C2, float* __restrict__ C3,
                        float* __restrict__ C4, float* __restrict__ C5,
                        int M, int K)
{
    int z = blockIdx.z;
    const float* B = (z == 0) ? B0 : (z == 1) ? B1 : (z == 2) ? B2 :
                     (z == 3) ? B3 : (z == 4) ? B4 : B5;
    float*       C = (z == 0) ? C0 : (z == 1) ? C1 : (z == 2) ? C2 :
                     (z == 3) ? C3 : (z == 4) ? C4 : C5;
    int N = (z < 3) ? 64 : (z < 5) ? 16 : 4;

    __shared__ float As[16][65];
    __shared__ float Bs[16][65];
    int tid = threadIdx.x;
    int m0 = blockIdx.y * 64;
    int tx = tid & 15, ty = tid >> 4;
    float acc[4][4] = {};
    for (int k0 = 0; k0 < K; k0 += 16) {
        {
            int row = tid >> 2, q4 = tid & 3;
            const float4 a = *reinterpret_cast<const float4*>(&A[(size_t)(m0 + row) * K + k0 + q4 * 4]);
            As[q4 * 4 + 0][row] = a.x;
            As[q4 * 4 + 1][row] = a.y;
            As[q4 * 4 + 2][row] = a.z;
            As[q4 * 4 + 3][row] = a.w;
        }
        #pragma unroll
        for (int j = 0; j < 4; ++j) {
            int lin = tid * 4 + j;
            int kr = lin >> 6, cc = lin & 63;
            Bs[kr][cc] = (cc < N) ? B[(size_t)(k0 + kr) * N + cc] : 0.f;
        }
        __syncthreads();
        #pragma unroll
        for (int k = 0; k < 16; ++k) {
            float av[4], bv[4];
            #pragma unroll
            for (int i = 0; i < 4; ++i) av[i] = As[k][ty * 4 + i];
            #pragma unroll
            for (int j = 0; j < 4; ++j) bv[j] = Bs[k][tx * 4 + j];
            #pragma unroll
            for (int i = 0; i < 4; ++i)
                #pragma unroll
                for (int j = 0; j < 4; ++j)
                    acc[i][j] = fmaf(av[i], bv[j], acc[i][j]);
        }
        __syncthreads();
    }
    #pragma unroll
    for (int i = 0; i < 4; ++i) {
        int m = m0 + ty * 4 + i;
        #pragma unroll
        for (int j = 0; j < 4; ++j) {
            int n = tx * 4 + j;
            if (n < N) C[(size_t)m * N + n] = acc[i][j];
        }
    }
}

// ---------------------------------------------------------------------------
// 128x128 f32 GEMM, fused over z (2 triples) — gate-b (K=16).
// ---------------------------------------------------------------------------
__global__ void gemm128b(const float* __restrict__ A0, const float* __restrict__ A1,
                         const float* __restrict__ B0, const float* __restrict__ B1,
                         float* __restrict__ C0, float* __restrict__ C1,
                         int M, int N, int K)
{
    const float* A = (blockIdx.z == 0) ? A0 : A1;
    const float* B = (blockIdx.z == 0) ? B0 : B1;
    float*       C = (blockIdx.z == 0) ? C0 : C1;

    __shared__ float As[16][132];
    __shared__ float Bs[16][132];
    int tid = threadIdx.x;
    int n0 = blockIdx.x * 128;
    int m0 = blockIdx.y * 128;
    int tx = tid & 15, ty = tid >> 4;
    float acc[8][8] = {};

    for (int k0 = 0; k0 < K; k0 += 16) {
        #pragma unroll
        for (int u = 0; u < 2; ++u) {
            int lin = tid + (u << 8);
            int row = lin >> 2, q4 = lin & 3;
            float4 a = *reinterpret_cast<const float4*>(&A[(size_t)(m0 + row) * K + k0 + q4 * 4]);
            As[q4 * 4 + 0][row] = a.x;
            As[q4 * 4 + 1][row] = a.y;
            As[q4 * 4 + 2][row] = a.z;
            As[q4 * 4 + 3][row] = a.w;
        }
        #pragma unroll
        for (int u = 0; u < 2; ++u) {
            int lin = tid + (u << 8);
            int kr = lin >> 5, c4 = lin & 31;
            *reinterpret_cast<float4*>(&Bs[kr][c4 * 4]) =
                *reinterpret_cast<const float4*>(&B[(size_t)(k0 + kr) * N + n0 + c4 * 4]);
        }
        __syncthreads();
        #pragma unroll
        for (int k = 0; k < 16; ++k) {
            float4 a0 = *(const float4*)&As[k][ty * 4];
            float4 a1 = *(const float4*)&As[k][64 + ty * 4];
            float4 b0 = *(const float4*)&Bs[k][tx * 4];
            float4 b1 = *(const float4*)&Bs[k][64 + tx * 4];
            float av[8] = {a0.x, a0.y, a0.z, a0.w, a1.x, a1.y, a1.z, a1.w};
            float bv[8] = {b0.x, b0.y, b0.z, b0.w, b1.x, b1.y, b1.z, b1.w};
            #pragma unroll
            for (int i = 0; i < 8; ++i)
                #pragma unroll
                for (int j = 0; j < 8; ++j)
                    acc[i][j] = fmaf(av[i], bv[j], acc[i][j]);
        }
        __syncthreads();
    }
    #pragma unroll
    for (int i = 0; i < 8; ++i) {
        int m = m0 + ((i < 4) ? ty * 4 + i : 64 + ty * 4 + (i - 4));
        float4 c0 = make_float4(acc[i][0], acc[i][1], acc[i][2], acc[i][3]);
        float4 c1 = make_float4(acc[i][4], acc[i][5], acc[i][6], acc[i][7]);
        *reinterpret_cast<float4*>(&C[(size_t)m * N + n0 + tx * 4]) = c0;
        *reinterpret_cast<float4*>(&C[(size_t)m * N + n0 + 64 + tx * 4]) = c1;
    }
}

// ---------------------------------------------------------------------------
__device__ inline float logsig(float x) {
    return fminf(x, 0.f) - log1pf(expf(-fabsf(x)));
}

__global__ void elementwise_pre(float* __restrict__ q1, float* __restrict__ q2,
                                float* __restrict__ k2, float* __restrict__ gk1,
                                float* __restrict__ gk2,
                                const float* __restrict__ bg1, const float* __restrict__ bg2,
                                const float* __restrict__ elog, float* __restrict__ rw)
{
    int l = blockIdx.x;
    int tid = threadIdx.x;
    int w = tid >> 6, lane = tid & 63;
    int idx = l * KD_ + (w << 6) + lane;

    q1[idx] *= 0.125f;
    q2[idx] *= 0.125f;

    float kv = k2[idx];
    float m = kv;
    for (int s = 32; s >= 1; s >>= 1) m = fmaxf(m, __shfl_xor(m, s, 64));
    float ev = expf(kv - m);
    float ssum = ev;
    for (int s = 32; s >= 1; s >>= 1) ssum += __shfl_xor(ssum, s, 64);
    k2[idx] = ev / ssum;

    int bi = (w << 6) + lane;
    gk1[idx] = logsig(gk1[idx] + bg1[bi]) * (1.f / 16.f);
    gk2[idx] = logsig(gk2[idx] + bg2[bi]) * (1.f / 16.f);

    if (tid == 0) {
        float xs[4];
        float mm = -1e30f;
        for (int j = 0; j < 4; ++j) { xs[j] = elog[l * 4 + j]; mm = fmaxf(mm, xs[j]); }
        float s4 = 0.f;
        for (int j = 0; j < 4; ++j) { xs[j] = expf(xs[j] - mm); s4 += xs[j]; }
        for (int j = 0; j < 4; ++j) xs[j] /= s4;
        int arg = 0; float best = xs[0];
        for (int j = 1; j < 4; ++j) if (xs[j] > best) { best = xs[j]; arg = j; }
        for (int j = 0; j < 4; ++j) rw[l * 4 + j] = (j == arg) ? xs[j] : 0.f;
    }
}

// ---------------------------------------------------------------------------
// Phase 1: chunk_kv + decay only. Block = (c,h,p), 2560 blocks.
// chunk_kv[d][e] = exp(glast[d]) * sum_t kg[t][d] v[t][e].
// ---------------------------------------------------------------------------
__global__ void gla_kv(const float* __restrict__ k1, const float* __restrict__ k2,
                       const float* __restrict__ gk1, const float* __restrict__ gk2,
                       const float* __restrict__ v, const float* __restrict__ rw,
                       float* __restrict__ kv_all, float* __restrict__ decay_all)
{
    int c = blockIdx.x, h = blockIdx.y, p = blockIdx.z;
    const float* kp = (p == 0) ? k1 : k2;
    const float* gp = (p == 0) ? gk1 : gk2;

    __shared__ float bufG[64][68];   // gk -> g
    __shared__ float bufK[64][68];   // kg TRANSPOSED [d][t]
    __shared__ float bufV[64][68];   // v [t][e]
    __shared__ float glast[64];
    __shared__ float wrow[64];
    __shared__ float segsum[4][64];

    int tid = threadIdx.x;
    int tx = tid & 15, ty = tid >> 4;
    int e0 = tx * 4;

    if (tid < 64) {
        int lg = c * 64 + tid;
        wrow[tid] = (p == 0) ? 1.f : rw[lg * 4 + (p - 1)];
    }
    __syncthreads();

    #pragma unroll
    for (int i = 0; i < 16; ++i) {      // masked gk tile
        int idx = tid + (i << 8);
        int t = idx >> 6, d = idx & 63;
        float xg = gp[(size_t)(c * 64 + t) * KD_ + (h << 6) + d];
        if (p > 0 && !(wrow[t] > 0.f)) xg = 0.f;
        bufG[t][d] = xg;
    }
    __syncthreads();

    {   // segmented cumsum
        int d = tid & 63, seg = tid >> 6;
        int tb = seg * 16;
        float s = 0.f;
        for (int t = tb; t < tb + 16; ++t) { s += bufG[t][d]; bufG[t][d] = s; }
        segsum[seg][d] = s;
        __syncthreads();
        float off = 0.f;
        for (int ss = 0; ss < seg; ++ss) off += segsum[ss][d];
        if (seg) for (int t = tb; t < tb + 16; ++t) bufG[t][d] += off;
        if (seg == 3) glast[d] = off + s;
    }
    __syncthreads();

    #pragma unroll
    for (int i = 0; i < 16; ++i) {      // kg -> bufK[d][t], v -> bufV[t][e]
        int idx = tid + (i << 8);
        int t = idx >> 6, d = idx & 63;
        int l = c * 64 + t;
        bufK[d][t] = kp[(size_t)l * KD_ + (h << 6) + d] * wrow[t] * expf(-bufG[t][d]);
        bufV[t][d] = v[(size_t)l * KD_ + (h << 6) + d];
    }
    __syncthreads();

    {   // kv[d][e]; d = ty + 16*i
        float acc[4][4] = {};
        for (int t0v = 0; t0v < 64; t0v += 4) {
            float4 kk[4];
            #pragma unroll
            for (int i = 0; i < 4; ++i) kk[i] = *(const float4*)&bufK[ty + 16 * i][t0v];
            #pragma unroll
            for (int ss = 0; ss < 4; ++ss) {
                float4 vv = *(const float4*)&bufV[t0v + ss][e0];
                #pragma unroll
                for (int i = 0; i < 4; ++i) {
                    float ki = f4c(kk[i], ss);
                    acc[i][0] = fmaf(ki, vv.x, acc[i][0]);
                    acc[i][1] = fmaf(ki, vv.y, acc[i][1]);
                    acc[i][2] = fmaf(ki, vv.z, acc[i][2]);
                    acc[i][3] = fmaf(ki, vv.w, acc[i][3]);
                }
            }
        }
        size_t base = (size_t)((c * 8 + h) * 5 + p) * 4096;
        #pragma unroll
        for (int i = 0; i < 4; ++i) {
            int d = ty + 16 * i;
            float dec = expf(glast[d]);
            #pragma unroll
            for (int j = 0; j < 4; ++j)
                kv_all[base + d * 64 + e0 + j] = acc[i][j] * dec;
        }
        if (tid < 64) decay_all[(size_t)((c * 8 + h) * 5 + p) * 64 + tid] = expf(glast[tid]);
    }
}

// ---------------------------------------------------------------------------
// Inter-chunk state scan: elementwise, in place over kv_all.
// ---------------------------------------------------------------------------
__global__ void gla_state_scan(float* __restrict__ kv, const float* __restrict__ decay)
{
    int gid = blockIdx.x * 256 + threadIdx.x;
    int sub = gid >> 6;
    const size_t stride = 8 * 5 * 64 * 64;
    float S = 0.f;
    float kvv = kv[gid];
    for (int c = 0; c < 64; ++c) {
        size_t o = (size_t)c * stride + gid;
        float nxt = (c < 63) ? kv[o + stride] : 0.f;
        float dec = decay[c * 2560 + sub];
        kv[o] = S;
        S = fmaf(dec, S, kvv);
        kvv = nxt;
    }
}

// ---------------------------------------------------------------------------
// Phase 2: complete per-pass output. Block = (c,h,p), 2560 blocks.
// o_p = tril(qg kg^T) v + qg S_pre  -> plain store into o_parts[p].
// ---------------------------------------------------------------------------
__global__ void gla_o(const float* __restrict__ q1, const float* __restrict__ q2,
                      const float* __restrict__ k1, const float* __restrict__ k2,
                      const float* __restrict__ gk1, const float* __restrict__ gk2,
                      const float* __restrict__ v, const float* __restrict__ rw,
                      const float* __restrict__ Spre, float* __restrict__ o_parts)
{
    int c = blockIdx.x, h = blockIdx.y, p = blockIdx.z;
    const float* qp = (p == 0) ? q1 : q2;
    const float* kp = (p == 0) ? k1 : k2;
    const float* gp = (p == 0) ? gk1 : gk2;

    __shared__ float bufA[64][68];   // qg -> later v
    __shared__ float bufB[64][68];   // kg [d][t] -> later S [d][e]
    __shared__ float bufC[64][68];   // gk -> g -> A[t][s]
    __shared__ float wrow[64];
    __shared__ float segsum[4][64];

    int tid = threadIdx.x;
    int tx = tid & 15, ty = tid >> 4;
    int t0 = ty * 4, e0 = tx * 4;

    float acc_o[4][4] = {};

    if (tid < 64) {
        int lg = c * 64 + tid;
        wrow[tid] = (p == 0) ? 1.f : rw[lg * 4 + (p - 1)];
    }
    __syncthreads();

    #pragma unroll
    for (int i = 0; i < 16; ++i) {      // masked gk -> bufC
        int idx = tid + (i << 8);
        int t = idx >> 6, d = idx & 63;
        float xg = gp[(size_t)(c * 64 + t) * KD_ + (h << 6) + d];
        if (p > 0 && !(wrow[t] > 0.f)) xg = 0.f;
        bufC[t][d] = xg;
    }
    __syncthreads();

    {   // segmented cumsum
        int d = tid & 63, seg = tid >> 6;
        int tb = seg * 16;
        float s = 0.f;
        for (int t = tb; t < tb + 16; ++t) { s += bufC[t][d]; bufC[t][d] = s; }
        segsum[seg][d] = s;
        __syncthreads();
        float off = 0.f;
        for (int ss = 0; ss < seg; ++ss) off += segsum[ss][d];
        if (seg) for (int t = tb; t < tb + 16; ++t) bufC[t][d] += off;
    }
    __syncthreads();

    #pragma unroll
    for (int i = 0; i < 16; ++i) {      // qg -> bufA[t][d], kg -> bufB[d][t]
        int idx = tid + (i << 8);
        int t = idx >> 6, d = idx & 63;
        int l = c * 64 + t;
        float wv = wrow[t];
        float g = bufC[t][d];
        bufA[t][d] = qp[(size_t)l * KD_ + (h << 6) + d] * wv * expf(g);
        bufB[d][t] = kp[(size_t)l * KD_ + (h << 6) + d] * wv * expf(-g);
    }
    __syncthreads();

    {   // A[t][s] = tril dot_d(qg[t], kg[s]) -> bufC (g dead)
        if (e0 <= t0 + 3) {             // e0 plays s0
            float acc[4][4] = {};
            for (int d0 = 0; d0 < 64; d0 += 4) {
                float4 a[4];
                #pragma unroll
                for (int i = 0; i < 4; ++i) a[i] = *(const float4*)&bufA[t0 + i][d0];
                #pragma unroll
                for (int dd = 0; dd < 4; ++dd) {
                    float4 bv = *(const float4*)&bufB[d0 + dd][e0];
                    #pragma unroll
                    for (int i = 0; i < 4; ++i) {
                        float aa = f4c(a[i], dd);
                        acc[i][0] = fmaf(aa, bv.x, acc[i][0]);
                        acc[i][1] = fmaf(aa, bv.y, acc[i][1]);
                        acc[i][2] = fmaf(aa, bv.z, acc[i][2]);
                        acc[i][3] = fmaf(aa, bv.w, acc[i][3]);
                    }
                }
            }
            #pragma unroll
            for (int i = 0; i < 4; ++i)
                #pragma unroll
                for (int j = 0; j < 4; ++j)
                    bufC[t0 + i][e0 + j] = (e0 + j <= t0 + i) ? acc[i][j] : 0.f;
        }
    }
    __syncthreads();

    {   // S tile -> bufB (kg dead)
        size_t sbase = (size_t)((c * 8 + h) * 5 + p) * 4096;
        #pragma unroll
        for (int i = 0; i < 16; ++i) {
            int idx = tid + (i << 8);
            bufB[idx >> 6][idx & 63] = Spre[sbase + idx];
        }
    }
    __syncthreads();

    {   // o2 = qg @ S  (bufA = qg, bufB = S)
        for (int d0 = 0; d0 < 64; d0 += 4) {
            float4 a[4];
            #pragma unroll
            for (int i = 0; i < 4; ++i) a[i] = *(const float4*)&bufA[t0 + i][d0];
            #pragma unroll
            for (int dd = 0; dd < 4; ++dd) {
                float4 sv = *(const float4*)&bufB[d0 + dd][e0];
                #pragma unroll
                for (int i = 0; i < 4; ++i) {
                    float aa = f4c(a[i], dd);
                    acc_o[i][0] = fmaf(aa, sv.x, acc_o[i][0]);
                    acc_o[i][1] = fmaf(aa, sv.y, acc_o[i][1]);
                    acc_o[i][2] = fmaf(aa, sv.z, acc_o[i][2]);
                    acc_o[i][3] = fmaf(aa, sv.w, acc_o[i][3]);
                }
            }
        }
    }
    __syncthreads();

    #pragma unroll
    for (int i = 0; i < 16; ++i) {      // v tile -> bufA (qg dead)
        int idx = tid + (i << 8);
        int t = idx >> 6, d = idx & 63;
        bufA[t][d] = v[(size_t)(c * 64 + t) * KD_ + (h << 6) + d];
    }
    __syncthreads();

    {   // o1 = tril(A) @ v, accumulate into acc_o
        for (int s0 = 0; s0 <= t0 + 3; s0 += 4) {
            float4 a[4];
            #pragma unroll
            for (int i = 0; i < 4; ++i) a[i] = *(const float4*)&bufC[t0 + i][s0];
            #pragma unroll
            for (int ss = 0; ss < 4; ++ss) {
                float4 vv = *(const float4*)&bufA[s0 + ss][e0];
                #pragma unroll
                for (int i = 0; i < 4; ++i) {
                    float aa = f4c(a[i], ss);
                    acc_o[i][0] = fmaf(aa, vv.x, acc_o[i][0]);
                    acc_o[i][1] = fmaf(aa, vv.y, acc_o[i][1]);
                    acc_o[i][2] = fmaf(aa, vv.z, acc_o[i][2]);
                    acc_o[i][3] = fmaf(aa, vv.w, acc_o[i][3]);
                }
            }
        }
    }

    // plain store into this pass's partial buffer
    size_t pbase = (size_t)p * ((size_t)LL * KD_);
    #pragma unroll
    for (int i = 0; i < 4; ++i)
        #pragma unroll
        for (int j = 0; j < 4; ++j)
            o_parts[pbase + (size_t)(c * 64 + t0 + i) * KD_ + (h << 6) + e0 + j] = acc_o[i][j];
}

// ---------------------------------------------------------------------------
// Post: sum 5 partials, RMS-norm, * norm_w, * silu(g); emit split-bf16 A.
// ---------------------------------------------------------------------------
__global__ void postnorm(const float* __restrict__ o_parts, const float* __restrict__ gbuf,
                         const float* __restrict__ norm_w, unsigned short* __restrict__ og2)
{
    int l = blockIdx.x;
    int tid = threadIdx.x;
    int w = tid >> 6, lane = tid & 63;
    int bi = (w << 6) + lane;
    int idx = l * KD_ + bi;
    const size_t LKD = (size_t)LL * KD_;
    float o = 0.f;
    #pragma unroll
    for (int p = 0; p < 5; ++p) o += o_parts[(size_t)p * LKD + idx];
    float ss = o * o;
    for (int s = 32; s >= 1; s >>= 1) ss += __shfl_xor(ss, s, 64);
    float r = rsqrtf(ss * (1.f / 64.f) + 1e-5f);
    float val = o * r * norm_w[lane];
    float gv = gbuf[idx];
    val *= gv / (1.f + expf(-gv));
    unsigned short h, lo;
    split2(val, h, lo);
    size_t ro = (size_t)l * (3 * KD_) + bi;
    og2[ro]           = h;
    og2[ro + KD_]     = lo;
    og2[ro + 2 * KD_] = h;
}

// ---------------------------------------------------------------------------
extern "C" void kernel_launch(void* const* d_in, const int* in_sizes, int n_in,
                              void* d_out, int out_size, void* d_ws, size_t ws_size,
                              hipStream_t stream)
{
    const float* x    = (const float*)d_in[0];
    const float* Wq   = (const float*)d_in[1];
    const float* Wk   = (const float*)d_in[2];
    const float* Wv   = (const float*)d_in[3];
    const float* Wqa  = (const float*)d_in[4];
    const float* Wqb  = (const float*)d_in[5];
    const float* Wka  = (const float*)d_in[6];
    const float* Wkb  = (const float*)d_in[7];
    const float* Wg1a = (const float*)d_in[8];
    const float* Wg1b = (const float*)d_in[9];
    const float* bg1  = (const float*)d_in[10];
    const float* Wg2a = (const float*)d_in[11];
    const float* Wg2b = (const float*)d_in[12];
    const float* bg2  = (const float*)d_in[13];
    const float* We   = (const float*)d_in[14];
    const float* Wga  = (const float*)d_in[15];
    const float* Wgb  = (const float*)d_in[16];
    const float* normw= (const float*)d_in[17];
    const float* Wo   = (const float*)d_in[18];

    float* ws = (float*)d_ws;
    const size_t LKD = (size_t)LL * KD_;   // 2M floats
    float* q1   = ws;
    float* k1   = q1 + LKD;
    float* v    = k1 + LKD;
    float* q2   = v  + LKD;
    float* k2   = q2 + LKD;
    float* gk1  = k2 + LKD;
    float* gk2  = gk1 + LKD;
    float* o_parts = gk2 + LKD;                // 5 x LKD = 40MB
    float* tqa  = o_parts + 5 * LKD;           // 4096*64 f32
    float* tka  = tqa + (size_t)LL * 64;
    float* tga  = tka + (size_t)LL * 64;
    float* tg1  = tga + (size_t)LL * 64;       // 4096*16
    float* tg2  = tg1 + (size_t)LL * 16;
    float* elog = tg2 + (size_t)LL * 16;       // 4096*4
    float* rw   = elog + (size_t)LL * 4;
    float* kv_all    = rw + (size_t)LL * 4;                    // 10.49M f32
    float* decay_all = kv_all + (size_t)64 * 8 * 5 * 64 * 64;  // 163840 f32

    unsigned short* bp = (unsigned short*)(decay_all + 163840);
    unsigned short* WqT2  = bp; bp += (size_t)512 * 3072;
    unsigned short* WkT2  = bp; bp += (size_t)512 * 3072;
    unsigned short* WvT2  = bp; bp += (size_t)512 * 3072;
    unsigned short* WoT2  = bp; bp += (size_t)1024 * 1536;
    unsigned short* WqbT2 = bp; bp += (size_t)512 * 192;
    unsigned short* WkbT2 = bp; bp += (size_t)512 * 192;
    unsigned short* WgbT2 = bp; bp += (size_t)512 * 192;
    unsigned short* tqab2 = bp; bp += (size_t)LL * 192;
    unsigned short* tkab2 = bp; bp += (size_t)LL * 192;
    unsigned short* tgab2 = bp; bp += (size_t)LL * 192;

    // time-multiplexed aliases of kv_all (disjoint lifetimes):
    unsigned short* xb2 = (unsigned short*)kv_all;   // [4096][3072]; dead before gla_kv
    unsigned short* og2 = (unsigned short*)kv_all;   // [4096][1536]; live after gla_o
    float* gbuf = k1;                                // reuse after gla_o

    dim3 blk(256);
    dim3 tblk(32, 8);

    // ---- split conversions ----
    cvt_splitA<<<dim3((LL * 1024 + 255) / 256), blk, 0, stream>>>(x, xb2, LL * 1024, 10);
    cvtT_split<<<dim3(16, 32), tblk, 0, stream>>>(Wq, WqT2, 1024, 512);
    cvtT_split<<<dim3(16, 32), tblk, 0, stream>>>(Wk, WkT2, 1024, 512);
    cvtT_split<<<dim3(16, 32), tblk, 0, stream>>>(Wv, WvT2, 1024, 512);
    cvtT_split<<<dim3(32, 16), tblk, 0, stream>>>(Wo, WoT2, 512, 1024);
    cvtT_split<<<dim3(16, 2),  tblk, 0, stream>>>(Wqb, WqbT2, 64, 512);
    cvtT_split<<<dim3(16, 2),  tblk, 0, stream>>>(Wkb, WkbT2, 64, 512);
    cvtT_split<<<dim3(16, 2),  tblk, 0, stream>>>(Wgb, WgbT2, 64, 512);

    // ---- QKV (split MFMA, K'=3072, fused) ----
    gemm_mfma<<<dim3(4, 32, 3), blk, 0, stream>>>(xb2, xb2, xb2, WqT2, WkT2, WvT2,
                                                  q1, k1, v, LL, KD_, 3072);

    // ---- LoRA-a / gate-a / router (f32, 6-way fused) ----
    gemm64x<<<dim3(1, 64, 6), blk, 0, stream>>>(x, Wqa, Wka, Wga, Wg1a, Wg2a, We,
                                                tqa, tka, tga, tg1, tg2, elog, LL, 1024);

    // ---- split LoRA intermediates ----
    cvt_splitA<<<dim3((LL * 64 + 255) / 256), blk, 0, stream>>>(tqa, tqab2, LL * 64, 6);
    cvt_splitA<<<dim3((LL * 64 + 255) / 256), blk, 0, stream>>>(tka, tkab2, LL * 64, 6);
    cvt_splitA<<<dim3((LL * 64 + 255) / 256), blk, 0, stream>>>(tga, tgab2, LL * 64, 6);

    // ---- LoRA-b q2,k2 (split MFMA, K'=192) ----
    gemm_mfma<<<dim3(4, 32, 2), blk, 0, stream>>>(tqab2, tkab2, tkab2, WqbT2, WkbT2, WkbT2,
                                                  q2, k2, k2, LL, KD_, 192);
    // ---- gate-b (f32, K=16, fused z=2) ----
    gemm128b<<<dim3(4, 32, 2), blk, 0, stream>>>(tg1, tg2, Wg1b, Wg2b, gk1, gk2, LL, KD_, 16);

    elementwise_pre<<<LL, 512, 0, stream>>>(q1, q2, k2, gk1, gk2, bg1, bg2, elog, rw);

    // ---- GLA: kv -> scan -> o ----
    gla_kv<<<dim3(64, 8, 5), blk, 0, stream>>>(k1, k2, gk1, gk2, v, rw, kv_all, decay_all);
    gla_state_scan<<<dim3(640), blk, 0, stream>>>(kv_all, decay_all);
    gla_o<<<dim3(64, 8, 5), blk, 0, stream>>>(q1, q2, k1, k2, gk1, gk2, v, rw,
                                              kv_all, o_parts);

    // ---- gating projection (split MFMA; k1 free after gla_o) ----
    gemm_mfma<<<dim3(4, 32, 1), blk, 0, stream>>>(tgab2, tgab2, tgab2, WgbT2, WgbT2, WgbT2,
                                                  gbuf, gbuf, gbuf, LL, KD_, 192);

    postnorm<<<LL, 512, 0, stream>>>(o_parts, gbuf, normw, og2);

    // ---- output projection (split MFMA, K'=1536) ----
    gemm_mfma<<<dim3(8, 32, 1), blk, 0, stream>>>(og2, og2, og2, WoT2, WoT2, WoT2,
                                                  (float*)d_out, (float*)d_out, (float*)d_out,
                                                  LL, 1024, 1536);
}

// Round 8
// 435.736 us; speedup vs baseline: 6.5253x; 1.0851x over previous
//
#include <hip/hip_runtime.h>
#include <math.h>

#define LL   4096
#define HH   8
#define DK_  64
#define DV_  64
#define KD_  512
#define NEXP 4

typedef __attribute__((ext_vector_type(8))) short  s16x8;
typedef __attribute__((ext_vector_type(4))) float  f32x4;

__device__ __forceinline__ float f4c(const float4& v, int i) {
    return i == 0 ? v.x : i == 1 ? v.y : i == 2 ? v.z : v.w;
}

__device__ __forceinline__ unsigned short f2bf(float f) {   // RNE f32->bf16
    unsigned u = __float_as_uint(f);
    u += 0x7FFFu + ((u >> 16) & 1u);
    return (unsigned short)(u >> 16);
}

__device__ __forceinline__ void split2(float v, unsigned short& h, unsigned short& l) {
    h = f2bf(v);
    float hf = __uint_as_float((unsigned)h << 16);
    l = f2bf(v - hf);
}

// ---------------------------------------------------------------------------
// f32 [M][K] -> split-bf16 A layout [M][3K] = [hi | lo | hi]. K = 2^kshift.
// ---------------------------------------------------------------------------
__global__ void cvt_splitA(const float* __restrict__ in, unsigned short* __restrict__ out,
                           int n, int kshift)
{
    int i = blockIdx.x * 256 + threadIdx.x;
    if (i >= n) return;
    unsigned short h, l;
    split2(in[i], h, l);
    int K = 1 << kshift;
    int m = i >> kshift, k = i & (K - 1);
    size_t ro = (size_t)m * 3 * K;
    out[ro + k]         = h;
    out[ro + K + k]     = l;
    out[ro + 2 * K + k] = h;
}

// ---------------------------------------------------------------------------
// f32 [K][N] -> split-bf16 B layout [N][3K] = [hi | hi | lo] (transposed).
// ---------------------------------------------------------------------------
__global__ void cvtT_split(const float* __restrict__ W, unsigned short* __restrict__ WT,
                           int K, int N)
{
    __shared__ float t[32][33];
    int bx = blockIdx.x * 32;   // n
    int by = blockIdx.y * 32;   // k
    int x = threadIdx.x, y = threadIdx.y;
    #pragma unroll
    for (int i = 0; i < 4; ++i)
        t[y + 8 * i][x] = W[(size_t)(by + y + 8 * i) * N + bx + x];
    __syncthreads();
    #pragma unroll
    for (int i = 0; i < 4; ++i) {
        unsigned short h, l;
        split2(t[x][y + 8 * i], h, l);
        size_t ro = (size_t)(bx + y + 8 * i) * 3 * K + (by + x);
        WT[ro]         = h;
        WT[ro + K]     = h;
        WT[ro + 2 * K] = l;
    }
}

// ---------------------------------------------------------------------------
// bf16 MFMA GEMM (split-bf16 accurate): 128x128 tile, BK=64, 4 waves.
// ---------------------------------------------------------------------------
__global__ __launch_bounds__(256) void gemm_mfma(
    const unsigned short* __restrict__ A0, const unsigned short* __restrict__ A1,
    const unsigned short* __restrict__ A2,
    const unsigned short* __restrict__ B0, const unsigned short* __restrict__ B1,
    const unsigned short* __restrict__ B2,
    float* __restrict__ C0, float* __restrict__ C1, float* __restrict__ C2,
    int M, int N, int K)
{
    const unsigned short* A = (blockIdx.z == 0) ? A0 : (blockIdx.z == 1) ? A1 : A2;
    const unsigned short* B = (blockIdx.z == 0) ? B0 : (blockIdx.z == 1) ? B1 : B2;
    float*                C = (blockIdx.z == 0) ? C0 : (blockIdx.z == 1) ? C1 : C2;

    __shared__ __align__(16) unsigned short sm[2 * 128 * 64];
    unsigned short* As = sm;
    unsigned short* Bs = sm + 128 * 64;

    int tid  = threadIdx.x;
    int lane = tid & 63;
    int w    = tid >> 6;
    int m0 = blockIdx.y * 128, n0 = blockIdx.x * 128;
    int wr = w >> 1, wc = w & 1;

    f32x4 acc[4][4];
    #pragma unroll
    for (int i = 0; i < 4; ++i)
        #pragma unroll
        for (int j = 0; j < 4; ++j)
            acc[i][j] = (f32x4){0.f, 0.f, 0.f, 0.f};

    const int srow = (lane >> 3);
    const int scb  = ((lane & 7) * 16) ^ (srow << 4);

    for (int kt = 0; kt < K; kt += 64) {
        __syncthreads();
        #pragma unroll
        for (int q = 0; q < 4; ++q) {
            int r = w * 32 + q * 8 + srow;
            const char* ga = (const char*)A + ((size_t)(m0 + r) * K + kt) * 2 + scb;
            const char* gb = (const char*)B + ((size_t)(n0 + r) * K + kt) * 2 + scb;
            __builtin_amdgcn_global_load_lds(
                (const __attribute__((address_space(1))) void*)ga,
                (__attribute__((address_space(3))) void*)((char*)As + (w * 32 + q * 8) * 128),
                16, 0, 0);
            __builtin_amdgcn_global_load_lds(
                (const __attribute__((address_space(1))) void*)gb,
                (__attribute__((address_space(3))) void*)((char*)Bs + (w * 32 + q * 8) * 128),
                16, 0, 0);
        }
        __syncthreads();

        #pragma unroll
        for (int kk = 0; kk < 2; ++kk) {
            int kb = kk * 64 + (lane >> 4) * 16;
            s16x8 af[4], bfr[4];
            #pragma unroll
            for (int mi = 0; mi < 4; ++mi) {
                int r = wr * 64 + mi * 16 + (lane & 15);
                af[mi] = *(const s16x8*)((const char*)As + r * 128 + (kb ^ ((r & 7) << 4)));
            }
            #pragma unroll
            for (int ni = 0; ni < 4; ++ni) {
                int r = wc * 64 + ni * 16 + (lane & 15);
                bfr[ni] = *(const s16x8*)((const char*)Bs + r * 128 + (kb ^ ((r & 7) << 4)));
            }
            #pragma unroll
            for (int mi = 0; mi < 4; ++mi)
                #pragma unroll
                for (int ni = 0; ni < 4; ++ni)
                    acc[mi][ni] = __builtin_amdgcn_mfma_f32_16x16x32_bf16(
                        af[mi], bfr[ni], acc[mi][ni], 0, 0, 0);
        }
    }

    #pragma unroll
    for (int mi = 0; mi < 4; ++mi)
        #pragma unroll
        for (int ni = 0; ni < 4; ++ni) {
            int col = n0 + wc * 64 + ni * 16 + (lane & 15);
            int rb  = m0 + wr * 64 + mi * 16 + (lane >> 4) * 4;
            #pragma unroll
            for (int j = 0; j < 4; ++j)
                C[(size_t)(rb + j) * N + col] = acc[mi][ni][j];
        }
}

// ---------------------------------------------------------------------------
// Small-N f32 GEMM (64x64 tile), 6-way fused over blockIdx.z; A = x for all.
// ---------------------------------------------------------------------------
__global__ void gemm64x(const float* __restrict__ A,
                        const float* __restrict__ B0, const float* __restrict__ B1,
                        const float* __restrict__ B2, const float* __restrict__ B3,
                        const float* __restrict__ B4, const float* __restrict__ B5,
                        float* __restrict__ C0, float* __restrict__ C1,
                        float* __restrict__ C2, float* __restrict__ C3,
                        float* __restrict__ C4, float* __restrict__ C5,
                        int M, int K)
{
    int z = blockIdx.z;
    const float* B = (z == 0) ? B0 : (z == 1) ? B1 : (z == 2) ? B2 :
                     (z == 3) ? B3 : (z == 4) ? B4 : B5;
    float*       C = (z == 0) ? C0 : (z == 1) ? C1 : (z == 2) ? C2 :
                     (z == 3) ? C3 : (z == 4) ? C4 : C5;
    int N = (z < 3) ? 64 : (z < 5) ? 16 : 4;

    __shared__ float As[16][65];
    __shared__ float Bs[16][65];
    int tid = threadIdx.x;
    int m0 = blockIdx.y * 64;
    int tx = tid & 15, ty = tid >> 4;
    float acc[4][4] = {};
    for (int k0 = 0; k0 < K; k0 += 16) {
        {
            int row = tid >> 2, q4 = tid & 3;
            const float4 a = *reinterpret_cast<const float4*>(&A[(size_t)(m0 + row) * K + k0 + q4 * 4]);
            As[q4 * 4 + 0][row] = a.x;
            As[q4 * 4 + 1][row] = a.y;
            As[q4 * 4 + 2][row] = a.z;
            As[q4 * 4 + 3][row] = a.w;
        }
        #pragma unroll
        for (int j = 0; j < 4; ++j) {
            int lin = tid * 4 + j;
            int kr = lin >> 6, cc = lin & 63;
            Bs[kr][cc] = (cc < N) ? B[(size_t)(k0 + kr) * N + cc] : 0.f;
        }
        __syncthreads();
        #pragma unroll
        for (int k = 0; k < 16; ++k) {
            float av[4], bv[4];
            #pragma unroll
            for (int i = 0; i < 4; ++i) av[i] = As[k][ty * 4 + i];
            #pragma unroll
            for (int j = 0; j < 4; ++j) bv[j] = Bs[k][tx * 4 + j];
            #pragma unroll
            for (int i = 0; i < 4; ++i)
                #pragma unroll
                for (int j = 0; j < 4; ++j)
                    acc[i][j] = fmaf(av[i], bv[j], acc[i][j]);
        }
        __syncthreads();
    }
    #pragma unroll
    for (int i = 0; i < 4; ++i) {
        int m = m0 + ty * 4 + i;
        #pragma unroll
        for (int j = 0; j < 4; ++j) {
            int n = tx * 4 + j;
            if (n < N) C[(size_t)m * N + n] = acc[i][j];
        }
    }
}

// ---------------------------------------------------------------------------
// 128x128 f32 GEMM, fused over z (2 triples) — gate-b (K=16).
// ---------------------------------------------------------------------------
__global__ void gemm128b(const float* __restrict__ A0, const float* __restrict__ A1,
                         const float* __restrict__ B0, const float* __restrict__ B1,
                         float* __restrict__ C0, float* __restrict__ C1,
                         int M, int N, int K)
{
    const float* A = (blockIdx.z == 0) ? A0 : A1;
    const float* B = (blockIdx.z == 0) ? B0 : B1;
    float*       C = (blockIdx.z == 0) ? C0 : C1;

    __shared__ float As[16][132];
    __shared__ float Bs[16][132];
    int tid = threadIdx.x;
    int n0 = blockIdx.x * 128;
    int m0 = blockIdx.y * 128;
    int tx = tid & 15, ty = tid >> 4;
    float acc[8][8] = {};

    for (int k0 = 0; k0 < K; k0 += 16) {
        #pragma unroll
        for (int u = 0; u < 2; ++u) {
            int lin = tid + (u << 8);
            int row = lin >> 2, q4 = lin & 3;
            float4 a = *reinterpret_cast<const float4*>(&A[(size_t)(m0 + row) * K + k0 + q4 * 4]);
            As[q4 * 4 + 0][row] = a.x;
            As[q4 * 4 + 1][row] = a.y;
            As[q4 * 4 + 2][row] = a.z;
            As[q4 * 4 + 3][row] = a.w;
        }
        #pragma unroll
        for (int u = 0; u < 2; ++u) {
            int lin = tid + (u << 8);
            int kr = lin >> 5, c4 = lin & 31;
            *reinterpret_cast<float4*>(&Bs[kr][c4 * 4]) =
                *reinterpret_cast<const float4*>(&B[(size_t)(k0 + kr) * N + n0 + c4 * 4]);
        }
        __syncthreads();
        #pragma unroll
        for (int k = 0; k < 16; ++k) {
            float4 a0 = *(const float4*)&As[k][ty * 4];
            float4 a1 = *(const float4*)&As[k][64 + ty * 4];
            float4 b0 = *(const float4*)&Bs[k][tx * 4];
            float4 b1 = *(const float4*)&Bs[k][64 + tx * 4];
            float av[8] = {a0.x, a0.y, a0.z, a0.w, a1.x, a1.y, a1.z, a1.w};
            float bv[8] = {b0.x, b0.y, b0.z, b0.w, b1.x, b1.y, b1.z, b1.w};
            #pragma unroll
            for (int i = 0; i < 8; ++i)
                #pragma unroll
                for (int j = 0; j < 8; ++j)
                    acc[i][j] = fmaf(av[i], bv[j], acc[i][j]);
        }
        __syncthreads();
    }
    #pragma unroll
    for (int i = 0; i < 8; ++i) {
        int m = m0 + ((i < 4) ? ty * 4 + i : 64 + ty * 4 + (i - 4));
        float4 c0 = make_float4(acc[i][0], acc[i][1], acc[i][2], acc[i][3]);
        float4 c1 = make_float4(acc[i][4], acc[i][5], acc[i][6], acc[i][7]);
        *reinterpret_cast<float4*>(&C[(size_t)m * N + n0 + tx * 4]) = c0;
        *reinterpret_cast<float4*>(&C[(size_t)m * N + n0 + 64 + tx * 4]) = c1;
    }
}

// ---------------------------------------------------------------------------
__device__ inline float logsig(float x) {
    return fminf(x, 0.f) - log1pf(expf(-fabsf(x)));
}

__global__ void elementwise_pre(float* __restrict__ q1, float* __restrict__ q2,
                                float* __restrict__ k2, float* __restrict__ gk1,
                                float* __restrict__ gk2,
                                const float* __restrict__ bg1, const float* __restrict__ bg2,
                                const float* __restrict__ elog, float* __restrict__ rw)
{
    int l = blockIdx.x;
    int tid = threadIdx.x;
    int w = tid >> 6, lane = tid & 63;
    int idx = l * KD_ + (w << 6) + lane;

    q1[idx] *= 0.125f;
    q2[idx] *= 0.125f;

    float kv = k2[idx];
    float m = kv;
    for (int s = 32; s >= 1; s >>= 1) m = fmaxf(m, __shfl_xor(m, s, 64));
    float ev = expf(kv - m);
    float ssum = ev;
    for (int s = 32; s >= 1; s >>= 1) ssum += __shfl_xor(ssum, s, 64);
    k2[idx] = ev / ssum;

    int bi = (w << 6) + lane;
    gk1[idx] = logsig(gk1[idx] + bg1[bi]) * (1.f / 16.f);
    gk2[idx] = logsig(gk2[idx] + bg2[bi]) * (1.f / 16.f);

    if (tid == 0) {
        float xs[4];
        float mm = -1e30f;
        for (int j = 0; j < 4; ++j) { xs[j] = elog[l * 4 + j]; mm = fmaxf(mm, xs[j]); }
        float s4 = 0.f;
        for (int j = 0; j < 4; ++j) { xs[j] = expf(xs[j] - mm); s4 += xs[j]; }
        for (int j = 0; j < 4; ++j) xs[j] /= s4;
        int arg = 0; float best = xs[0];
        for (int j = 1; j < 4; ++j) if (xs[j] > best) { best = xs[j]; arg = j; }
        for (int j = 0; j < 4; ++j) rw[l * 4 + j] = (j == arg) ? xs[j] : 0.f;
    }
}

// ---------------------------------------------------------------------------
// Phase 1: chunk_kv + decay. Block = (p,h,c) — p fastest for L2 sharing.
// Register-resident cumsum: thread owns (d = tid&63, seg = tid>>6).
// ---------------------------------------------------------------------------
__global__ void gla_kv(const float* __restrict__ k1, const float* __restrict__ k2,
                       const float* __restrict__ gk1, const float* __restrict__ gk2,
                       const float* __restrict__ v, const float* __restrict__ rw,
                       float* __restrict__ kv_all, float* __restrict__ decay_all)
{
    int p = blockIdx.x, h = blockIdx.y, c = blockIdx.z;
    const float* kp = (p == 0) ? k1 : k2;
    const float* gp = (p == 0) ? gk1 : gk2;

    __shared__ float bufK[64][68];   // kg TRANSPOSED [d][t]
    __shared__ float bufV[64][68];   // v [t][e]
    __shared__ float glast[64];
    __shared__ float wrow[64];
    __shared__ float segsum[4][64];

    int tid = threadIdx.x;
    int tx = tid & 15, ty = tid >> 4;
    int e0 = tx * 4;
    int d = tid & 63, seg = tid >> 6;

    // prefetch (independent loads, coalesced across d)
    float gkv[16], kvv[16], vv_[16];
    #pragma unroll
    for (int i = 0; i < 16; ++i) {
        size_t base = (size_t)(c * 64 + seg * 16 + i) * KD_ + (h << 6) + d;
        gkv[i] = gp[base];
        kvv[i] = kp[base];
        vv_[i] = v[base];
    }
    if (tid < 64) {
        int lg = c * 64 + tid;
        wrow[tid] = (p == 0) ? 1.f : rw[lg * 4 + (p - 1)];
    }
    __syncthreads();

    {   // masked register cumsum
        float s = 0.f;
        #pragma unroll
        for (int i = 0; i < 16; ++i) {
            int t = seg * 16 + i;
            float xg = gkv[i];
            if (p > 0 && !(wrow[t] > 0.f)) xg = 0.f;
            s += xg;
            gkv[i] = s;
        }
        segsum[seg][d] = s;
    }
    __syncthreads();
    {
        float off = 0.f, tot = 0.f;
        #pragma unroll
        for (int ss = 0; ss < 4; ++ss) {
            float x = segsum[ss][d];
            tot += x;
            if (ss < seg) off += x;
        }
        if (seg == 0) glast[d] = tot;
        #pragma unroll
        for (int i = 0; i < 16; ++i) {
            int t = seg * 16 + i;
            float g = off + gkv[i];
            bufK[d][t] = kvv[i] * wrow[t] * expf(-g);
            bufV[t][d] = vv_[i];
        }
    }
    __syncthreads();

    {   // kv[d][e] = exp(glast[d]) * sum_t kg[t][d] v[t][e]; d rows = ty + 16*i
        float acc[4][4] = {};
        for (int t0v = 0; t0v < 64; t0v += 4) {
            float4 kk[4];
            #pragma unroll
            for (int i = 0; i < 4; ++i) kk[i] = *(const float4*)&bufK[ty + 16 * i][t0v];
            #pragma unroll
            for (int ss = 0; ss < 4; ++ss) {
                float4 vv = *(const float4*)&bufV[t0v + ss][e0];
                #pragma unroll
                for (int i = 0; i < 4; ++i) {
                    float ki = f4c(kk[i], ss);
                    acc[i][0] = fmaf(ki, vv.x, acc[i][0]);
                    acc[i][1] = fmaf(ki, vv.y, acc[i][1]);
                    acc[i][2] = fmaf(ki, vv.z, acc[i][2]);
                    acc[i][3] = fmaf(ki, vv.w, acc[i][3]);
                }
            }
        }
        size_t base = (size_t)((c * 8 + h) * 5 + p) * 4096;
        #pragma unroll
        for (int i = 0; i < 4; ++i) {
            int dd = ty + 16 * i;
            float dec = expf(glast[dd]);
            #pragma unroll
            for (int j = 0; j < 4; ++j)
                kv_all[base + dd * 64 + e0 + j] = acc[i][j] * dec;
        }
        if (tid < 64) decay_all[(size_t)((c * 8 + h) * 5 + p) * 64 + tid] = expf(glast[tid]);
    }
}

// ---------------------------------------------------------------------------
// Inter-chunk state scan: elementwise, in place over kv_all.
// ---------------------------------------------------------------------------
__global__ void gla_state_scan(float* __restrict__ kv, const float* __restrict__ decay)
{
    int gid = blockIdx.x * 256 + threadIdx.x;
    int sub = gid >> 6;
    const size_t stride = 8 * 5 * 64 * 64;
    float S = 0.f;
    float kvv = kv[gid];
    for (int c = 0; c < 64; ++c) {
        size_t o = (size_t)c * stride + gid;
        float nxt = (c < 63) ? kv[o + stride] : 0.f;
        float dec = decay[c * 2560 + sub];
        kv[o] = S;
        S = fmaf(dec, S, kvv);
        kvv = nxt;
    }
}

// ---------------------------------------------------------------------------
// Phase 2: full per-pass output. Block = (p,h,c) — p fastest for L2 sharing.
// Register cumsum + register prefetch of S and v (latency hidden under A-matmul).
// ---------------------------------------------------------------------------
__global__ void gla_o(const float* __restrict__ q1, const float* __restrict__ q2,
                      const float* __restrict__ k1, const float* __restrict__ k2,
                      const float* __restrict__ gk1, const float* __restrict__ gk2,
                      const float* __restrict__ v, const float* __restrict__ rw,
                      const float* __restrict__ Spre, float* __restrict__ o_parts)
{
    int p = blockIdx.x, h = blockIdx.y, c = blockIdx.z;
    const float* qp = (p == 0) ? q1 : q2;
    const float* kp = (p == 0) ? k1 : k2;
    const float* gp = (p == 0) ? gk1 : gk2;

    __shared__ float bufA[64][68];   // qg -> later v
    __shared__ float bufB[64][68];   // kg [d][t] -> later S [d][e]
    __shared__ float bufC[64][68];   // A[t][s]
    __shared__ float wrow[64];
    __shared__ float segsum[4][64];

    int tid = threadIdx.x;
    int tx = tid & 15, ty = tid >> 4;
    int t0 = ty * 4, e0 = tx * 4;
    int d = tid & 63, seg = tid >> 6;

    float acc_o[4][4] = {};

    {   // prefetch gk/q/k for owned tokens; cumsum in registers; stage qg/kg
        float gkv[16], qv[16], kvv[16];
        #pragma unroll
        for (int i = 0; i < 16; ++i) {
            size_t base = (size_t)(c * 64 + seg * 16 + i) * KD_ + (h << 6) + d;
            gkv[i] = gp[base];
            qv[i]  = qp[base];
            kvv[i] = kp[base];
        }
        if (tid < 64) {
            int lg = c * 64 + tid;
            wrow[tid] = (p == 0) ? 1.f : rw[lg * 4 + (p - 1)];
        }
        __syncthreads();

        float s = 0.f;
        #pragma unroll
        for (int i = 0; i < 16; ++i) {
            int t = seg * 16 + i;
            float xg = gkv[i];
            if (p > 0 && !(wrow[t] > 0.f)) xg = 0.f;
            s += xg;
            gkv[i] = s;
        }
        segsum[seg][d] = s;
        __syncthreads();

        float off = 0.f;
        for (int ss = 0; ss < seg; ++ss) off += segsum[ss][d];
        #pragma unroll
        for (int i = 0; i < 16; ++i) {
            int t = seg * 16 + i;
            float g = off + gkv[i];
            float wv = wrow[t];
            bufA[t][d] = qv[i] * wv * expf(g);
            bufB[d][t] = kvv[i] * wv * expf(-g);
        }
    }

    // prefetch S into registers (consumed after A-matmul)
    float Sv[16];
    {
        size_t sbase = (size_t)((c * 8 + h) * 5 + p) * 4096;
        #pragma unroll
        for (int i = 0; i < 16; ++i) Sv[i] = Spre[sbase + tid + (i << 8)];
    }
    __syncthreads();

    {   // A[t][s] = tril dot_d(qg[t], kg[s]) -> bufC
        if (e0 <= t0 + 3) {             // e0 plays s0
            float acc[4][4] = {};
            for (int d0 = 0; d0 < 64; d0 += 4) {
                float4 a[4];
                #pragma unroll
                for (int i = 0; i < 4; ++i) a[i] = *(const float4*)&bufA[t0 + i][d0];
                #pragma unroll
                for (int dd = 0; dd < 4; ++dd) {
                    float4 bv = *(const float4*)&bufB[d0 + dd][e0];
                    #pragma unroll
                    for (int i = 0; i < 4; ++i) {
                        float aa = f4c(a[i], dd);
                        acc[i][0] = fmaf(aa, bv.x, acc[i][0]);
                        acc[i][1] = fmaf(aa, bv.y, acc[i][1]);
                        acc[i][2] = fmaf(aa, bv.z, acc[i][2]);
                        acc[i][3] = fmaf(aa, bv.w, acc[i][3]);
                    }
                }
            }
            #pragma unroll
            for (int i = 0; i < 4; ++i)
                #pragma unroll
                for (int j = 0; j < 4; ++j)
                    bufC[t0 + i][e0 + j] = (e0 + j <= t0 + i) ? acc[i][j] : 0.f;
        }
    }
    __syncthreads();

    // S regs -> bufB (kg dead); prefetch v into regs for the o1 stage
    float vv_[16];
    {
        #pragma unroll
        for (int i = 0; i < 16; ++i) {
            int idx = tid + (i << 8);
            bufB[idx >> 6][idx & 63] = Sv[i];
        }
        #pragma unroll
        for (int i = 0; i < 16; ++i) {
            size_t base = (size_t)(c * 64 + seg * 16 + i) * KD_ + (h << 6) + d;
            vv_[i] = v[base];
        }
    }
    __syncthreads();

    {   // o2 = qg @ S  (bufA = qg, bufB = S)
        for (int d0 = 0; d0 < 64; d0 += 4) {
            float4 a[4];
            #pragma unroll
            for (int i = 0; i < 4; ++i) a[i] = *(const float4*)&bufA[t0 + i][d0];
            #pragma unroll
            for (int dd = 0; dd < 4; ++dd) {
                float4 sv = *(const float4*)&bufB[d0 + dd][e0];
                #pragma unroll
                for (int i = 0; i < 4; ++i) {
                    float aa = f4c(a[i], dd);
                    acc_o[i][0] = fmaf(aa, sv.x, acc_o[i][0]);
                    acc_o[i][1] = fmaf(aa, sv.y, acc_o[i][1]);
                    acc_o[i][2] = fmaf(aa, sv.z, acc_o[i][2]);
                    acc_o[i][3] = fmaf(aa, sv.w, acc_o[i][3]);
                }
            }
        }
    }
    __syncthreads();

    #pragma unroll
    for (int i = 0; i < 16; ++i)        // v regs -> bufA (qg dead)
        bufA[seg * 16 + i][d] = vv_[i];
    __syncthreads();

    {   // o1 = tril(A) @ v, accumulate into acc_o
        for (int s0 = 0; s0 <= t0 + 3; s0 += 4) {
            float4 a[4];
            #pragma unroll
            for (int i = 0; i < 4; ++i) a[i] = *(const float4*)&bufC[t0 + i][s0];
            #pragma unroll
            for (int ss = 0; ss < 4; ++ss) {
                float4 vv = *(const float4*)&bufA[s0 + ss][e0];
                #pragma unroll
                for (int i = 0; i < 4; ++i) {
                    float aa = f4c(a[i], ss);
                    acc_o[i][0] = fmaf(aa, vv.x, acc_o[i][0]);
                    acc_o[i][1] = fmaf(aa, vv.y, acc_o[i][1]);
                    acc_o[i][2] = fmaf(aa, vv.z, acc_o[i][2]);
                    acc_o[i][3] = fmaf(aa, vv.w, acc_o[i][3]);
                }
            }
        }
    }

    size_t pbase = (size_t)p * ((size_t)LL * KD_);
    #pragma unroll
    for (int i = 0; i < 4; ++i)
        #pragma unroll
        for (int j = 0; j < 4; ++j)
            o_parts[pbase + (size_t)(c * 64 + t0 + i) * KD_ + (h << 6) + e0 + j] = acc_o[i][j];
}

// ---------------------------------------------------------------------------
// Post: sum 5 partials, RMS-norm, * norm_w, * silu(g); emit split-bf16 A.
// ---------------------------------------------------------------------------
__global__ void postnorm(const float* __restrict__ o_parts, const float* __restrict__ gbuf,
                         const float* __restrict__ norm_w, unsigned short* __restrict__ og2)
{
    int l = blockIdx.x;
    int tid = threadIdx.x;
    int w = tid >> 6, lane = tid & 63;
    int bi = (w << 6) + lane;
    int idx = l * KD_ + bi;
    const size_t LKD = (size_t)LL * KD_;
    float o = 0.f;
    #pragma unroll
    for (int p = 0; p < 5; ++p) o += o_parts[(size_t)p * LKD + idx];
    float ss = o * o;
    for (int s = 32; s >= 1; s >>= 1) ss += __shfl_xor(ss, s, 64);
    float r = rsqrtf(ss * (1.f / 64.f) + 1e-5f);
    float val = o * r * norm_w[lane];
    float gv = gbuf[idx];
    val *= gv / (1.f + expf(-gv));
    unsigned short h, lo;
    split2(val, h, lo);
    size_t ro = (size_t)l * (3 * KD_) + bi;
    og2[ro]           = h;
    og2[ro + KD_]     = lo;
    og2[ro + 2 * KD_] = h;
}

// ---------------------------------------------------------------------------
extern "C" void kernel_launch(void* const* d_in, const int* in_sizes, int n_in,
                              void* d_out, int out_size, void* d_ws, size_t ws_size,
                              hipStream_t stream)
{
    const float* x    = (const float*)d_in[0];
    const float* Wq   = (const float*)d_in[1];
    const float* Wk   = (const float*)d_in[2];
    const float* Wv   = (const float*)d_in[3];
    const float* Wqa  = (const float*)d_in[4];
    const float* Wqb  = (const float*)d_in[5];
    const float* Wka  = (const float*)d_in[6];
    const float* Wkb  = (const float*)d_in[7];
    const float* Wg1a = (const float*)d_in[8];
    const float* Wg1b = (const float*)d_in[9];
    const float* bg1  = (const float*)d_in[10];
    const float* Wg2a = (const float*)d_in[11];
    const float* Wg2b = (const float*)d_in[12];
    const float* bg2  = (const float*)d_in[13];
    const float* We   = (const float*)d_in[14];
    const float* Wga  = (const float*)d_in[15];
    const float* Wgb  = (const float*)d_in[16];
    const float* normw= (const float*)d_in[17];
    const float* Wo   = (const float*)d_in[18];

    float* ws = (float*)d_ws;
    const size_t LKD = (size_t)LL * KD_;   // 2M floats
    float* q1   = ws;
    float* k1   = q1 + LKD;
    float* v    = k1 + LKD;
    float* q2   = v  + LKD;
    float* k2   = q2 + LKD;
    float* gk1  = k2 + LKD;
    float* gk2  = gk1 + LKD;
    float* o_parts = gk2 + LKD;                // 5 x LKD = 40MB
    float* tqa  = o_parts + 5 * LKD;           // 4096*64 f32
    float* tka  = tqa + (size_t)LL * 64;
    float* tga  = tka + (size_t)LL * 64;
    float* tg1  = tga + (size_t)LL * 64;       // 4096*16
    float* tg2  = tg1 + (size_t)LL * 16;
    float* elog = tg2 + (size_t)LL * 16;       // 4096*4
    float* rw   = elog + (size_t)LL * 4;
    float* kv_all    = rw + (size_t)LL * 4;                    // 10.49M f32
    float* decay_all = kv_all + (size_t)64 * 8 * 5 * 64 * 64;  // 163840 f32

    unsigned short* bp = (unsigned short*)(decay_all + 163840);
    unsigned short* WqT2  = bp; bp += (size_t)512 * 3072;
    unsigned short* WkT2  = bp; bp += (size_t)512 * 3072;
    unsigned short* WvT2  = bp; bp += (size_t)512 * 3072;
    unsigned short* WoT2  = bp; bp += (size_t)1024 * 1536;
    unsigned short* WqbT2 = bp; bp += (size_t)512 * 192;
    unsigned short* WkbT2 = bp; bp += (size_t)512 * 192;
    unsigned short* WgbT2 = bp; bp += (size_t)512 * 192;
    unsigned short* tqab2 = bp; bp += (size_t)LL * 192;
    unsigned short* tkab2 = bp; bp += (size_t)LL * 192;
    unsigned short* tgab2 = bp; bp += (size_t)LL * 192;

    // time-multiplexed aliases of kv_all (disjoint lifetimes):
    unsigned short* xb2 = (unsigned short*)kv_all;   // [4096][3072]; dead before gla_kv
    unsigned short* og2 = (unsigned short*)kv_all;   // [4096][1536]; live after gla_o
    float* gbuf = k1;                                // reuse after gla_o

    dim3 blk(256);
    dim3 tblk(32, 8);

    // ---- split conversions ----
    cvt_splitA<<<dim3((LL * 1024 + 255) / 256), blk, 0, stream>>>(x, xb2, LL * 1024, 10);
    cvtT_split<<<dim3(16, 32), tblk, 0, stream>>>(Wq, WqT2, 1024, 512);
    cvtT_split<<<dim3(16, 32), tblk, 0, stream>>>(Wk, WkT2, 1024, 512);
    cvtT_split<<<dim3(16, 32), tblk, 0, stream>>>(Wv, WvT2, 1024, 512);
    cvtT_split<<<dim3(32, 16), tblk, 0, stream>>>(Wo, WoT2, 512, 1024);
    cvtT_split<<<dim3(16, 2),  tblk, 0, stream>>>(Wqb, WqbT2, 64, 512);
    cvtT_split<<<dim3(16, 2),  tblk, 0, stream>>>(Wkb, WkbT2, 64, 512);
    cvtT_split<<<dim3(16, 2),  tblk, 0, stream>>>(Wgb, WgbT2, 64, 512);

    // ---- QKV (split MFMA, K'=3072, fused) ----
    gemm_mfma<<<dim3(4, 32, 3), blk, 0, stream>>>(xb2, xb2, xb2, WqT2, WkT2, WvT2,
                                                  q1, k1, v, LL, KD_, 3072);

    // ---- LoRA-a / gate-a / router (f32, 6-way fused) ----
    gemm64x<<<dim3(1, 64, 6), blk, 0, stream>>>(x, Wqa, Wka, Wga, Wg1a, Wg2a, We,
                                                tqa, tka, tga, tg1, tg2, elog, LL, 1024);

    // ---- split LoRA intermediates ----
    cvt_splitA<<<dim3((LL * 64 + 255) / 256), blk, 0, stream>>>(tqa, tqab2, LL * 64, 6);
    cvt_splitA<<<dim3((LL * 64 + 255) / 256), blk, 0, stream>>>(tka, tkab2, LL * 64, 6);
    cvt_splitA<<<dim3((LL * 64 + 255) / 256), blk, 0, stream>>>(tga, tgab2, LL * 64, 6);

    // ---- LoRA-b q2,k2 (split MFMA, K'=192) ----
    gemm_mfma<<<dim3(4, 32, 2), blk, 0, stream>>>(tqab2, tkab2, tkab2, WqbT2, WkbT2, WkbT2,
                                                  q2, k2, k2, LL, KD_, 192);
    // ---- gate-b (f32, K=16, fused z=2) ----
    gemm128b<<<dim3(4, 32, 2), blk, 0, stream>>>(tg1, tg2, Wg1b, Wg2b, gk1, gk2, LL, KD_, 16);

    elementwise_pre<<<LL, 512, 0, stream>>>(q1, q2, k2, gk1, gk2, bg1, bg2, elog, rw);

    // ---- GLA: kv -> scan -> o (p fastest-varying for L2 sharing) ----
    gla_kv<<<dim3(5, 8, 64), blk, 0, stream>>>(k1, k2, gk1, gk2, v, rw, kv_all, decay_all);
    gla_state_scan<<<dim3(640), blk, 0, stream>>>(kv_all, decay_all);
    gla_o<<<dim3(5, 8, 64), blk, 0, stream>>>(q1, q2, k1, k2, gk1, gk2, v, rw,
                                              kv_all, o_parts);

    // ---- gating projection (split MFMA; k1 free after gla_o) ----
    gemm_mfma<<<dim3(4, 32, 1), blk, 0, stream>>>(tgab2, tgab2, tgab2, WgbT2, WgbT2, WgbT2,
                                                  gbuf, gbuf, gbuf, LL, KD_, 192);

    postnorm<<<LL, 512, 0, stream>>>(o_parts, gbuf, normw, og2);

    // ---- output projection (split MFMA, K'=1536) ----
    gemm_mfma<<<dim3(8, 32, 1), blk, 0, stream>>>(og2, og2, og2, WoT2, WoT2, WoT2,
                                                  (float*)d_out, (float*)d_out, (float*)d_out,
                                                  LL, 1024, 1536);
}

// Round 9
// 391.699 us; speedup vs baseline: 7.2589x; 1.1124x over previous
//
#include <hip/hip_runtime.h>
#include <math.h>

#define LL   4096
#define HH   8
#define DK_  64
#define DV_  64
#define KD_  512
#define NEXP 4

typedef __attribute__((ext_vector_type(8))) short  s16x8;
typedef __attribute__((ext_vector_type(4))) float  f32x4;

__device__ __forceinline__ float f4c(const float4& v, int i) {
    return i == 0 ? v.x : i == 1 ? v.y : i == 2 ? v.z : v.w;
}

__device__ __forceinline__ unsigned short f2bf(float f) {   // RNE f32->bf16
    unsigned u = __float_as_uint(f);
    u += 0x7FFFu + ((u >> 16) & 1u);
    return (unsigned short)(u >> 16);
}

__device__ __forceinline__ void split2(float v, unsigned short& h, unsigned short& l) {
    h = f2bf(v);
    float hf = __uint_as_float((unsigned)h << 16);
    l = f2bf(v - hf);
}

// ---------------------------------------------------------------------------
// f32 [M][K] -> split-bf16 A layout [M][3K] = [hi | lo | hi]. K = 2^kshift.
// ---------------------------------------------------------------------------
__global__ void cvt_splitA(const float* __restrict__ in, unsigned short* __restrict__ out,
                           int n, int kshift)
{
    int i = blockIdx.x * 256 + threadIdx.x;
    if (i >= n) return;
    unsigned short h, l;
    split2(in[i], h, l);
    int K = 1 << kshift;
    int m = i >> kshift, k = i & (K - 1);
    size_t ro = (size_t)m * 3 * K;
    out[ro + k]         = h;
    out[ro + K + k]     = l;
    out[ro + 2 * K + k] = h;
}

// ---------------------------------------------------------------------------
// f32 [K][N] -> split-bf16 B layout [N][3K] = [hi | hi | lo] (transposed).
// N-guarded (N need not be a multiple of 32). Grid ((N+31)/32, K/32), blk (32,8).
// ---------------------------------------------------------------------------
__global__ void cvtT_split(const float* __restrict__ W, unsigned short* __restrict__ WT,
                           int K, int N)
{
    __shared__ float t[32][33];
    int bx = blockIdx.x * 32;   // n
    int by = blockIdx.y * 32;   // k
    int x = threadIdx.x, y = threadIdx.y;
    #pragma unroll
    for (int i = 0; i < 4; ++i)
        t[y + 8 * i][x] = (bx + x < N) ? W[(size_t)(by + y + 8 * i) * N + bx + x] : 0.f;
    __syncthreads();
    #pragma unroll
    for (int i = 0; i < 4; ++i) {
        int n = bx + y + 8 * i;
        if (n < N) {
            unsigned short h, l;
            split2(t[x][y + 8 * i], h, l);
            size_t ro = (size_t)n * 3 * K + (by + x);
            WT[ro]         = h;
            WT[ro + K]     = h;
            WT[ro + 2 * K] = l;
        }
    }
}

// ---------------------------------------------------------------------------
// bf16 MFMA GEMM (split-bf16 accurate): 128x128 tile, BK=64, 4 waves.
// ---------------------------------------------------------------------------
__global__ __launch_bounds__(256) void gemm_mfma(
    const unsigned short* __restrict__ A0, const unsigned short* __restrict__ A1,
    const unsigned short* __restrict__ A2,
    const unsigned short* __restrict__ B0, const unsigned short* __restrict__ B1,
    const unsigned short* __restrict__ B2,
    float* __restrict__ C0, float* __restrict__ C1, float* __restrict__ C2,
    int M, int N, int K)
{
    const unsigned short* A = (blockIdx.z == 0) ? A0 : (blockIdx.z == 1) ? A1 : A2;
    const unsigned short* B = (blockIdx.z == 0) ? B0 : (blockIdx.z == 1) ? B1 : B2;
    float*                C = (blockIdx.z == 0) ? C0 : (blockIdx.z == 1) ? C1 : C2;

    __shared__ __align__(16) unsigned short sm[2 * 128 * 64];
    unsigned short* As = sm;
    unsigned short* Bs = sm + 128 * 64;

    int tid  = threadIdx.x;
    int lane = tid & 63;
    int w    = tid >> 6;
    int m0 = blockIdx.y * 128, n0 = blockIdx.x * 128;
    int wr = w >> 1, wc = w & 1;

    f32x4 acc[4][4];
    #pragma unroll
    for (int i = 0; i < 4; ++i)
        #pragma unroll
        for (int j = 0; j < 4; ++j)
            acc[i][j] = (f32x4){0.f, 0.f, 0.f, 0.f};

    const int srow = (lane >> 3);
    const int scb  = ((lane & 7) * 16) ^ (srow << 4);

    for (int kt = 0; kt < K; kt += 64) {
        __syncthreads();
        #pragma unroll
        for (int q = 0; q < 4; ++q) {
            int r = w * 32 + q * 8 + srow;
            const char* ga = (const char*)A + ((size_t)(m0 + r) * K + kt) * 2 + scb;
            const char* gb = (const char*)B + ((size_t)(n0 + r) * K + kt) * 2 + scb;
            __builtin_amdgcn_global_load_lds(
                (const __attribute__((address_space(1))) void*)ga,
                (__attribute__((address_space(3))) void*)((char*)As + (w * 32 + q * 8) * 128),
                16, 0, 0);
            __builtin_amdgcn_global_load_lds(
                (const __attribute__((address_space(1))) void*)gb,
                (__attribute__((address_space(3))) void*)((char*)Bs + (w * 32 + q * 8) * 128),
                16, 0, 0);
        }
        __syncthreads();

        #pragma unroll
        for (int kk = 0; kk < 2; ++kk) {
            int kb = kk * 64 + (lane >> 4) * 16;
            s16x8 af[4], bfr[4];
            #pragma unroll
            for (int mi = 0; mi < 4; ++mi) {
                int r = wr * 64 + mi * 16 + (lane & 15);
                af[mi] = *(const s16x8*)((const char*)As + r * 128 + (kb ^ ((r & 7) << 4)));
            }
            #pragma unroll
            for (int ni = 0; ni < 4; ++ni) {
                int r = wc * 64 + ni * 16 + (lane & 15);
                bfr[ni] = *(const s16x8*)((const char*)Bs + r * 128 + (kb ^ ((r & 7) << 4)));
            }
            #pragma unroll
            for (int mi = 0; mi < 4; ++mi)
                #pragma unroll
                for (int ni = 0; ni < 4; ++ni)
                    acc[mi][ni] = __builtin_amdgcn_mfma_f32_16x16x32_bf16(
                        af[mi], bfr[ni], acc[mi][ni], 0, 0, 0);
        }
    }

    #pragma unroll
    for (int mi = 0; mi < 4; ++mi)
        #pragma unroll
        for (int ni = 0; ni < 4; ++ni) {
            int col = n0 + wc * 64 + ni * 16 + (lane & 15);
            int rb  = m0 + wr * 64 + mi * 16 + (lane >> 4) * 4;
            #pragma unroll
            for (int j = 0; j < 4; ++j)
                C[(size_t)(rb + j) * N + col] = acc[mi][ni][j];
        }
}

// ---------------------------------------------------------------------------
// Unpack the concatenated projection tcat [LL][256]:
// cols 0-63 -> tqab2 (split-bf16 [LL][192]), 64-127 -> tkab2, 128-191 -> tgab2,
// 192-207 -> tg1 f32, 208-223 -> tg2 f32, 224-227 -> elog f32.
// ---------------------------------------------------------------------------
__global__ void unpack_cat(const float* __restrict__ tcat,
                           unsigned short* __restrict__ tqab2,
                           unsigned short* __restrict__ tkab2,
                           unsigned short* __restrict__ tgab2,
                           float* __restrict__ tg1, float* __restrict__ tg2,
                           float* __restrict__ elog)
{
    int m = blockIdx.x;
    int c = threadIdx.x;
    float vx = tcat[(size_t)m * 256 + c];
    if (c < 192) {
        unsigned short h, l;
        split2(vx, h, l);
        unsigned short* dst = (c < 64) ? tqab2 : (c < 128) ? tkab2 : tgab2;
        int cc = c & 63;
        size_t ro = (size_t)m * 192;
        dst[ro + cc]       = h;
        dst[ro + 64 + cc]  = l;
        dst[ro + 128 + cc] = h;
    } else if (c < 208) {
        tg1[(size_t)m * 16 + (c - 192)] = vx;
    } else if (c < 224) {
        tg2[(size_t)m * 16 + (c - 208)] = vx;
    } else if (c < 228) {
        elog[(size_t)m * 4 + (c - 224)] = vx;
    }
}

// ---------------------------------------------------------------------------
// 128x128 f32 GEMM, fused over z (2 triples) — gate-b (K=16).
// ---------------------------------------------------------------------------
__global__ void gemm128b(const float* __restrict__ A0, const float* __restrict__ A1,
                         const float* __restrict__ B0, const float* __restrict__ B1,
                         float* __restrict__ C0, float* __restrict__ C1,
                         int M, int N, int K)
{
    const float* A = (blockIdx.z == 0) ? A0 : A1;
    const float* B = (blockIdx.z == 0) ? B0 : B1;
    float*       C = (blockIdx.z == 0) ? C0 : C1;

    __shared__ float As[16][132];
    __shared__ float Bs[16][132];
    int tid = threadIdx.x;
    int n0 = blockIdx.x * 128;
    int m0 = blockIdx.y * 128;
    int tx = tid & 15, ty = tid >> 4;
    float acc[8][8] = {};

    for (int k0 = 0; k0 < K; k0 += 16) {
        #pragma unroll
        for (int u = 0; u < 2; ++u) {
            int lin = tid + (u << 8);
            int row = lin >> 2, q4 = lin & 3;
            float4 a = *reinterpret_cast<const float4*>(&A[(size_t)(m0 + row) * K + k0 + q4 * 4]);
            As[q4 * 4 + 0][row] = a.x;
            As[q4 * 4 + 1][row] = a.y;
            As[q4 * 4 + 2][row] = a.z;
            As[q4 * 4 + 3][row] = a.w;
        }
        #pragma unroll
        for (int u = 0; u < 2; ++u) {
            int lin = tid + (u << 8);
            int kr = lin >> 5, c4 = lin & 31;
            *reinterpret_cast<float4*>(&Bs[kr][c4 * 4]) =
                *reinterpret_cast<const float4*>(&B[(size_t)(k0 + kr) * N + n0 + c4 * 4]);
        }
        __syncthreads();
        #pragma unroll
        for (int k = 0; k < 16; ++k) {
            float4 a0 = *(const float4*)&As[k][ty * 4];
            float4 a1 = *(const float4*)&As[k][64 + ty * 4];
            float4 b0 = *(const float4*)&Bs[k][tx * 4];
            float4 b1 = *(const float4*)&Bs[k][64 + tx * 4];
            float av[8] = {a0.x, a0.y, a0.z, a0.w, a1.x, a1.y, a1.z, a1.w};
            float bv[8] = {b0.x, b0.y, b0.z, b0.w, b1.x, b1.y, b1.z, b1.w};
            #pragma unroll
            for (int i = 0; i < 8; ++i)
                #pragma unroll
                for (int j = 0; j < 8; ++j)
                    acc[i][j] = fmaf(av[i], bv[j], acc[i][j]);
        }
        __syncthreads();
    }
    #pragma unroll
    for (int i = 0; i < 8; ++i) {
        int m = m0 + ((i < 4) ? ty * 4 + i : 64 + ty * 4 + (i - 4));
        float4 c0 = make_float4(acc[i][0], acc[i][1], acc[i][2], acc[i][3]);
        float4 c1 = make_float4(acc[i][4], acc[i][5], acc[i][6], acc[i][7]);
        *reinterpret_cast<float4*>(&C[(size_t)m * N + n0 + tx * 4]) = c0;
        *reinterpret_cast<float4*>(&C[(size_t)m * N + n0 + 64 + tx * 4]) = c1;
    }
}

// ---------------------------------------------------------------------------
__device__ inline float logsig(float x) {
    return fminf(x, 0.f) - log1pf(expf(-fabsf(x)));
}

__global__ void elementwise_pre(float* __restrict__ q1, float* __restrict__ q2,
                                float* __restrict__ k2, float* __restrict__ gk1,
                                float* __restrict__ gk2,
                                const float* __restrict__ bg1, const float* __restrict__ bg2,
                                const float* __restrict__ elog, float* __restrict__ rw)
{
    int l = blockIdx.x;
    int tid = threadIdx.x;
    int w = tid >> 6, lane = tid & 63;
    int idx = l * KD_ + (w << 6) + lane;

    q1[idx] *= 0.125f;
    q2[idx] *= 0.125f;

    float kv = k2[idx];
    float m = kv;
    for (int s = 32; s >= 1; s >>= 1) m = fmaxf(m, __shfl_xor(m, s, 64));
    float ev = expf(kv - m);
    float ssum = ev;
    for (int s = 32; s >= 1; s >>= 1) ssum += __shfl_xor(ssum, s, 64);
    k2[idx] = ev / ssum;

    int bi = (w << 6) + lane;
    gk1[idx] = logsig(gk1[idx] + bg1[bi]) * (1.f / 16.f);
    gk2[idx] = logsig(gk2[idx] + bg2[bi]) * (1.f / 16.f);

    if (tid == 0) {
        float xs[4];
        float mm = -1e30f;
        for (int j = 0; j < 4; ++j) { xs[j] = elog[l * 4 + j]; mm = fmaxf(mm, xs[j]); }
        float s4 = 0.f;
        for (int j = 0; j < 4; ++j) { xs[j] = expf(xs[j] - mm); s4 += xs[j]; }
        for (int j = 0; j < 4; ++j) xs[j] /= s4;
        int arg = 0; float best = xs[0];
        for (int j = 1; j < 4; ++j) if (xs[j] > best) { best = xs[j]; arg = j; }
        for (int j = 0; j < 4; ++j) rw[l * 4 + j] = (j == arg) ? xs[j] : 0.f;
    }
}

// ---------------------------------------------------------------------------
// Phase 1: chunk_kv + decay. Block = (p,h,c) — p fastest for L2 sharing.
// Register-resident cumsum: thread owns (d = tid&63, seg = tid>>6).
// ---------------------------------------------------------------------------
__global__ void gla_kv(const float* __restrict__ k1, const float* __restrict__ k2,
                       const float* __restrict__ gk1, const float* __restrict__ gk2,
                       const float* __restrict__ v, const float* __restrict__ rw,
                       float* __restrict__ kv_all, float* __restrict__ decay_all)
{
    int p = blockIdx.x, h = blockIdx.y, c = blockIdx.z;
    const float* kp = (p == 0) ? k1 : k2;
    const float* gp = (p == 0) ? gk1 : gk2;

    __shared__ float bufK[64][68];   // kg TRANSPOSED [d][t]
    __shared__ float bufV[64][68];   // v [t][e]
    __shared__ float glast[64];
    __shared__ float wrow[64];
    __shared__ float segsum[4][64];

    int tid = threadIdx.x;
    int tx = tid & 15, ty = tid >> 4;
    int e0 = tx * 4;
    int d = tid & 63, seg = tid >> 6;

    float gkv[16], kvv[16], vv_[16];
    #pragma unroll
    for (int i = 0; i < 16; ++i) {
        size_t base = (size_t)(c * 64 + seg * 16 + i) * KD_ + (h << 6) + d;
        gkv[i] = gp[base];
        kvv[i] = kp[base];
        vv_[i] = v[base];
    }
    if (tid < 64) {
        int lg = c * 64 + tid;
        wrow[tid] = (p == 0) ? 1.f : rw[lg * 4 + (p - 1)];
    }
    __syncthreads();

    {   // masked register cumsum
        float s = 0.f;
        #pragma unroll
        for (int i = 0; i < 16; ++i) {
            int t = seg * 16 + i;
            float xg = gkv[i];
            if (p > 0 && !(wrow[t] > 0.f)) xg = 0.f;
            s += xg;
            gkv[i] = s;
        }
        segsum[seg][d] = s;
    }
    __syncthreads();
    {
        float off = 0.f, tot = 0.f;
        #pragma unroll
        for (int ss = 0; ss < 4; ++ss) {
            float x = segsum[ss][d];
            tot += x;
            if (ss < seg) off += x;
        }
        if (seg == 0) glast[d] = tot;
        #pragma unroll
        for (int i = 0; i < 16; ++i) {
            int t = seg * 16 + i;
            float g = off + gkv[i];
            bufK[d][t] = kvv[i] * wrow[t] * expf(-g);
            bufV[t][d] = vv_[i];
        }
    }
    __syncthreads();

    {   // kv[d][e] = exp(glast[d]) * sum_t kg[t][d] v[t][e]
        float acc[4][4] = {};
        for (int t0v = 0; t0v < 64; t0v += 4) {
            float4 kk[4];
            #pragma unroll
            for (int i = 0; i < 4; ++i) kk[i] = *(const float4*)&bufK[ty + 16 * i][t0v];
            #pragma unroll
            for (int ss = 0; ss < 4; ++ss) {
                float4 vv = *(const float4*)&bufV[t0v + ss][e0];
                #pragma unroll
                for (int i = 0; i < 4; ++i) {
                    float ki = f4c(kk[i], ss);
                    acc[i][0] = fmaf(ki, vv.x, acc[i][0]);
                    acc[i][1] = fmaf(ki, vv.y, acc[i][1]);
                    acc[i][2] = fmaf(ki, vv.z, acc[i][2]);
                    acc[i][3] = fmaf(ki, vv.w, acc[i][3]);
                }
            }
        }
        size_t base = (size_t)((c * 8 + h) * 5 + p) * 4096;
        #pragma unroll
        for (int i = 0; i < 4; ++i) {
            int dd = ty + 16 * i;
            float dec = expf(glast[dd]);
            #pragma unroll
            for (int j = 0; j < 4; ++j)
                kv_all[base + dd * 64 + e0 + j] = acc[i][j] * dec;
        }
        if (tid < 64) decay_all[(size_t)((c * 8 + h) * 5 + p) * 64 + tid] = expf(glast[tid]);
    }
}

// ---------------------------------------------------------------------------
// Inter-chunk state scan: elementwise, in place over kv_all.
// ---------------------------------------------------------------------------
__global__ void gla_state_scan(float* __restrict__ kv, const float* __restrict__ decay)
{
    int gid = blockIdx.x * 256 + threadIdx.x;
    int sub = gid >> 6;
    const size_t stride = 8 * 5 * 64 * 64;
    float S = 0.f;
    float kvv = kv[gid];
    for (int c = 0; c < 64; ++c) {
        size_t o = (size_t)c * stride + gid;
        float nxt = (c < 63) ? kv[o + stride] : 0.f;
        float dec = decay[c * 2560 + sub];
        kv[o] = S;
        S = fmaf(dec, S, kvv);
        kvv = nxt;
    }
}

// ---------------------------------------------------------------------------
// Phase 2: full per-pass output. Block = (p,h,c) — p fastest for L2 sharing.
// ---------------------------------------------------------------------------
__global__ void gla_o(const float* __restrict__ q1, const float* __restrict__ q2,
                      const float* __restrict__ k1, const float* __restrict__ k2,
                      const float* __restrict__ gk1, const float* __restrict__ gk2,
                      const float* __restrict__ v, const float* __restrict__ rw,
                      const float* __restrict__ Spre, float* __restrict__ o_parts)
{
    int p = blockIdx.x, h = blockIdx.y, c = blockIdx.z;
    const float* qp = (p == 0) ? q1 : q2;
    const float* kp = (p == 0) ? k1 : k2;
    const float* gp = (p == 0) ? gk1 : gk2;

    __shared__ float bufA[64][68];   // qg -> later v
    __shared__ float bufB[64][68];   // kg [d][t] -> later S [d][e]
    __shared__ float bufC[64][68];   // A[t][s]
    __shared__ float wrow[64];
    __shared__ float segsum[4][64];

    int tid = threadIdx.x;
    int tx = tid & 15, ty = tid >> 4;
    int t0 = ty * 4, e0 = tx * 4;
    int d = tid & 63, seg = tid >> 6;

    float acc_o[4][4] = {};

    {   // prefetch gk/q/k; cumsum in registers; stage qg/kg
        float gkv[16], qv[16], kvv[16];
        #pragma unroll
        for (int i = 0; i < 16; ++i) {
            size_t base = (size_t)(c * 64 + seg * 16 + i) * KD_ + (h << 6) + d;
            gkv[i] = gp[base];
            qv[i]  = qp[base];
            kvv[i] = kp[base];
        }
        if (tid < 64) {
            int lg = c * 64 + tid;
            wrow[tid] = (p == 0) ? 1.f : rw[lg * 4 + (p - 1)];
        }
        __syncthreads();

        float s = 0.f;
        #pragma unroll
        for (int i = 0; i < 16; ++i) {
            int t = seg * 16 + i;
            float xg = gkv[i];
            if (p > 0 && !(wrow[t] > 0.f)) xg = 0.f;
            s += xg;
            gkv[i] = s;
        }
        segsum[seg][d] = s;
        __syncthreads();

        float off = 0.f;
        for (int ss = 0; ss < seg; ++ss) off += segsum[ss][d];
        #pragma unroll
        for (int i = 0; i < 16; ++i) {
            int t = seg * 16 + i;
            float g = off + gkv[i];
            float wv = wrow[t];
            bufA[t][d] = qv[i] * wv * expf(g);
            bufB[d][t] = kvv[i] * wv * expf(-g);
        }
    }

    float Sv[16];
    {
        size_t sbase = (size_t)((c * 8 + h) * 5 + p) * 4096;
        #pragma unroll
        for (int i = 0; i < 16; ++i) Sv[i] = Spre[sbase + tid + (i << 8)];
    }
    __syncthreads();

    {   // A[t][s] = tril dot_d(qg[t], kg[s]) -> bufC
        if (e0 <= t0 + 3) {
            float acc[4][4] = {};
            for (int d0 = 0; d0 < 64; d0 += 4) {
                float4 a[4];
                #pragma unroll
                for (int i = 0; i < 4; ++i) a[i] = *(const float4*)&bufA[t0 + i][d0];
                #pragma unroll
                for (int dd = 0; dd < 4; ++dd) {
                    float4 bv = *(const float4*)&bufB[d0 + dd][e0];
                    #pragma unroll
                    for (int i = 0; i < 4; ++i) {
                        float aa = f4c(a[i], dd);
                        acc[i][0] = fmaf(aa, bv.x, acc[i][0]);
                        acc[i][1] = fmaf(aa, bv.y, acc[i][1]);
                        acc[i][2] = fmaf(aa, bv.z, acc[i][2]);
                        acc[i][3] = fmaf(aa, bv.w, acc[i][3]);
                    }
                }
            }
            #pragma unroll
            for (int i = 0; i < 4; ++i)
                #pragma unroll
                for (int j = 0; j < 4; ++j)
                    bufC[t0 + i][e0 + j] = (e0 + j <= t0 + i) ? acc[i][j] : 0.f;
        }
    }
    __syncthreads();

    float vv_[16];
    {
        #pragma unroll
        for (int i = 0; i < 16; ++i) {
            int idx = tid + (i << 8);
            bufB[idx >> 6][idx & 63] = Sv[i];
        }
        #pragma unroll
        for (int i = 0; i < 16; ++i) {
            size_t base = (size_t)(c * 64 + seg * 16 + i) * KD_ + (h << 6) + d;
            vv_[i] = v[base];
        }
    }
    __syncthreads();

    {   // o2 = qg @ S
        for (int d0 = 0; d0 < 64; d0 += 4) {
            float4 a[4];
            #pragma unroll
            for (int i = 0; i < 4; ++i) a[i] = *(const float4*)&bufA[t0 + i][d0];
            #pragma unroll
            for (int dd = 0; dd < 4; ++dd) {
                float4 sv = *(const float4*)&bufB[d0 + dd][e0];
                #pragma unroll
                for (int i = 0; i < 4; ++i) {
                    float aa = f4c(a[i], dd);
                    acc_o[i][0] = fmaf(aa, sv.x, acc_o[i][0]);
                    acc_o[i][1] = fmaf(aa, sv.y, acc_o[i][1]);
                    acc_o[i][2] = fmaf(aa, sv.z, acc_o[i][2]);
                    acc_o[i][3] = fmaf(aa, sv.w, acc_o[i][3]);
                }
            }
        }
    }
    __syncthreads();

    #pragma unroll
    for (int i = 0; i < 16; ++i)        // v regs -> bufA (qg dead)
        bufA[seg * 16 + i][d] = vv_[i];
    __syncthreads();

    {   // o1 = tril(A) @ v
        for (int s0 = 0; s0 <= t0 + 3; s0 += 4) {
            float4 a[4];
            #pragma unroll
            for (int i = 0; i < 4; ++i) a[i] = *(const float4*)&bufC[t0 + i][s0];
            #pragma unroll
            for (int ss = 0; ss < 4; ++ss) {
                float4 vv = *(const float4*)&bufA[s0 + ss][e0];
                #pragma unroll
                for (int i = 0; i < 4; ++i) {
                    float aa = f4c(a[i], ss);
                    acc_o[i][0] = fmaf(aa, vv.x, acc_o[i][0]);
                    acc_o[i][1] = fmaf(aa, vv.y, acc_o[i][1]);
                    acc_o[i][2] = fmaf(aa, vv.z, acc_o[i][2]);
                    acc_o[i][3] = fmaf(aa, vv.w, acc_o[i][3]);
                }
            }
        }
    }

    size_t pbase = (size_t)p * ((size_t)LL * KD_);
    #pragma unroll
    for (int i = 0; i < 4; ++i)
        #pragma unroll
        for (int j = 0; j < 4; ++j)
            o_parts[pbase + (size_t)(c * 64 + t0 + i) * KD_ + (h << 6) + e0 + j] = acc_o[i][j];
}

// ---------------------------------------------------------------------------
// Post: sum 5 partials, RMS-norm, * norm_w, * silu(g); emit split-bf16 A.
// ---------------------------------------------------------------------------
__global__ void postnorm(const float* __restrict__ o_parts, const float* __restrict__ gbuf,
                         const float* __restrict__ norm_w, unsigned short* __restrict__ og2)
{
    int l = blockIdx.x;
    int tid = threadIdx.x;
    int w = tid >> 6, lane = tid & 63;
    int bi = (w << 6) + lane;
    int idx = l * KD_ + bi;
    const size_t LKD = (size_t)LL * KD_;
    float o = 0.f;
    #pragma unroll
    for (int p = 0; p < 5; ++p) o += o_parts[(size_t)p * LKD + idx];
    float ss = o * o;
    for (int s = 32; s >= 1; s >>= 1) ss += __shfl_xor(ss, s, 64);
    float r = rsqrtf(ss * (1.f / 64.f) + 1e-5f);
    float val = o * r * norm_w[lane];
    float gv = gbuf[idx];
    val *= gv / (1.f + expf(-gv));
    unsigned short h, lo;
    split2(val, h, lo);
    size_t ro = (size_t)l * (3 * KD_) + bi;
    og2[ro]           = h;
    og2[ro + KD_]     = lo;
    og2[ro + 2 * KD_] = h;
}

// ---------------------------------------------------------------------------
extern "C" void kernel_launch(void* const* d_in, const int* in_sizes, int n_in,
                              void* d_out, int out_size, void* d_ws, size_t ws_size,
                              hipStream_t stream)
{
    const float* x    = (const float*)d_in[0];
    const float* Wq   = (const float*)d_in[1];
    const float* Wk   = (const float*)d_in[2];
    const float* Wv   = (const float*)d_in[3];
    const float* Wqa  = (const float*)d_in[4];
    const float* Wqb  = (const float*)d_in[5];
    const float* Wka  = (const float*)d_in[6];
    const float* Wkb  = (const float*)d_in[7];
    const float* Wg1a = (const float*)d_in[8];
    const float* Wg1b = (const float*)d_in[9];
    const float* bg1  = (const float*)d_in[10];
    const float* Wg2a = (const float*)d_in[11];
    const float* Wg2b = (const float*)d_in[12];
    const float* bg2  = (const float*)d_in[13];
    const float* We   = (const float*)d_in[14];
    const float* Wga  = (const float*)d_in[15];
    const float* Wgb  = (const float*)d_in[16];
    const float* normw= (const float*)d_in[17];
    const float* Wo   = (const float*)d_in[18];

    float* ws = (float*)d_ws;
    const size_t LKD = (size_t)LL * KD_;   // 2M floats
    float* q1   = ws;
    float* k1   = q1 + LKD;
    float* v    = k1 + LKD;
    float* q2   = v  + LKD;
    float* k2   = q2 + LKD;
    float* gk1  = k2 + LKD;
    float* gk2  = gk1 + LKD;
    float* o_parts = gk2 + LKD;                // 5 x LKD
    float* tg1  = o_parts + 5 * LKD;           // 4096*16
    float* tg2  = tg1 + (size_t)LL * 16;
    float* elog = tg2 + (size_t)LL * 16;       // 4096*4
    float* rw   = elog + (size_t)LL * 4;
    float* kv_all    = rw + (size_t)LL * 4;                    // 10.49M f32
    float* decay_all = kv_all + (size_t)64 * 8 * 5 * 64 * 64;  // 163840 f32

    unsigned short* bp = (unsigned short*)(decay_all + 163840);
    unsigned short* WqT2   = bp; bp += (size_t)512 * 3072;
    unsigned short* WkT2   = bp; bp += (size_t)512 * 3072;
    unsigned short* WvT2   = bp; bp += (size_t)512 * 3072;
    unsigned short* WoT2   = bp; bp += (size_t)1024 * 1536;
    unsigned short* WqbT2  = bp; bp += (size_t)512 * 192;
    unsigned short* WkbT2  = bp; bp += (size_t)512 * 192;
    unsigned short* WgbT2  = bp; bp += (size_t)512 * 192;
    unsigned short* WcatT2 = bp; bp += (size_t)256 * 3072;     // concat LoRA-a/gate-a/router
    unsigned short* tqab2  = bp; bp += (size_t)LL * 192;
    unsigned short* tkab2  = bp; bp += (size_t)LL * 192;
    unsigned short* tgab2  = bp; bp += (size_t)LL * 192;
    float* tcat = (float*)bp;                                  // 4096*256 f32

    // time-multiplexed aliases of kv_all (disjoint lifetimes):
    unsigned short* xb2 = (unsigned short*)kv_all;   // [4096][3072]; dead before gla_kv
    unsigned short* og2 = (unsigned short*)kv_all;   // [4096][1536]; live after gla_o
    float* gbuf = k1;                                // reuse after gla_o

    dim3 blk(256);
    dim3 tblk(32, 8);

    // ---- split conversions ----
    cvt_splitA<<<dim3((LL * 1024 + 255) / 256), blk, 0, stream>>>(x, xb2, LL * 1024, 10);
    cvtT_split<<<dim3(16, 32), tblk, 0, stream>>>(Wq, WqT2, 1024, 512);
    cvtT_split<<<dim3(16, 32), tblk, 0, stream>>>(Wk, WkT2, 1024, 512);
    cvtT_split<<<dim3(16, 32), tblk, 0, stream>>>(Wv, WvT2, 1024, 512);
    cvtT_split<<<dim3(32, 16), tblk, 0, stream>>>(Wo, WoT2, 512, 1024);
    cvtT_split<<<dim3(16, 2),  tblk, 0, stream>>>(Wqb, WqbT2, 64, 512);
    cvtT_split<<<dim3(16, 2),  tblk, 0, stream>>>(Wkb, WkbT2, 64, 512);
    cvtT_split<<<dim3(16, 2),  tblk, 0, stream>>>(Wgb, WgbT2, 64, 512);

    // concat small-projection weights into WcatT2 rows (pad rows zeroed)
    hipMemsetAsync(WcatT2 + (size_t)228 * 3072, 0, (size_t)(256 - 228) * 3072 * 2, stream);
    cvtT_split<<<dim3(2, 32), tblk, 0, stream>>>(Wqa,  WcatT2 + (size_t)0   * 3072, 1024, 64);
    cvtT_split<<<dim3(2, 32), tblk, 0, stream>>>(Wka,  WcatT2 + (size_t)64  * 3072, 1024, 64);
    cvtT_split<<<dim3(2, 32), tblk, 0, stream>>>(Wga,  WcatT2 + (size_t)128 * 3072, 1024, 64);
    cvtT_split<<<dim3(1, 32), tblk, 0, stream>>>(Wg1a, WcatT2 + (size_t)192 * 3072, 1024, 16);
    cvtT_split<<<dim3(1, 32), tblk, 0, stream>>>(Wg2a, WcatT2 + (size_t)208 * 3072, 1024, 16);
    cvtT_split<<<dim3(1, 32), tblk, 0, stream>>>(We,   WcatT2 + (size_t)224 * 3072, 1024, 4);

    // ---- QKV (split MFMA, K'=3072, fused) ----
    gemm_mfma<<<dim3(4, 32, 3), blk, 0, stream>>>(xb2, xb2, xb2, WqT2, WkT2, WvT2,
                                                  q1, k1, v, LL, KD_, 3072);

    // ---- concatenated LoRA-a / gate-a / router (split MFMA, N=256) ----
    gemm_mfma<<<dim3(2, 32, 1), blk, 0, stream>>>(xb2, xb2, xb2, WcatT2, WcatT2, WcatT2,
                                                  tcat, tcat, tcat, LL, 256, 3072);
    unpack_cat<<<dim3(LL), blk, 0, stream>>>(tcat, tqab2, tkab2, tgab2, tg1, tg2, elog);

    // ---- LoRA-b q2,k2 (split MFMA, K'=192) ----
    gemm_mfma<<<dim3(4, 32, 2), blk, 0, stream>>>(tqab2, tkab2, tkab2, WqbT2, WkbT2, WkbT2,
                                                  q2, k2, k2, LL, KD_, 192);
    // ---- gate-b (f32, K=16, fused z=2) ----
    gemm128b<<<dim3(4, 32, 2), blk, 0, stream>>>(tg1, tg2, Wg1b, Wg2b, gk1, gk2, LL, KD_, 16);

    elementwise_pre<<<LL, 512, 0, stream>>>(q1, q2, k2, gk1, gk2, bg1, bg2, elog, rw);

    // ---- GLA: kv -> scan -> o (p fastest-varying for L2 sharing) ----
    gla_kv<<<dim3(5, 8, 64), blk, 0, stream>>>(k1, k2, gk1, gk2, v, rw, kv_all, decay_all);
    gla_state_scan<<<dim3(640), blk, 0, stream>>>(kv_all, decay_all);
    gla_o<<<dim3(5, 8, 64), blk, 0, stream>>>(q1, q2, k1, k2, gk1, gk2, v, rw,
                                              kv_all, o_parts);

    // ---- gating projection (split MFMA; k1 free after gla_o) ----
    gemm_mfma<<<dim3(4, 32, 1), blk, 0, stream>>>(tgab2, tgab2, tgab2, WgbT2, WgbT2, WgbT2,
                                                  gbuf, gbuf, gbuf, LL, KD_, 192);

    postnorm<<<LL, 512, 0, stream>>>(o_parts, gbuf, normw, og2);

    // ---- output projection (split MFMA, K'=1536) ----
    gemm_mfma<<<dim3(8, 32, 1), blk, 0, stream>>>(og2, og2, og2, WoT2, WoT2, WoT2,
                                                  (float*)d_out, (float*)d_out, (float*)d_out,
                                                  LL, 1024, 1536);
}

// Round 10
// 334.456 us; speedup vs baseline: 8.5013x; 1.1712x over previous
//
#include <hip/hip_runtime.h>
#include <math.h>

#define LL   4096
#define HH   8
#define DK_  64
#define DV_  64
#define KD_  512
#define NEXP 4

typedef __attribute__((ext_vector_type(8))) short  s16x8;
typedef __attribute__((ext_vector_type(4))) float  f32x4;

__device__ __forceinline__ float f4c(const float4& v, int i) {
    return i == 0 ? v.x : i == 1 ? v.y : i == 2 ? v.z : v.w;
}

__device__ __forceinline__ unsigned short f2bf(float f) {   // RNE f32->bf16
    unsigned u = __float_as_uint(f);
    u += 0x7FFFu + ((u >> 16) & 1u);
    return (unsigned short)(u >> 16);
}

__device__ __forceinline__ void split2(float v, unsigned short& h, unsigned short& l) {
    h = f2bf(v);
    float hf = __uint_as_float((unsigned)h << 16);
    l = f2bf(v - hf);
}

// ---------------------------------------------------------------------------
// f32 [M][K] -> split-bf16 A layout [M][3K] = [hi | lo | hi]. K = 2^kshift.
// ---------------------------------------------------------------------------
__global__ void cvt_splitA(const float* __restrict__ in, unsigned short* __restrict__ out,
                           int n, int kshift)
{
    int i = blockIdx.x * 256 + threadIdx.x;
    if (i >= n) return;
    unsigned short h, l;
    split2(in[i], h, l);
    int K = 1 << kshift;
    int m = i >> kshift, k = i & (K - 1);
    size_t ro = (size_t)m * 3 * K;
    out[ro + k]         = h;
    out[ro + K + k]     = l;
    out[ro + 2 * K + k] = h;
}

// ---------------------------------------------------------------------------
// f32 [K][N] -> split-bf16 B layout [N][3K] = [hi | hi | lo] (transposed).
// N-guarded. Grid ((N+31)/32, K/32), blk (32,8).
// ---------------------------------------------------------------------------
__global__ void cvtT_split(const float* __restrict__ W, unsigned short* __restrict__ WT,
                           int K, int N)
{
    __shared__ float t[32][33];
    int bx = blockIdx.x * 32;   // n
    int by = blockIdx.y * 32;   // k
    int x = threadIdx.x, y = threadIdx.y;
    #pragma unroll
    for (int i = 0; i < 4; ++i)
        t[y + 8 * i][x] = (bx + x < N) ? W[(size_t)(by + y + 8 * i) * N + bx + x] : 0.f;
    __syncthreads();
    #pragma unroll
    for (int i = 0; i < 4; ++i) {
        int n = bx + y + 8 * i;
        if (n < N) {
            unsigned short h, l;
            split2(t[x][y + 8 * i], h, l);
            size_t ro = (size_t)n * 3 * K + (by + x);
            WT[ro]         = h;
            WT[ro + K]     = h;
            WT[ro + 2 * K] = l;
        }
    }
}

// ---------------------------------------------------------------------------
// bf16 MFMA GEMM (split-bf16 accurate): 128x128 tile, BK=64, 4 waves.
// ---------------------------------------------------------------------------
__global__ __launch_bounds__(256) void gemm_mfma(
    const unsigned short* __restrict__ A0, const unsigned short* __restrict__ A1,
    const unsigned short* __restrict__ A2,
    const unsigned short* __restrict__ B0, const unsigned short* __restrict__ B1,
    const unsigned short* __restrict__ B2,
    float* __restrict__ C0, float* __restrict__ C1, float* __restrict__ C2,
    int M, int N, int K)
{
    const unsigned short* A = (blockIdx.z == 0) ? A0 : (blockIdx.z == 1) ? A1 : A2;
    const unsigned short* B = (blockIdx.z == 0) ? B0 : (blockIdx.z == 1) ? B1 : B2;
    float*                C = (blockIdx.z == 0) ? C0 : (blockIdx.z == 1) ? C1 : C2;

    __shared__ __align__(16) unsigned short sm[2 * 128 * 64];
    unsigned short* As = sm;
    unsigned short* Bs = sm + 128 * 64;

    int tid  = threadIdx.x;
    int lane = tid & 63;
    int w    = tid >> 6;
    int m0 = blockIdx.y * 128, n0 = blockIdx.x * 128;
    int wr = w >> 1, wc = w & 1;

    f32x4 acc[4][4];
    #pragma unroll
    for (int i = 0; i < 4; ++i)
        #pragma unroll
        for (int j = 0; j < 4; ++j)
            acc[i][j] = (f32x4){0.f, 0.f, 0.f, 0.f};

    const int srow = (lane >> 3);
    const int scb  = ((lane & 7) * 16) ^ (srow << 4);

    for (int kt = 0; kt < K; kt += 64) {
        __syncthreads();
        #pragma unroll
        for (int q = 0; q < 4; ++q) {
            int r = w * 32 + q * 8 + srow;
            const char* ga = (const char*)A + ((size_t)(m0 + r) * K + kt) * 2 + scb;
            const char* gb = (const char*)B + ((size_t)(n0 + r) * K + kt) * 2 + scb;
            __builtin_amdgcn_global_load_lds(
                (const __attribute__((address_space(1))) void*)ga,
                (__attribute__((address_space(3))) void*)((char*)As + (w * 32 + q * 8) * 128),
                16, 0, 0);
            __builtin_amdgcn_global_load_lds(
                (const __attribute__((address_space(1))) void*)gb,
                (__attribute__((address_space(3))) void*)((char*)Bs + (w * 32 + q * 8) * 128),
                16, 0, 0);
        }
        __syncthreads();

        #pragma unroll
        for (int kk = 0; kk < 2; ++kk) {
            int kb = kk * 64 + (lane >> 4) * 16;
            s16x8 af[4], bfr[4];
            #pragma unroll
            for (int mi = 0; mi < 4; ++mi) {
                int r = wr * 64 + mi * 16 + (lane & 15);
                af[mi] = *(const s16x8*)((const char*)As + r * 128 + (kb ^ ((r & 7) << 4)));
            }
            #pragma unroll
            for (int ni = 0; ni < 4; ++ni) {
                int r = wc * 64 + ni * 16 + (lane & 15);
                bfr[ni] = *(const s16x8*)((const char*)Bs + r * 128 + (kb ^ ((r & 7) << 4)));
            }
            #pragma unroll
            for (int mi = 0; mi < 4; ++mi)
                #pragma unroll
                for (int ni = 0; ni < 4; ++ni)
                    acc[mi][ni] = __builtin_amdgcn_mfma_f32_16x16x32_bf16(
                        af[mi], bfr[ni], acc[mi][ni], 0, 0, 0);
        }
    }

    #pragma unroll
    for (int mi = 0; mi < 4; ++mi)
        #pragma unroll
        for (int ni = 0; ni < 4; ++ni) {
            int col = n0 + wc * 64 + ni * 16 + (lane & 15);
            int rb  = m0 + wr * 64 + mi * 16 + (lane >> 4) * 4;
            #pragma unroll
            for (int j = 0; j < 4; ++j)
                C[(size_t)(rb + j) * N + col] = acc[mi][ni][j];
        }
}

// ---------------------------------------------------------------------------
// Unpack the concatenated projection tcat [LL][256].
// ---------------------------------------------------------------------------
__global__ void unpack_cat(const float* __restrict__ tcat,
                           unsigned short* __restrict__ tqab2,
                           unsigned short* __restrict__ tkab2,
                           unsigned short* __restrict__ tgab2,
                           float* __restrict__ tg1, float* __restrict__ tg2,
                           float* __restrict__ elog)
{
    int m = blockIdx.x;
    int c = threadIdx.x;
    float vx = tcat[(size_t)m * 256 + c];
    if (c < 192) {
        unsigned short h, l;
        split2(vx, h, l);
        unsigned short* dst = (c < 64) ? tqab2 : (c < 128) ? tkab2 : tgab2;
        int cc = c & 63;
        size_t ro = (size_t)m * 192;
        dst[ro + cc]       = h;
        dst[ro + 64 + cc]  = l;
        dst[ro + 128 + cc] = h;
    } else if (c < 208) {
        tg1[(size_t)m * 16 + (c - 192)] = vx;
    } else if (c < 224) {
        tg2[(size_t)m * 16 + (c - 208)] = vx;
    } else if (c < 228) {
        elog[(size_t)m * 4 + (c - 224)] = vx;
    }
}

// ---------------------------------------------------------------------------
// 128x128 f32 GEMM, fused over z (2 triples) — gate-b (K=16).
// ---------------------------------------------------------------------------
__global__ void gemm128b(const float* __restrict__ A0, const float* __restrict__ A1,
                         const float* __restrict__ B0, const float* __restrict__ B1,
                         float* __restrict__ C0, float* __restrict__ C1,
                         int M, int N, int K)
{
    const float* A = (blockIdx.z == 0) ? A0 : A1;
    const float* B = (blockIdx.z == 0) ? B0 : B1;
    float*       C = (blockIdx.z == 0) ? C0 : C1;

    __shared__ float As[16][132];
    __shared__ float Bs[16][132];
    int tid = threadIdx.x;
    int n0 = blockIdx.x * 128;
    int m0 = blockIdx.y * 128;
    int tx = tid & 15, ty = tid >> 4;
    float acc[8][8] = {};

    for (int k0 = 0; k0 < K; k0 += 16) {
        #pragma unroll
        for (int u = 0; u < 2; ++u) {
            int lin = tid + (u << 8);
            int row = lin >> 2, q4 = lin & 3;
            float4 a = *reinterpret_cast<const float4*>(&A[(size_t)(m0 + row) * K + k0 + q4 * 4]);
            As[q4 * 4 + 0][row] = a.x;
            As[q4 * 4 + 1][row] = a.y;
            As[q4 * 4 + 2][row] = a.z;
            As[q4 * 4 + 3][row] = a.w;
        }
        #pragma unroll
        for (int u = 0; u < 2; ++u) {
            int lin = tid + (u << 8);
            int kr = lin >> 5, c4 = lin & 31;
            *reinterpret_cast<float4*>(&Bs[kr][c4 * 4]) =
                *reinterpret_cast<const float4*>(&B[(size_t)(k0 + kr) * N + n0 + c4 * 4]);
        }
        __syncthreads();
        #pragma unroll
        for (int k = 0; k < 16; ++k) {
            float4 a0 = *(const float4*)&As[k][ty * 4];
            float4 a1 = *(const float4*)&As[k][64 + ty * 4];
            float4 b0 = *(const float4*)&Bs[k][tx * 4];
            float4 b1 = *(const float4*)&Bs[k][64 + tx * 4];
            float av[8] = {a0.x, a0.y, a0.z, a0.w, a1.x, a1.y, a1.z, a1.w};
            float bv[8] = {b0.x, b0.y, b0.z, b0.w, b1.x, b1.y, b1.z, b1.w};
            #pragma unroll
            for (int i = 0; i < 8; ++i)
                #pragma unroll
                for (int j = 0; j < 8; ++j)
                    acc[i][j] = fmaf(av[i], bv[j], acc[i][j]);
        }
        __syncthreads();
    }
    #pragma unroll
    for (int i = 0; i < 8; ++i) {
        int m = m0 + ((i < 4) ? ty * 4 + i : 64 + ty * 4 + (i - 4));
        float4 c0 = make_float4(acc[i][0], acc[i][1], acc[i][2], acc[i][3]);
        float4 c1 = make_float4(acc[i][4], acc[i][5], acc[i][6], acc[i][7]);
        *reinterpret_cast<float4*>(&C[(size_t)m * N + n0 + tx * 4]) = c0;
        *reinterpret_cast<float4*>(&C[(size_t)m * N + n0 + 64 + tx * 4]) = c1;
    }
}

// ---------------------------------------------------------------------------
__device__ inline float logsig(float x) {
    return fminf(x, 0.f) - log1pf(expf(-fabsf(x)));
}

__global__ void elementwise_pre(float* __restrict__ q1, float* __restrict__ q2,
                                float* __restrict__ k2, float* __restrict__ gk1,
                                float* __restrict__ gk2,
                                const float* __restrict__ bg1, const float* __restrict__ bg2,
                                const float* __restrict__ elog, float* __restrict__ rw)
{
    int l = blockIdx.x;
    int tid = threadIdx.x;
    int w = tid >> 6, lane = tid & 63;
    int idx = l * KD_ + (w << 6) + lane;

    q1[idx] *= 0.125f;
    q2[idx] *= 0.125f;

    float kv = k2[idx];
    float m = kv;
    for (int s = 32; s >= 1; s >>= 1) m = fmaxf(m, __shfl_xor(m, s, 64));
    float ev = expf(kv - m);
    float ssum = ev;
    for (int s = 32; s >= 1; s >>= 1) ssum += __shfl_xor(ssum, s, 64);
    k2[idx] = ev / ssum;

    int bi = (w << 6) + lane;
    gk1[idx] = logsig(gk1[idx] + bg1[bi]) * (1.f / 16.f);
    gk2[idx] = logsig(gk2[idx] + bg2[bi]) * (1.f / 16.f);

    if (tid == 0) {
        float xs[4];
        float mm = -1e30f;
        for (int j = 0; j < 4; ++j) { xs[j] = elog[l * 4 + j]; mm = fmaxf(mm, xs[j]); }
        float s4 = 0.f;
        for (int j = 0; j < 4; ++j) { xs[j] = expf(xs[j] - mm); s4 += xs[j]; }
        for (int j = 0; j < 4; ++j) xs[j] /= s4;
        int arg = 0; float best = xs[0];
        for (int j = 1; j < 4; ++j) if (xs[j] > best) { best = xs[j]; arg = j; }
        for (int j = 0; j < 4; ++j) rw[l * 4 + j] = (j == arg) ? xs[j] : 0.f;
    }
}

// ---------------------------------------------------------------------------
// Phase 1: chunk_kv + decay via split-bf16 MFMA (f32-accurate; kv feeds the
// 64-step scan so errors would compound). Block = (p,h,c).
// kv[d][e] = exp(glast[d]) * sum_t kg[t][d] v[t][e]  (contraction over t).
// A-op = kgT [d][t-split 192], B-op = vT [e][t-split 192].
// ---------------------------------------------------------------------------
__global__ void gla_kv(const float* __restrict__ k1, const float* __restrict__ k2,
                       const float* __restrict__ gk1, const float* __restrict__ gk2,
                       const float* __restrict__ v, const float* __restrict__ rw,
                       float* __restrict__ kv_all, float* __restrict__ decay_all)
{
    int p = blockIdx.x, h = blockIdx.y, c = blockIdx.z;
    const float* kp = (p == 0) ? k1 : k2;
    const float* gp = (p == 0) ? gk1 : gk2;

    __shared__ __align__(16) unsigned short kgT[64][200];  // [d][hi|lo|hi along t]
    __shared__ __align__(16) unsigned short vT[64][200];   // [e][hi|hi|lo along t]
    __shared__ float glast[64];
    __shared__ float wrow[64];
    __shared__ float segsum[4][64];

    int tid = threadIdx.x;
    int lane = tid & 63, w = tid >> 6;
    int d = lane, seg = w;

    float gkv[16], kvv[16], vv_[16];
    #pragma unroll
    for (int i = 0; i < 16; ++i) {
        size_t base = (size_t)(c * 64 + seg * 16 + i) * KD_ + (h << 6) + d;
        gkv[i] = gp[base];
        kvv[i] = kp[base];
        vv_[i] = v[base];
    }
    if (tid < 64) {
        int lg = c * 64 + tid;
        wrow[tid] = (p == 0) ? 1.f : rw[lg * 4 + (p - 1)];
    }
    __syncthreads();

    {   // masked register cumsum
        float s = 0.f;
        #pragma unroll
        for (int i = 0; i < 16; ++i) {
            int t = seg * 16 + i;
            float xg = gkv[i];
            if (p > 0 && !(wrow[t] > 0.f)) xg = 0.f;
            s += xg;
            gkv[i] = s;
        }
        segsum[seg][d] = s;
    }
    __syncthreads();
    {
        float off = 0.f, tot = 0.f;
        #pragma unroll
        for (int ss = 0; ss < 4; ++ss) {
            float x = segsum[ss][d];
            tot += x;
            if (ss < seg) off += x;
        }
        if (seg == 0) glast[d] = tot;
        #pragma unroll
        for (int i = 0; i < 16; ++i) {
            int t = seg * 16 + i;
            float g = off + gkv[i];
            float kgval = kvv[i] * wrow[t] * expf(-g);
            unsigned short hh, ll;
            split2(kgval, hh, ll);
            kgT[d][t] = hh; kgT[d][64 + t] = ll; kgT[d][128 + t] = hh;
            split2(vv_[i], hh, ll);
            vT[d][t] = hh; vT[d][64 + t] = hh; vT[d][128 + t] = ll;
        }
    }
    __syncthreads();

    size_t base = (size_t)((c * 8 + h) * 5 + p) * 4096;
    int ar = 16 * w + (lane & 15);
    int kb = (lane >> 4) * 16;
    float dec_[4];
    #pragma unroll
    for (int j = 0; j < 4; ++j) dec_[j] = expf(glast[16 * w + (lane >> 4) * 4 + j]);

    #pragma unroll
    for (int ni = 0; ni < 4; ++ni) {
        f32x4 acc = (f32x4){0.f, 0.f, 0.f, 0.f};
        int br = 16 * ni + (lane & 15);
        #pragma unroll
        for (int kk = 0; kk < 6; ++kk) {
            s16x8 af = *(const s16x8*)((const char*)&kgT[ar][0] + kk * 64 + kb);
            s16x8 bf = *(const s16x8*)((const char*)&vT[br][0] + kk * 64 + kb);
            acc = __builtin_amdgcn_mfma_f32_16x16x32_bf16(af, bf, acc, 0, 0, 0);
        }
        #pragma unroll
        for (int j = 0; j < 4; ++j) {
            int dd = 16 * w + (lane >> 4) * 4 + j;
            kv_all[base + dd * 64 + 16 * ni + (lane & 15)] = acc[j] * dec_[j];
        }
    }
    if (tid < 64) decay_all[(size_t)((c * 8 + h) * 5 + p) * 64 + tid] = expf(glast[tid]);
}

// ---------------------------------------------------------------------------
// Inter-chunk state scan: elementwise, in place over kv_all (f32).
// ---------------------------------------------------------------------------
__global__ void gla_state_scan(float* __restrict__ kv, const float* __restrict__ decay)
{
    int gid = blockIdx.x * 256 + threadIdx.x;
    int sub = gid >> 6;
    const size_t stride = 8 * 5 * 64 * 64;
    float S = 0.f;
    float kvv = kv[gid];
    for (int c = 0; c < 64; ++c) {
        size_t o = (size_t)c * stride + gid;
        float nxt = (c < 63) ? kv[o + stride] : 0.f;
        float dec = decay[c * 2560 + sub];
        kv[o] = S;
        S = fmaf(dec, S, kvv);
        kvv = nxt;
    }
}

// ---------------------------------------------------------------------------
// Phase 2: per-pass output via bf16 MFMA. Block = (p,h,c).
// A = tril(qg kg^T) (f32 acc, masked, ->bf16 LDS); o = qg@S + A@v.
// p==0 -> o_dense; p>=1 -> predicated rows into shared o_sparse
// (top-1 routing => expert passes own disjoint row sets).
// ---------------------------------------------------------------------------
__global__ void gla_o(const float* __restrict__ q1, const float* __restrict__ q2,
                      const float* __restrict__ k1, const float* __restrict__ k2,
                      const float* __restrict__ gk1, const float* __restrict__ gk2,
                      const float* __restrict__ v, const float* __restrict__ rw,
                      const float* __restrict__ Spre,
                      float* __restrict__ o_dense, float* __restrict__ o_sparse)
{
    int p = blockIdx.x, h = blockIdx.y, c = blockIdx.z;
    const float* qp = (p == 0) ? q1 : q2;
    const float* kp = (p == 0) ? k1 : k2;
    const float* gp = (p == 0) ? gk1 : gk2;

    __shared__ __align__(16) unsigned short qg_bf[64][72];  // [t][d]
    __shared__ __align__(16) unsigned short kg_bf[64][72];  // [s][d]
    __shared__ __align__(16) unsigned short A_bf[64][72];   // [t][s]
    __shared__ __align__(16) unsigned short vT_bf[64][72];  // [e][s]
    __shared__ __align__(16) unsigned short ST_bf[64][72];  // [e][d]
    __shared__ float wrow[64];
    __shared__ float segsum[4][64];

    int tid = threadIdx.x;
    int lane = tid & 63, w = tid >> 6;
    int d = lane, seg = w;

    {   // prefetch gk/q/k; register cumsum; stage qg/kg bf16
        float gkv[16], qv[16], kvv[16];
        #pragma unroll
        for (int i = 0; i < 16; ++i) {
            size_t base = (size_t)(c * 64 + seg * 16 + i) * KD_ + (h << 6) + d;
            gkv[i] = gp[base];
            qv[i]  = qp[base];
            kvv[i] = kp[base];
        }
        if (tid < 64) {
            int lg = c * 64 + tid;
            wrow[tid] = (p == 0) ? 1.f : rw[lg * 4 + (p - 1)];
        }
        __syncthreads();

        float s = 0.f;
        #pragma unroll
        for (int i = 0; i < 16; ++i) {
            int t = seg * 16 + i;
            float xg = gkv[i];
            if (p > 0 && !(wrow[t] > 0.f)) xg = 0.f;
            s += xg;
            gkv[i] = s;
        }
        segsum[seg][d] = s;
        __syncthreads();

        float off = 0.f;
        for (int ss = 0; ss < seg; ++ss) off += segsum[ss][d];
        #pragma unroll
        for (int i = 0; i < 16; ++i) {
            int t = seg * 16 + i;
            float g = off + gkv[i];
            float wv = wrow[t];
            qg_bf[t][d] = f2bf(qv[i] * wv * expf(g));
            kg_bf[t][d] = f2bf(kvv[i] * wv * expf(-g));
        }
    }

    {   // stage S^T and v^T bf16 (reg round-trip; latency hides under staging)
        size_t sbase = (size_t)((c * 8 + h) * 5 + p) * 4096;
        float Sv[16], vv_[16];
        #pragma unroll
        for (int i = 0; i < 16; ++i) Sv[i] = Spre[sbase + tid + (i << 8)];
        #pragma unroll
        for (int i = 0; i < 16; ++i)
            vv_[i] = v[(size_t)(c * 64 + seg * 16 + i) * KD_ + (h << 6) + d];
        #pragma unroll
        for (int i = 0; i < 16; ++i) ST_bf[d][4 * i + seg] = f2bf(Sv[i]);   // [e=d][dd]
        #pragma unroll
        for (int i = 0; i < 16; ++i) vT_bf[d][seg * 16 + i] = f2bf(vv_[i]); // [e=d][t]
    }
    __syncthreads();

    int am = 16 * w + (lane & 15);
    int kb = (lane >> 4) * 16;

    // A = tril(qg kg^T): wave w computes its 16-row strip; skip tiles above diag
    #pragma unroll
    for (int ni = 0; ni < 4; ++ni) {
        f32x4 acc = (f32x4){0.f, 0.f, 0.f, 0.f};
        if (ni <= w) {
            int br = 16 * ni + (lane & 15);
            #pragma unroll
            for (int kk = 0; kk < 2; ++kk) {
                s16x8 af = *(const s16x8*)((const char*)&qg_bf[am][0] + kk * 64 + kb);
                s16x8 bf = *(const s16x8*)((const char*)&kg_bf[br][0] + kk * 64 + kb);
                acc = __builtin_amdgcn_mfma_f32_16x16x32_bf16(af, bf, acc, 0, 0, 0);
            }
        }
        #pragma unroll
        for (int j = 0; j < 4; ++j) {
            int t = 16 * w + (lane >> 4) * 4 + j;
            int s = 16 * ni + (lane & 15);
            A_bf[t][s] = (s <= t) ? f2bf(acc[j]) : (unsigned short)0;
        }
    }
    __syncthreads();

    // o = qg@S + A@v
    #pragma unroll
    for (int ni = 0; ni < 4; ++ni) {
        f32x4 acc = (f32x4){0.f, 0.f, 0.f, 0.f};
        int br = 16 * ni + (lane & 15);
        #pragma unroll
        for (int kk = 0; kk < 2; ++kk) {
            s16x8 af = *(const s16x8*)((const char*)&qg_bf[am][0] + kk * 64 + kb);
            s16x8 bf = *(const s16x8*)((const char*)&ST_bf[br][0] + kk * 64 + kb);
            acc = __builtin_amdgcn_mfma_f32_16x16x32_bf16(af, bf, acc, 0, 0, 0);
        }
        #pragma unroll
        for (int kk = 0; kk < 2; ++kk) {
            s16x8 af = *(const s16x8*)((const char*)&A_bf[am][0] + kk * 64 + kb);
            s16x8 bf = *(const s16x8*)((const char*)&vT_bf[br][0] + kk * 64 + kb);
            acc = __builtin_amdgcn_mfma_f32_16x16x32_bf16(af, bf, acc, 0, 0, 0);
        }
        #pragma unroll
        for (int j = 0; j < 4; ++j) {
            int t = 16 * w + (lane >> 4) * 4 + j;
            int e = 16 * ni + (lane & 15);
            size_t idx = (size_t)(c * 64 + t) * KD_ + (h << 6) + e;
            if (p == 0)                 o_dense[idx]  = acc[j];
            else if (wrow[t] > 0.f)     o_sparse[idx] = acc[j];
        }
    }
}

// ---------------------------------------------------------------------------
// Post: sum dense+sparse, RMS-norm, * norm_w, * silu(g); emit split-bf16 A.
// ---------------------------------------------------------------------------
__global__ void postnorm(const float* __restrict__ o_dense, const float* __restrict__ o_sparse,
                         const float* __restrict__ gbuf,
                         const float* __restrict__ norm_w, unsigned short* __restrict__ og2)
{
    int l = blockIdx.x;
    int tid = threadIdx.x;
    int w = tid >> 6, lane = tid & 63;
    int bi = (w << 6) + lane;
    int idx = l * KD_ + bi;
    float o = o_dense[idx] + o_sparse[idx];
    float ss = o * o;
    for (int s = 32; s >= 1; s >>= 1) ss += __shfl_xor(ss, s, 64);
    float r = rsqrtf(ss * (1.f / 64.f) + 1e-5f);
    float val = o * r * norm_w[lane];
    float gv = gbuf[idx];
    val *= gv / (1.f + expf(-gv));
    unsigned short h, lo;
    split2(val, h, lo);
    size_t ro = (size_t)l * (3 * KD_) + bi;
    og2[ro]           = h;
    og2[ro + KD_]     = lo;
    og2[ro + 2 * KD_] = h;
}

// ---------------------------------------------------------------------------
extern "C" void kernel_launch(void* const* d_in, const int* in_sizes, int n_in,
                              void* d_out, int out_size, void* d_ws, size_t ws_size,
                              hipStream_t stream)
{
    const float* x    = (const float*)d_in[0];
    const float* Wq   = (const float*)d_in[1];
    const float* Wk   = (const float*)d_in[2];
    const float* Wv   = (const float*)d_in[3];
    const float* Wqa  = (const float*)d_in[4];
    const float* Wqb  = (const float*)d_in[5];
    const float* Wka  = (const float*)d_in[6];
    const float* Wkb  = (const float*)d_in[7];
    const float* Wg1a = (const float*)d_in[8];
    const float* Wg1b = (const float*)d_in[9];
    const float* bg1  = (const float*)d_in[10];
    const float* Wg2a = (const float*)d_in[11];
    const float* Wg2b = (const float*)d_in[12];
    const float* bg2  = (const float*)d_in[13];
    const float* We   = (const float*)d_in[14];
    const float* Wga  = (const float*)d_in[15];
    const float* Wgb  = (const float*)d_in[16];
    const float* normw= (const float*)d_in[17];
    const float* Wo   = (const float*)d_in[18];

    float* ws = (float*)d_ws;
    const size_t LKD = (size_t)LL * KD_;   // 2M floats
    float* q1   = ws;
    float* k1   = q1 + LKD;
    float* v    = k1 + LKD;
    float* q2   = v  + LKD;
    float* k2   = q2 + LKD;
    float* gk1  = k2 + LKD;
    float* gk2  = gk1 + LKD;
    float* o_dense  = gk2 + LKD;
    float* o_sparse = o_dense + LKD;
    float* tg1  = o_sparse + LKD;              // 4096*16
    float* tg2  = tg1 + (size_t)LL * 16;
    float* elog = tg2 + (size_t)LL * 16;       // 4096*4
    float* rw   = elog + (size_t)LL * 4;
    float* kv_all    = rw + (size_t)LL * 4;                    // 10.49M f32
    float* decay_all = kv_all + (size_t)64 * 8 * 5 * 64 * 64;  // 163840 f32

    unsigned short* bp = (unsigned short*)(decay_all + 163840);
    unsigned short* WqT2   = bp; bp += (size_t)512 * 3072;
    unsigned short* WkT2   = bp; bp += (size_t)512 * 3072;
    unsigned short* WvT2   = bp; bp += (size_t)512 * 3072;
    unsigned short* WoT2   = bp; bp += (size_t)1024 * 1536;
    unsigned short* WqbT2  = bp; bp += (size_t)512 * 192;
    unsigned short* WkbT2  = bp; bp += (size_t)512 * 192;
    unsigned short* WgbT2  = bp; bp += (size_t)512 * 192;
    unsigned short* WcatT2 = bp; bp += (size_t)256 * 3072;
    unsigned short* tqab2  = bp; bp += (size_t)LL * 192;
    unsigned short* tkab2  = bp; bp += (size_t)LL * 192;
    unsigned short* tgab2  = bp; bp += (size_t)LL * 192;
    float* tcat = (float*)bp;                                  // 4096*256 f32

    // time-multiplexed aliases of kv_all (disjoint lifetimes):
    unsigned short* xb2 = (unsigned short*)kv_all;   // [4096][3072]; dead before gla_kv
    unsigned short* og2 = (unsigned short*)kv_all;   // [4096][1536]; live after gla_o
    float* gbuf = k1;                                // reuse after gla_o

    dim3 blk(256);
    dim3 tblk(32, 8);

    // ---- split conversions ----
    cvt_splitA<<<dim3((LL * 1024 + 255) / 256), blk, 0, stream>>>(x, xb2, LL * 1024, 10);
    cvtT_split<<<dim3(16, 32), tblk, 0, stream>>>(Wq, WqT2, 1024, 512);
    cvtT_split<<<dim3(16, 32), tblk, 0, stream>>>(Wk, WkT2, 1024, 512);
    cvtT_split<<<dim3(16, 32), tblk, 0, stream>>>(Wv, WvT2, 1024, 512);
    cvtT_split<<<dim3(32, 16), tblk, 0, stream>>>(Wo, WoT2, 512, 1024);
    cvtT_split<<<dim3(16, 2),  tblk, 0, stream>>>(Wqb, WqbT2, 64, 512);
    cvtT_split<<<dim3(16, 2),  tblk, 0, stream>>>(Wkb, WkbT2, 64, 512);
    cvtT_split<<<dim3(16, 2),  tblk, 0, stream>>>(Wgb, WgbT2, 64, 512);

    // concat small-projection weights (pad rows zeroed)
    hipMemsetAsync(WcatT2 + (size_t)228 * 3072, 0, (size_t)(256 - 228) * 3072 * 2, stream);
    cvtT_split<<<dim3(2, 32), tblk, 0, stream>>>(Wqa,  WcatT2 + (size_t)0   * 3072, 1024, 64);
    cvtT_split<<<dim3(2, 32), tblk, 0, stream>>>(Wka,  WcatT2 + (size_t)64  * 3072, 1024, 64);
    cvtT_split<<<dim3(2, 32), tblk, 0, stream>>>(Wga,  WcatT2 + (size_t)128 * 3072, 1024, 64);
    cvtT_split<<<dim3(1, 32), tblk, 0, stream>>>(Wg1a, WcatT2 + (size_t)192 * 3072, 1024, 16);
    cvtT_split<<<dim3(1, 32), tblk, 0, stream>>>(Wg2a, WcatT2 + (size_t)208 * 3072, 1024, 16);
    cvtT_split<<<dim3(1, 32), tblk, 0, stream>>>(We,   WcatT2 + (size_t)224 * 3072, 1024, 4);

    // ---- QKV (split MFMA, K'=3072, fused) ----
    gemm_mfma<<<dim3(4, 32, 3), blk, 0, stream>>>(xb2, xb2, xb2, WqT2, WkT2, WvT2,
                                                  q1, k1, v, LL, KD_, 3072);

    // ---- concatenated LoRA-a / gate-a / router (split MFMA, N=256) ----
    gemm_mfma<<<dim3(2, 32, 1), blk, 0, stream>>>(xb2, xb2, xb2, WcatT2, WcatT2, WcatT2,
                                                  tcat, tcat, tcat, LL, 256, 3072);
    unpack_cat<<<dim3(LL), blk, 0, stream>>>(tcat, tqab2, tkab2, tgab2, tg1, tg2, elog);

    // ---- LoRA-b q2,k2 (split MFMA, K'=192) ----
    gemm_mfma<<<dim3(4, 32, 2), blk, 0, stream>>>(tqab2, tkab2, tkab2, WqbT2, WkbT2, WkbT2,
                                                  q2, k2, k2, LL, KD_, 192);
    // ---- gate-b (f32, K=16, fused z=2) ----
    gemm128b<<<dim3(4, 32, 2), blk, 0, stream>>>(tg1, tg2, Wg1b, Wg2b, gk1, gk2, LL, KD_, 16);

    elementwise_pre<<<LL, 512, 0, stream>>>(q1, q2, k2, gk1, gk2, bg1, bg2, elog, rw);

    // ---- GLA: kv -> scan -> o (p fastest-varying for L2 sharing) ----
    gla_kv<<<dim3(5, 8, 64), blk, 0, stream>>>(k1, k2, gk1, gk2, v, rw, kv_all, decay_all);
    gla_state_scan<<<dim3(640), blk, 0, stream>>>(kv_all, decay_all);
    gla_o<<<dim3(5, 8, 64), blk, 0, stream>>>(q1, q2, k1, k2, gk1, gk2, v, rw,
                                              kv_all, o_dense, o_sparse);

    // ---- gating projection (split MFMA; k1 free after gla_o) ----
    gemm_mfma<<<dim3(4, 32, 1), blk, 0, stream>>>(tgab2, tgab2, tgab2, WgbT2, WgbT2, WgbT2,
                                                  gbuf, gbuf, gbuf, LL, KD_, 192);

    postnorm<<<LL, 512, 0, stream>>>(o_dense, o_sparse, gbuf, normw, og2);

    // ---- output projection (split MFMA, K'=1536) ----
    gemm_mfma<<<dim3(8, 32, 1), blk, 0, stream>>>(og2, og2, og2, WoT2, WoT2, WoT2,
                                                  (float*)d_out, (float*)d_out, (float*)d_out,
                                                  LL, 1024, 1536);
}

// Round 11
// 277.498 us; speedup vs baseline: 10.2463x; 1.2053x over previous
//
#include <hip/hip_runtime.h>
#include <math.h>

#define LL   4096
#define HH   8
#define DK_  64
#define DV_  64
#define KD_  512
#define NEXP 4

typedef __attribute__((ext_vector_type(8))) short  s16x8;
typedef __attribute__((ext_vector_type(4))) float  f32x4;

__device__ __forceinline__ float f4c(const float4& v, int i) {
    return i == 0 ? v.x : i == 1 ? v.y : i == 2 ? v.z : v.w;
}

__device__ __forceinline__ unsigned short f2bf(float f) {   // RNE f32->bf16
    unsigned u = __float_as_uint(f);
    u += 0x7FFFu + ((u >> 16) & 1u);
    return (unsigned short)(u >> 16);
}

__device__ __forceinline__ void split2(float v, unsigned short& h, unsigned short& l) {
    h = f2bf(v);
    float hf = __uint_as_float((unsigned)h << 16);
    l = f2bf(v - hf);
}

// ---------------------------------------------------------------------------
// f32 [M][K] -> split-bf16 A layout [M][3K] = [hi | lo | hi]. K = 2^kshift.
// ---------------------------------------------------------------------------
__global__ void cvt_splitA(const float* __restrict__ in, unsigned short* __restrict__ out,
                           int n, int kshift)
{
    int i = blockIdx.x * 256 + threadIdx.x;
    if (i >= n) return;
    unsigned short h, l;
    split2(in[i], h, l);
    int K = 1 << kshift;
    int m = i >> kshift, k = i & (K - 1);
    size_t ro = (size_t)m * 3 * K;
    out[ro + k]         = h;
    out[ro + K + k]     = l;
    out[ro + 2 * K + k] = h;
}

// ---------------------------------------------------------------------------
// f32 [K][N] -> split-bf16 B layout [N][3K] = [hi | hi | lo] (transposed).
// N-guarded. Grid ((N+31)/32, K/32), blk (32,8).
// ---------------------------------------------------------------------------
__global__ void cvtT_split(const float* __restrict__ W, unsigned short* __restrict__ WT,
                           int K, int N)
{
    __shared__ float t[32][33];
    int bx = blockIdx.x * 32;   // n
    int by = blockIdx.y * 32;   // k
    int x = threadIdx.x, y = threadIdx.y;
    #pragma unroll
    for (int i = 0; i < 4; ++i)
        t[y + 8 * i][x] = (bx + x < N) ? W[(size_t)(by + y + 8 * i) * N + bx + x] : 0.f;
    __syncthreads();
    #pragma unroll
    for (int i = 0; i < 4; ++i) {
        int n = bx + y + 8 * i;
        if (n < N) {
            unsigned short h, l;
            split2(t[x][y + 8 * i], h, l);
            size_t ro = (size_t)n * 3 * K + (by + x);
            WT[ro]         = h;
            WT[ro + K]     = h;
            WT[ro + 2 * K] = l;
        }
    }
}

// ---------------------------------------------------------------------------
// Mega GEMM: [q1|k1|v|tcat] = x @ [Wq|Wk|Wv|Wcat] in one launch.
// A = xb2 [M][3072] split-A; B = WallT2 [1792][3072] split-B.
// 128x128 tile, BK=64, 4 waves. Epilogue routes per-block to the right C.
// ---------------------------------------------------------------------------
__global__ __launch_bounds__(256) void gemm_qkvcat(
    const unsigned short* __restrict__ A, const unsigned short* __restrict__ B,
    float* __restrict__ Cq, float* __restrict__ Ck, float* __restrict__ Cv,
    float* __restrict__ Ct, int M, int K)
{
    __shared__ __align__(16) unsigned short sm[2 * 128 * 64];
    unsigned short* As = sm;
    unsigned short* Bs = sm + 128 * 64;

    int tid  = threadIdx.x;
    int lane = tid & 63;
    int w    = tid >> 6;
    int m0 = blockIdx.y * 128, n0 = blockIdx.x * 128;
    int wr = w >> 1, wc = w & 1;

    f32x4 acc[4][4];
    #pragma unroll
    for (int i = 0; i < 4; ++i)
        #pragma unroll
        for (int j = 0; j < 4; ++j)
            acc[i][j] = (f32x4){0.f, 0.f, 0.f, 0.f};

    const int srow = (lane >> 3);
    const int scb  = ((lane & 7) * 16) ^ (srow << 4);

    for (int kt = 0; kt < K; kt += 64) {
        __syncthreads();
        #pragma unroll
        for (int q = 0; q < 4; ++q) {
            int r = w * 32 + q * 8 + srow;
            const char* ga = (const char*)A + ((size_t)(m0 + r) * K + kt) * 2 + scb;
            const char* gb = (const char*)B + ((size_t)(n0 + r) * K + kt) * 2 + scb;
            __builtin_amdgcn_global_load_lds(
                (const __attribute__((address_space(1))) void*)ga,
                (__attribute__((address_space(3))) void*)((char*)As + (w * 32 + q * 8) * 128),
                16, 0, 0);
            __builtin_amdgcn_global_load_lds(
                (const __attribute__((address_space(1))) void*)gb,
                (__attribute__((address_space(3))) void*)((char*)Bs + (w * 32 + q * 8) * 128),
                16, 0, 0);
        }
        __syncthreads();

        #pragma unroll
        for (int kk = 0; kk < 2; ++kk) {
            int kb = kk * 64 + (lane >> 4) * 16;
            s16x8 af[4], bfr[4];
            #pragma unroll
            for (int mi = 0; mi < 4; ++mi) {
                int r = wr * 64 + mi * 16 + (lane & 15);
                af[mi] = *(const s16x8*)((const char*)As + r * 128 + (kb ^ ((r & 7) << 4)));
            }
            #pragma unroll
            for (int ni = 0; ni < 4; ++ni) {
                int r = wc * 64 + ni * 16 + (lane & 15);
                bfr[ni] = *(const s16x8*)((const char*)Bs + r * 128 + (kb ^ ((r & 7) << 4)));
            }
            #pragma unroll
            for (int mi = 0; mi < 4; ++mi)
                #pragma unroll
                for (int ni = 0; ni < 4; ++ni)
                    acc[mi][ni] = __builtin_amdgcn_mfma_f32_16x16x32_bf16(
                        af[mi], bfr[ni], acc[mi][ni], 0, 0, 0);
        }
    }

    // route: cols [0,512) -> Cq, [512,1024) -> Ck, [1024,1536) -> Cv,
    //        [1536,1792) -> Ct (ld 256). 128-tiles never straddle boundaries.
    int base = n0 >> 9;
    float* C;
    int ldc, cb;
    if (base == 0)      { C = Cq; ldc = 512; cb = 0; }
    else if (base == 1) { C = Ck; ldc = 512; cb = 512; }
    else if (base == 2) { C = Cv; ldc = 512; cb = 1024; }
    else                { C = Ct; ldc = 256; cb = 1536; }

    #pragma unroll
    for (int mi = 0; mi < 4; ++mi)
        #pragma unroll
        for (int ni = 0; ni < 4; ++ni) {
            int col = n0 + wc * 64 + ni * 16 + (lane & 15) - cb;
            int rb  = m0 + wr * 64 + mi * 16 + (lane >> 4) * 4;
            #pragma unroll
            for (int j = 0; j < 4; ++j)
                C[(size_t)(rb + j) * ldc + col] = acc[mi][ni][j];
        }
}

// ---------------------------------------------------------------------------
// bf16 MFMA GEMM (split-bf16 accurate): 128x128 tile, BK=64, 4 waves.
// ---------------------------------------------------------------------------
__global__ __launch_bounds__(256) void gemm_mfma(
    const unsigned short* __restrict__ A0, const unsigned short* __restrict__ A1,
    const unsigned short* __restrict__ A2,
    const unsigned short* __restrict__ B0, const unsigned short* __restrict__ B1,
    const unsigned short* __restrict__ B2,
    float* __restrict__ C0, float* __restrict__ C1, float* __restrict__ C2,
    int M, int N, int K)
{
    const unsigned short* A = (blockIdx.z == 0) ? A0 : (blockIdx.z == 1) ? A1 : A2;
    const unsigned short* B = (blockIdx.z == 0) ? B0 : (blockIdx.z == 1) ? B1 : B2;
    float*                C = (blockIdx.z == 0) ? C0 : (blockIdx.z == 1) ? C1 : C2;

    __shared__ __align__(16) unsigned short sm[2 * 128 * 64];
    unsigned short* As = sm;
    unsigned short* Bs = sm + 128 * 64;

    int tid  = threadIdx.x;
    int lane = tid & 63;
    int w    = tid >> 6;
    int m0 = blockIdx.y * 128, n0 = blockIdx.x * 128;
    int wr = w >> 1, wc = w & 1;

    f32x4 acc[4][4];
    #pragma unroll
    for (int i = 0; i < 4; ++i)
        #pragma unroll
        for (int j = 0; j < 4; ++j)
            acc[i][j] = (f32x4){0.f, 0.f, 0.f, 0.f};

    const int srow = (lane >> 3);
    const int scb  = ((lane & 7) * 16) ^ (srow << 4);

    for (int kt = 0; kt < K; kt += 64) {
        __syncthreads();
        #pragma unroll
        for (int q = 0; q < 4; ++q) {
            int r = w * 32 + q * 8 + srow;
            const char* ga = (const char*)A + ((size_t)(m0 + r) * K + kt) * 2 + scb;
            const char* gb = (const char*)B + ((size_t)(n0 + r) * K + kt) * 2 + scb;
            __builtin_amdgcn_global_load_lds(
                (const __attribute__((address_space(1))) void*)ga,
                (__attribute__((address_space(3))) void*)((char*)As + (w * 32 + q * 8) * 128),
                16, 0, 0);
            __builtin_amdgcn_global_load_lds(
                (const __attribute__((address_space(1))) void*)gb,
                (__attribute__((address_space(3))) void*)((char*)Bs + (w * 32 + q * 8) * 128),
                16, 0, 0);
        }
        __syncthreads();

        #pragma unroll
        for (int kk = 0; kk < 2; ++kk) {
            int kb = kk * 64 + (lane >> 4) * 16;
            s16x8 af[4], bfr[4];
            #pragma unroll
            for (int mi = 0; mi < 4; ++mi) {
                int r = wr * 64 + mi * 16 + (lane & 15);
                af[mi] = *(const s16x8*)((const char*)As + r * 128 + (kb ^ ((r & 7) << 4)));
            }
            #pragma unroll
            for (int ni = 0; ni < 4; ++ni) {
                int r = wc * 64 + ni * 16 + (lane & 15);
                bfr[ni] = *(const s16x8*)((const char*)Bs + r * 128 + (kb ^ ((r & 7) << 4)));
            }
            #pragma unroll
            for (int mi = 0; mi < 4; ++mi)
                #pragma unroll
                for (int ni = 0; ni < 4; ++ni)
                    acc[mi][ni] = __builtin_amdgcn_mfma_f32_16x16x32_bf16(
                        af[mi], bfr[ni], acc[mi][ni], 0, 0, 0);
        }
    }

    #pragma unroll
    for (int mi = 0; mi < 4; ++mi)
        #pragma unroll
        for (int ni = 0; ni < 4; ++ni) {
            int col = n0 + wc * 64 + ni * 16 + (lane & 15);
            int rb  = m0 + wr * 64 + mi * 16 + (lane >> 4) * 4;
            #pragma unroll
            for (int j = 0; j < 4; ++j)
                C[(size_t)(rb + j) * N + col] = acc[mi][ni][j];
        }
}

// ---------------------------------------------------------------------------
// Unpack the concatenated projection tcat [LL][256].
// ---------------------------------------------------------------------------
__global__ void unpack_cat(const float* __restrict__ tcat,
                           unsigned short* __restrict__ tqab2,
                           unsigned short* __restrict__ tkab2,
                           unsigned short* __restrict__ tgab2,
                           float* __restrict__ tg1, float* __restrict__ tg2,
                           float* __restrict__ elog)
{
    int m = blockIdx.x;
    int c = threadIdx.x;
    float vx = tcat[(size_t)m * 256 + c];
    if (c < 192) {
        unsigned short h, l;
        split2(vx, h, l);
        unsigned short* dst = (c < 64) ? tqab2 : (c < 128) ? tkab2 : tgab2;
        int cc = c & 63;
        size_t ro = (size_t)m * 192;
        dst[ro + cc]       = h;
        dst[ro + 64 + cc]  = l;
        dst[ro + 128 + cc] = h;
    } else if (c < 208) {
        tg1[(size_t)m * 16 + (c - 192)] = vx;
    } else if (c < 224) {
        tg2[(size_t)m * 16 + (c - 208)] = vx;
    } else if (c < 228) {
        elog[(size_t)m * 4 + (c - 224)] = vx;
    }
}

// ---------------------------------------------------------------------------
// 128x128 f32 GEMM, fused over z (2 triples) — gate-b (K=16).
// ---------------------------------------------------------------------------
__global__ void gemm128b(const float* __restrict__ A0, const float* __restrict__ A1,
                         const float* __restrict__ B0, const float* __restrict__ B1,
                         float* __restrict__ C0, float* __restrict__ C1,
                         int M, int N, int K)
{
    const float* A = (blockIdx.z == 0) ? A0 : A1;
    const float* B = (blockIdx.z == 0) ? B0 : B1;
    float*       C = (blockIdx.z == 0) ? C0 : C1;

    __shared__ float As[16][132];
    __shared__ float Bs[16][132];
    int tid = threadIdx.x;
    int n0 = blockIdx.x * 128;
    int m0 = blockIdx.y * 128;
    int tx = tid & 15, ty = tid >> 4;
    float acc[8][8] = {};

    for (int k0 = 0; k0 < K; k0 += 16) {
        #pragma unroll
        for (int u = 0; u < 2; ++u) {
            int lin = tid + (u << 8);
            int row = lin >> 2, q4 = lin & 3;
            float4 a = *reinterpret_cast<const float4*>(&A[(size_t)(m0 + row) * K + k0 + q4 * 4]);
            As[q4 * 4 + 0][row] = a.x;
            As[q4 * 4 + 1][row] = a.y;
            As[q4 * 4 + 2][row] = a.z;
            As[q4 * 4 + 3][row] = a.w;
        }
        #pragma unroll
        for (int u = 0; u < 2; ++u) {
            int lin = tid + (u << 8);
            int kr = lin >> 5, c4 = lin & 31;
            *reinterpret_cast<float4*>(&Bs[kr][c4 * 4]) =
                *reinterpret_cast<const float4*>(&B[(size_t)(k0 + kr) * N + n0 + c4 * 4]);
        }
        __syncthreads();
        #pragma unroll
        for (int k = 0; k < 16; ++k) {
            float4 a0 = *(const float4*)&As[k][ty * 4];
            float4 a1 = *(const float4*)&As[k][64 + ty * 4];
            float4 b0 = *(const float4*)&Bs[k][tx * 4];
            float4 b1 = *(const float4*)&Bs[k][64 + tx * 4];
            float av[8] = {a0.x, a0.y, a0.z, a0.w, a1.x, a1.y, a1.z, a1.w};
            float bv[8] = {b0.x, b0.y, b0.z, b0.w, b1.x, b1.y, b1.z, b1.w};
            #pragma unroll
            for (int i = 0; i < 8; ++i)
                #pragma unroll
                for (int j = 0; j < 8; ++j)
                    acc[i][j] = fmaf(av[i], bv[j], acc[i][j]);
        }
        __syncthreads();
    }
    #pragma unroll
    for (int i = 0; i < 8; ++i) {
        int m = m0 + ((i < 4) ? ty * 4 + i : 64 + ty * 4 + (i - 4));
        float4 c0 = make_float4(acc[i][0], acc[i][1], acc[i][2], acc[i][3]);
        float4 c1 = make_float4(acc[i][4], acc[i][5], acc[i][6], acc[i][7]);
        *reinterpret_cast<float4*>(&C[(size_t)m * N + n0 + tx * 4]) = c0;
        *reinterpret_cast<float4*>(&C[(size_t)m * N + n0 + 64 + tx * 4]) = c1;
    }
}

// ---------------------------------------------------------------------------
__device__ inline float logsig(float x) {
    return fminf(x, 0.f) - log1pf(expf(-fabsf(x)));
}

__global__ void elementwise_pre(float* __restrict__ q1, float* __restrict__ q2,
                                float* __restrict__ k2, float* __restrict__ gk1,
                                float* __restrict__ gk2,
                                const float* __restrict__ bg1, const float* __restrict__ bg2,
                                const float* __restrict__ elog, float* __restrict__ rw)
{
    int l = blockIdx.x;
    int tid = threadIdx.x;
    int w = tid >> 6, lane = tid & 63;
    int idx = l * KD_ + (w << 6) + lane;

    q1[idx] *= 0.125f;
    q2[idx] *= 0.125f;

    float kv = k2[idx];
    float m = kv;
    for (int s = 32; s >= 1; s >>= 1) m = fmaxf(m, __shfl_xor(m, s, 64));
    float ev = expf(kv - m);
    float ssum = ev;
    for (int s = 32; s >= 1; s >>= 1) ssum += __shfl_xor(ssum, s, 64);
    k2[idx] = ev / ssum;

    int bi = (w << 6) + lane;
    gk1[idx] = logsig(gk1[idx] + bg1[bi]) * (1.f / 16.f);
    gk2[idx] = logsig(gk2[idx] + bg2[bi]) * (1.f / 16.f);

    if (tid == 0) {
        float xs[4];
        float mm = -1e30f;
        for (int j = 0; j < 4; ++j) { xs[j] = elog[l * 4 + j]; mm = fmaxf(mm, xs[j]); }
        float s4 = 0.f;
        for (int j = 0; j < 4; ++j) { xs[j] = expf(xs[j] - mm); s4 += xs[j]; }
        for (int j = 0; j < 4; ++j) xs[j] /= s4;
        int arg = 0; float best = xs[0];
        for (int j = 1; j < 4; ++j) if (xs[j] > best) { best = xs[j]; arg = j; }
        for (int j = 0; j < 4; ++j) rw[l * 4 + j] = (j == arg) ? xs[j] : 0.f;
    }
}

// ---------------------------------------------------------------------------
// Phase 1: chunk_kv + decay via split-bf16 MFMA (f32-accurate). Block = (p,h,c).
// ---------------------------------------------------------------------------
__global__ void gla_kv(const float* __restrict__ k1, const float* __restrict__ k2,
                       const float* __restrict__ gk1, const float* __restrict__ gk2,
                       const float* __restrict__ v, const float* __restrict__ rw,
                       float* __restrict__ kv_all, float* __restrict__ decay_all)
{
    int p = blockIdx.x, h = blockIdx.y, c = blockIdx.z;
    const float* kp = (p == 0) ? k1 : k2;
    const float* gp = (p == 0) ? gk1 : gk2;

    __shared__ __align__(16) unsigned short kgT[64][200];  // [d][hi|lo|hi along t]
    __shared__ __align__(16) unsigned short vT[64][200];   // [e][hi|hi|lo along t]
    __shared__ float glast[64];
    __shared__ float wrow[64];
    __shared__ float segsum[4][64];

    int tid = threadIdx.x;
    int lane = tid & 63, w = tid >> 6;
    int d = lane, seg = w;

    float gkv[16], kvv[16], vv_[16];
    #pragma unroll
    for (int i = 0; i < 16; ++i) {
        size_t base = (size_t)(c * 64 + seg * 16 + i) * KD_ + (h << 6) + d;
        gkv[i] = gp[base];
        kvv[i] = kp[base];
        vv_[i] = v[base];
    }
    if (tid < 64) {
        int lg = c * 64 + tid;
        wrow[tid] = (p == 0) ? 1.f : rw[lg * 4 + (p - 1)];
    }
    __syncthreads();

    {   // masked register cumsum
        float s = 0.f;
        #pragma unroll
        for (int i = 0; i < 16; ++i) {
            int t = seg * 16 + i;
            float xg = gkv[i];
            if (p > 0 && !(wrow[t] > 0.f)) xg = 0.f;
            s += xg;
            gkv[i] = s;
        }
        segsum[seg][d] = s;
    }
    __syncthreads();
    {
        float off = 0.f, tot = 0.f;
        #pragma unroll
        for (int ss = 0; ss < 4; ++ss) {
            float x = segsum[ss][d];
            tot += x;
            if (ss < seg) off += x;
        }
        if (seg == 0) glast[d] = tot;
        #pragma unroll
        for (int i = 0; i < 16; ++i) {
            int t = seg * 16 + i;
            float g = off + gkv[i];
            float kgval = kvv[i] * wrow[t] * expf(-g);
            unsigned short hh, ll;
            split2(kgval, hh, ll);
            kgT[d][t] = hh; kgT[d][64 + t] = ll; kgT[d][128 + t] = hh;
            split2(vv_[i], hh, ll);
            vT[d][t] = hh; vT[d][64 + t] = hh; vT[d][128 + t] = ll;
        }
    }
    __syncthreads();

    size_t base = (size_t)((c * 8 + h) * 5 + p) * 4096;
    int ar = 16 * w + (lane & 15);
    int kb = (lane >> 4) * 16;
    float dec_[4];
    #pragma unroll
    for (int j = 0; j < 4; ++j) dec_[j] = expf(glast[16 * w + (lane >> 4) * 4 + j]);

    #pragma unroll
    for (int ni = 0; ni < 4; ++ni) {
        f32x4 acc = (f32x4){0.f, 0.f, 0.f, 0.f};
        int br = 16 * ni + (lane & 15);
        #pragma unroll
        for (int kk = 0; kk < 6; ++kk) {
            s16x8 af = *(const s16x8*)((const char*)&kgT[ar][0] + kk * 64 + kb);
            s16x8 bf = *(const s16x8*)((const char*)&vT[br][0] + kk * 64 + kb);
            acc = __builtin_amdgcn_mfma_f32_16x16x32_bf16(af, bf, acc, 0, 0, 0);
        }
        #pragma unroll
        for (int j = 0; j < 4; ++j) {
            int dd = 16 * w + (lane >> 4) * 4 + j;
            kv_all[base + dd * 64 + 16 * ni + (lane & 15)] = acc[j] * dec_[j];
        }
    }
    if (tid < 64) decay_all[(size_t)((c * 8 + h) * 5 + p) * 64 + tid] = expf(glast[tid]);
}

// ---------------------------------------------------------------------------
// Inter-chunk state scan: elementwise, in place over kv_all (f32).
// ---------------------------------------------------------------------------
__global__ void gla_state_scan(float* __restrict__ kv, const float* __restrict__ decay)
{
    int gid = blockIdx.x * 256 + threadIdx.x;
    int sub = gid >> 6;
    const size_t stride = 8 * 5 * 64 * 64;
    float S = 0.f;
    float kvv = kv[gid];
    for (int c = 0; c < 64; ++c) {
        size_t o = (size_t)c * stride + gid;
        float nxt = (c < 63) ? kv[o + stride] : 0.f;
        float dec = decay[c * 2560 + sub];
        kv[o] = S;
        S = fmaf(dec, S, kvv);
        kvv = nxt;
    }
}

// ---------------------------------------------------------------------------
// Phase 2: per-pass output via bf16 MFMA. Block = (p,h,c).
// A = tril(qg kg^T); o = qg@S + A@v. p==0 -> o_dense; p>=1 -> predicated
// rows into shared o_sparse (top-1 routing => disjoint row sets).
// ---------------------------------------------------------------------------
__global__ void gla_o(const float* __restrict__ q1, const float* __restrict__ q2,
                      const float* __restrict__ k1, const float* __restrict__ k2,
                      const float* __restrict__ gk1, const float* __restrict__ gk2,
                      const float* __restrict__ v, const float* __restrict__ rw,
                      const float* __restrict__ Spre,
                      float* __restrict__ o_dense, float* __restrict__ o_sparse)
{
    int p = blockIdx.x, h = blockIdx.y, c = blockIdx.z;
    const float* qp = (p == 0) ? q1 : q2;
    const float* kp = (p == 0) ? k1 : k2;
    const float* gp = (p == 0) ? gk1 : gk2;

    __shared__ __align__(16) unsigned short qg_bf[64][72];  // [t][d]
    __shared__ __align__(16) unsigned short kg_bf[64][72];  // [s][d]
    __shared__ __align__(16) unsigned short A_bf[64][72];   // [t][s]
    __shared__ __align__(16) unsigned short vT_bf[64][72];  // [e][s]
    __shared__ __align__(16) unsigned short ST_bf[64][72];  // [e][d]
    __shared__ float wrow[64];
    __shared__ float segsum[4][64];

    int tid = threadIdx.x;
    int lane = tid & 63, w = tid >> 6;
    int d = lane, seg = w;

    {   // prefetch gk/q/k; register cumsum; stage qg/kg bf16
        float gkv[16], qv[16], kvv[16];
        #pragma unroll
        for (int i = 0; i < 16; ++i) {
            size_t base = (size_t)(c * 64 + seg * 16 + i) * KD_ + (h << 6) + d;
            gkv[i] = gp[base];
            qv[i]  = qp[base];
            kvv[i] = kp[base];
        }
        if (tid < 64) {
            int lg = c * 64 + tid;
            wrow[tid] = (p == 0) ? 1.f : rw[lg * 4 + (p - 1)];
        }
        __syncthreads();

        float s = 0.f;
        #pragma unroll
        for (int i = 0; i < 16; ++i) {
            int t = seg * 16 + i;
            float xg = gkv[i];
            if (p > 0 && !(wrow[t] > 0.f)) xg = 0.f;
            s += xg;
            gkv[i] = s;
        }
        segsum[seg][d] = s;
        __syncthreads();

        float off = 0.f;
        for (int ss = 0; ss < seg; ++ss) off += segsum[ss][d];
        #pragma unroll
        for (int i = 0; i < 16; ++i) {
            int t = seg * 16 + i;
            float g = off + gkv[i];
            float wv = wrow[t];
            qg_bf[t][d] = f2bf(qv[i] * wv * expf(g));
            kg_bf[t][d] = f2bf(kvv[i] * wv * expf(-g));
        }
    }

    {   // stage S^T and v^T bf16
        size_t sbase = (size_t)((c * 8 + h) * 5 + p) * 4096;
        float Sv[16], vv_[16];
        #pragma unroll
        for (int i = 0; i < 16; ++i) Sv[i] = Spre[sbase + tid + (i << 8)];
        #pragma unroll
        for (int i = 0; i < 16; ++i)
            vv_[i] = v[(size_t)(c * 64 + seg * 16 + i) * KD_ + (h << 6) + d];
        #pragma unroll
        for (int i = 0; i < 16; ++i) ST_bf[d][4 * i + seg] = f2bf(Sv[i]);   // [e=d][dd]
        #pragma unroll
        for (int i = 0; i < 16; ++i) vT_bf[d][seg * 16 + i] = f2bf(vv_[i]); // [e=d][t]
    }
    __syncthreads();

    int am = 16 * w + (lane & 15);
    int kb = (lane >> 4) * 16;

    // A = tril(qg kg^T)
    #pragma unroll
    for (int ni = 0; ni < 4; ++ni) {
        f32x4 acc = (f32x4){0.f, 0.f, 0.f, 0.f};
        if (ni <= w) {
            int br = 16 * ni + (lane & 15);
            #pragma unroll
            for (int kk = 0; kk < 2; ++kk) {
                s16x8 af = *(const s16x8*)((const char*)&qg_bf[am][0] + kk * 64 + kb);
                s16x8 bf = *(const s16x8*)((const char*)&kg_bf[br][0] + kk * 64 + kb);
                acc = __builtin_amdgcn_mfma_f32_16x16x32_bf16(af, bf, acc, 0, 0, 0);
            }
        }
        #pragma unroll
        for (int j = 0; j < 4; ++j) {
            int t = 16 * w + (lane >> 4) * 4 + j;
            int s = 16 * ni + (lane & 15);
            A_bf[t][s] = (s <= t) ? f2bf(acc[j]) : (unsigned short)0;
        }
    }
    __syncthreads();

    // o = qg@S + A@v
    #pragma unroll
    for (int ni = 0; ni < 4; ++ni) {
        f32x4 acc = (f32x4){0.f, 0.f, 0.f, 0.f};
        int br = 16 * ni + (lane & 15);
        #pragma unroll
        for (int kk = 0; kk < 2; ++kk) {
            s16x8 af = *(const s16x8*)((const char*)&qg_bf[am][0] + kk * 64 + kb);
            s16x8 bf = *(const s16x8*)((const char*)&ST_bf[br][0] + kk * 64 + kb);
            acc = __builtin_amdgcn_mfma_f32_16x16x32_bf16(af, bf, acc, 0, 0, 0);
        }
        #pragma unroll
        for (int kk = 0; kk < 2; ++kk) {
            s16x8 af = *(const s16x8*)((const char*)&A_bf[am][0] + kk * 64 + kb);
            s16x8 bf = *(const s16x8*)((const char*)&vT_bf[br][0] + kk * 64 + kb);
            acc = __builtin_amdgcn_mfma_f32_16x16x32_bf16(af, bf, acc, 0, 0, 0);
        }
        #pragma unroll
        for (int j = 0; j < 4; ++j) {
            int t = 16 * w + (lane >> 4) * 4 + j;
            int e = 16 * ni + (lane & 15);
            size_t idx = (size_t)(c * 64 + t) * KD_ + (h << 6) + e;
            if (p == 0)                 o_dense[idx]  = acc[j];
            else if (wrow[t] > 0.f)     o_sparse[idx] = acc[j];
        }
    }
}

// ---------------------------------------------------------------------------
// Post: sum dense+sparse, RMS-norm, * norm_w, * silu(g); emit split-bf16 A.
// ---------------------------------------------------------------------------
__global__ void postnorm(const float* __restrict__ o_dense, const float* __restrict__ o_sparse,
                         const float* __restrict__ gbuf,
                         const float* __restrict__ norm_w, unsigned short* __restrict__ og2)
{
    int l = blockIdx.x;
    int tid = threadIdx.x;
    int w = tid >> 6, lane = tid & 63;
    int bi = (w << 6) + lane;
    int idx = l * KD_ + bi;
    float o = o_dense[idx] + o_sparse[idx];
    float ss = o * o;
    for (int s = 32; s >= 1; s >>= 1) ss += __shfl_xor(ss, s, 64);
    float r = rsqrtf(ss * (1.f / 64.f) + 1e-5f);
    float val = o * r * norm_w[lane];
    float gv = gbuf[idx];
    val *= gv / (1.f + expf(-gv));
    unsigned short h, lo;
    split2(val, h, lo);
    size_t ro = (size_t)l * (3 * KD_) + bi;
    og2[ro]           = h;
    og2[ro + KD_]     = lo;
    og2[ro + 2 * KD_] = h;
}

// ---------------------------------------------------------------------------
extern "C" void kernel_launch(void* const* d_in, const int* in_sizes, int n_in,
                              void* d_out, int out_size, void* d_ws, size_t ws_size,
                              hipStream_t stream)
{
    const float* x    = (const float*)d_in[0];
    const float* Wq   = (const float*)d_in[1];
    const float* Wk   = (const float*)d_in[2];
    const float* Wv   = (const float*)d_in[3];
    const float* Wqa  = (const float*)d_in[4];
    const float* Wqb  = (const float*)d_in[5];
    const float* Wka  = (const float*)d_in[6];
    const float* Wkb  = (const float*)d_in[7];
    const float* Wg1a = (const float*)d_in[8];
    const float* Wg1b = (const float*)d_in[9];
    const float* bg1  = (const float*)d_in[10];
    const float* Wg2a = (const float*)d_in[11];
    const float* Wg2b = (const float*)d_in[12];
    const float* bg2  = (const float*)d_in[13];
    const float* We   = (const float*)d_in[14];
    const float* Wga  = (const float*)d_in[15];
    const float* Wgb  = (const float*)d_in[16];
    const float* normw= (const float*)d_in[17];
    const float* Wo   = (const float*)d_in[18];

    float* ws = (float*)d_ws;
    const size_t LKD = (size_t)LL * KD_;   // 2M floats
    float* q1   = ws;
    float* k1   = q1 + LKD;
    float* v    = k1 + LKD;
    float* q2   = v  + LKD;
    float* k2   = q2 + LKD;
    float* gk1  = k2 + LKD;
    float* gk2  = gk1 + LKD;
    float* o_dense  = gk2 + LKD;
    float* o_sparse = o_dense + LKD;
    float* gbuf = o_sparse + LKD;
    float* tg1  = gbuf + LKD;                  // 4096*16
    float* tg2  = tg1 + (size_t)LL * 16;
    float* elog = tg2 + (size_t)LL * 16;       // 4096*4
    float* rw   = elog + (size_t)LL * 4;
    float* kv_all    = rw + (size_t)LL * 4;                    // 10.49M f32
    float* decay_all = kv_all + (size_t)64 * 8 * 5 * 64 * 64;  // 163840 f32

    unsigned short* bp = (unsigned short*)(decay_all + 163840);
    unsigned short* WallT2 = bp; bp += (size_t)1792 * 3072;    // [Wq|Wk|Wv|Wcat]
    unsigned short* WoT2   = bp; bp += (size_t)1024 * 1536;
    unsigned short* WqbT2  = bp; bp += (size_t)512 * 192;
    unsigned short* WkbT2  = bp; bp += (size_t)512 * 192;
    unsigned short* WgbT2  = bp; bp += (size_t)512 * 192;
    unsigned short* tqab2  = bp; bp += (size_t)LL * 192;
    unsigned short* tkab2  = bp; bp += (size_t)LL * 192;
    unsigned short* tgab2  = bp; bp += (size_t)LL * 192;
    float* tcat = (float*)bp;                                  // 4096*256 f32

    // time-multiplexed aliases of kv_all (disjoint lifetimes):
    unsigned short* xb2 = (unsigned short*)kv_all;   // [4096][3072]; dead before gla_kv
    unsigned short* og2 = (unsigned short*)kv_all;   // [4096][1536]; live after gla_o

    dim3 blk(256);
    dim3 tblk(32, 8);

    // ---- split conversions ----
    cvt_splitA<<<dim3((LL * 1024 + 255) / 256), blk, 0, stream>>>(x, xb2, LL * 1024, 10);
    cvtT_split<<<dim3(16, 32), tblk, 0, stream>>>(Wq, WallT2 + (size_t)0    * 3072, 1024, 512);
    cvtT_split<<<dim3(16, 32), tblk, 0, stream>>>(Wk, WallT2 + (size_t)512  * 3072, 1024, 512);
    cvtT_split<<<dim3(16, 32), tblk, 0, stream>>>(Wv, WallT2 + (size_t)1024 * 3072, 1024, 512);
    hipMemsetAsync(WallT2 + (size_t)1764 * 3072, 0, (size_t)(1792 - 1764) * 3072 * 2, stream);
    cvtT_split<<<dim3(2, 32), tblk, 0, stream>>>(Wqa,  WallT2 + (size_t)1536 * 3072, 1024, 64);
    cvtT_split<<<dim3(2, 32), tblk, 0, stream>>>(Wka,  WallT2 + (size_t)1600 * 3072, 1024, 64);
    cvtT_split<<<dim3(2, 32), tblk, 0, stream>>>(Wga,  WallT2 + (size_t)1664 * 3072, 1024, 64);
    cvtT_split<<<dim3(1, 32), tblk, 0, stream>>>(Wg1a, WallT2 + (size_t)1728 * 3072, 1024, 16);
    cvtT_split<<<dim3(1, 32), tblk, 0, stream>>>(Wg2a, WallT2 + (size_t)1744 * 3072, 1024, 16);
    cvtT_split<<<dim3(1, 32), tblk, 0, stream>>>(We,   WallT2 + (size_t)1760 * 3072, 1024, 4);
    cvtT_split<<<dim3(32, 16), tblk, 0, stream>>>(Wo, WoT2, 512, 1024);
    cvtT_split<<<dim3(16, 2),  tblk, 0, stream>>>(Wqb, WqbT2, 64, 512);
    cvtT_split<<<dim3(16, 2),  tblk, 0, stream>>>(Wkb, WkbT2, 64, 512);
    cvtT_split<<<dim3(16, 2),  tblk, 0, stream>>>(Wgb, WgbT2, 64, 512);

    // ---- mega GEMM: QKV + LoRA-a + gate-a + router in one launch ----
    gemm_qkvcat<<<dim3(14, 32), blk, 0, stream>>>(xb2, WallT2, q1, k1, v, tcat, LL, 3072);
    unpack_cat<<<dim3(LL), blk, 0, stream>>>(tcat, tqab2, tkab2, tgab2, tg1, tg2, elog);

    // ---- LoRA-b q2,k2 + gating projection (split MFMA, K'=192, z=3) ----
    gemm_mfma<<<dim3(4, 32, 3), blk, 0, stream>>>(tqab2, tkab2, tgab2, WqbT2, WkbT2, WgbT2,
                                                  q2, k2, gbuf, LL, KD_, 192);
    // ---- gate-b (f32, K=16, fused z=2) ----
    gemm128b<<<dim3(4, 32, 2), blk, 0, stream>>>(tg1, tg2, Wg1b, Wg2b, gk1, gk2, LL, KD_, 16);

    elementwise_pre<<<LL, 512, 0, stream>>>(q1, q2, k2, gk1, gk2, bg1, bg2, elog, rw);

    // ---- GLA: kv -> scan -> o (p fastest-varying for L2 sharing) ----
    gla_kv<<<dim3(5, 8, 64), blk, 0, stream>>>(k1, k2, gk1, gk2, v, rw, kv_all, decay_all);
    gla_state_scan<<<dim3(640), blk, 0, stream>>>(kv_all, decay_all);
    gla_o<<<dim3(5, 8, 64), blk, 0, stream>>>(q1, q2, k1, k2, gk1, gk2, v, rw,
                                              kv_all, o_dense, o_sparse);

    postnorm<<<LL, 512, 0, stream>>>(o_dense, o_sparse, gbuf, normw, og2);

    // ---- output projection (split MFMA, K'=1536) ----
    gemm_mfma<<<dim3(8, 32, 1), blk, 0, stream>>>(og2, og2, og2, WoT2, WoT2, WoT2,
                                                  (float*)d_out, (float*)d_out, (float*)d_out,
                                                  LL, 1024, 1536);
}

// Round 12
// 232.209 us; speedup vs baseline: 12.2447x; 1.1950x over previous
//
#include <hip/hip_runtime.h>
#include <math.h>

#define LL   4096
#define HH   8
#define DK_  64
#define DV_  64
#define KD_  512
#define NEXP 4

typedef __attribute__((ext_vector_type(8))) short  s16x8;
typedef __attribute__((ext_vector_type(4))) float  f32x4;

__device__ __forceinline__ unsigned short f2bf(float f) {   // RNE f32->bf16
    unsigned u = __float_as_uint(f);
    u += 0x7FFFu + ((u >> 16) & 1u);
    return (unsigned short)(u >> 16);
}

__device__ __forceinline__ void split2(float v, unsigned short& h, unsigned short& l) {
    h = f2bf(v);
    float hf = __uint_as_float((unsigned)h << 16);
    l = f2bf(v - hf);
}

// ---------------------------------------------------------------------------
// f32 [M][K] -> split-bf16 A layout [M][3K] = [hi | lo | hi]. K = 2^kshift.
// ---------------------------------------------------------------------------
__global__ void cvt_splitA(const float* __restrict__ in, unsigned short* __restrict__ out,
                           int n, int kshift)
{
    int i = blockIdx.x * 256 + threadIdx.x;
    if (i >= n) return;
    unsigned short h, l;
    split2(in[i], h, l);
    int K = 1 << kshift;
    int m = i >> kshift, k = i & (K - 1);
    size_t ro = (size_t)m * 3 * K;
    out[ro + k]         = h;
    out[ro + K + k]     = l;
    out[ro + 2 * K + k] = h;
}

// ---------------------------------------------------------------------------
// ALL weight conversions in one launch. z selects the weight. Each does
// f32 [K][N] -> split-bf16 B layout [N][ld] = [hi|hi|lo] (+zero pad for K=16).
// Grid (32, 32, 15), blk (32,8); blocks outside a weight's range exit.
// ---------------------------------------------------------------------------
__global__ void cvt_weights_all(
    const float* __restrict__ Wq,  const float* __restrict__ Wk,  const float* __restrict__ Wv,
    const float* __restrict__ Wqa, const float* __restrict__ Wka, const float* __restrict__ Wga,
    const float* __restrict__ Wg1a,const float* __restrict__ Wg2a,const float* __restrict__ We,
    const float* __restrict__ Wo,  const float* __restrict__ Wqb, const float* __restrict__ Wkb,
    const float* __restrict__ Wgb, const float* __restrict__ Wg1b,const float* __restrict__ Wg2b,
    unsigned short* __restrict__ WallT2, unsigned short* __restrict__ WoT2,
    unsigned short* __restrict__ WqbT2,  unsigned short* __restrict__ WkbT2,
    unsigned short* __restrict__ WgbT2,  unsigned short* __restrict__ Wg1bT2,
    unsigned short* __restrict__ Wg2bT2)
{
    int z = blockIdx.z;
    const float* W; unsigned short* WT; int K, N, ldr, pad = 0;
    switch (z) {
        case 0:  W = Wq;   WT = WallT2;                       K = 1024; N = 512;  ldr = 3072; break;
        case 1:  W = Wk;   WT = WallT2 + (size_t)512 * 3072;  K = 1024; N = 512;  ldr = 3072; break;
        case 2:  W = Wv;   WT = WallT2 + (size_t)1024 * 3072; K = 1024; N = 512;  ldr = 3072; break;
        case 3:  W = Wqa;  WT = WallT2 + (size_t)1536 * 3072; K = 1024; N = 64;   ldr = 3072; break;
        case 4:  W = Wka;  WT = WallT2 + (size_t)1600 * 3072; K = 1024; N = 64;   ldr = 3072; break;
        case 5:  W = Wga;  WT = WallT2 + (size_t)1664 * 3072; K = 1024; N = 64;   ldr = 3072; break;
        case 6:  W = Wg1a; WT = WallT2 + (size_t)1728 * 3072; K = 1024; N = 16;   ldr = 3072; break;
        case 7:  W = Wg2a; WT = WallT2 + (size_t)1744 * 3072; K = 1024; N = 16;   ldr = 3072; break;
        case 8:  W = We;   WT = WallT2 + (size_t)1760 * 3072; K = 1024; N = 4;    ldr = 3072; break;
        case 9:  W = Wo;   WT = WoT2;   K = 512; N = 1024; ldr = 1536; break;
        case 10: W = Wqb;  WT = WqbT2;  K = 64;  N = 512;  ldr = 192;  break;
        case 11: W = Wkb;  WT = WkbT2;  K = 64;  N = 512;  ldr = 192;  break;
        case 12: W = Wgb;  WT = WgbT2;  K = 64;  N = 512;  ldr = 192;  break;
        case 13: W = Wg1b; WT = Wg1bT2; K = 16;  N = 512;  ldr = 64; pad = 1; break;
        default: W = Wg2b; WT = Wg2bT2; K = 16;  N = 512;  ldr = 64; pad = 1; break;
    }
    int bx = blockIdx.x * 32, by = blockIdx.y * 32;
    if (bx >= N || by >= K) return;

    __shared__ float t[32][33];
    int x = threadIdx.x, y = threadIdx.y;
    #pragma unroll
    for (int i = 0; i < 4; ++i) {
        int kk = by + y + 8 * i;
        t[y + 8 * i][x] = (bx + x < N && kk < K) ? W[(size_t)kk * N + bx + x] : 0.f;
    }
    __syncthreads();
    #pragma unroll
    for (int i = 0; i < 4; ++i) {
        int n = bx + y + 8 * i;
        int kidx = by + x;
        if (n < N && kidx < K) {
            unsigned short h, l;
            split2(t[x][y + 8 * i], h, l);
            size_t ro = (size_t)n * ldr + kidx;
            WT[ro]         = h;
            WT[ro + K]     = h;
            WT[ro + 2 * K] = l;
        }
        if (pad && n < N && x < 16)
            WT[(size_t)n * ldr + 3 * K + x] = 0;
    }
}

// ---------------------------------------------------------------------------
// Mega GEMM: [q1|k1|v|tcat] = x @ [Wq|Wk|Wv|Wcat]. XCD-chunked swizzle.
// ---------------------------------------------------------------------------
__global__ __launch_bounds__(256) void gemm_qkvcat(
    const unsigned short* __restrict__ A, const unsigned short* __restrict__ B,
    float* __restrict__ Cq, float* __restrict__ Ck, float* __restrict__ Cv,
    float* __restrict__ Ct, int M, int K)
{
    __shared__ __align__(16) unsigned short sm[2 * 128 * 64];
    unsigned short* As = sm;
    unsigned short* Bs = sm + 128 * 64;

    int bxi = blockIdx.x, byi = blockIdx.y;
    {
        int gx = gridDim.x, nwg = gx * gridDim.y;
        int b = byi * gx + bxi;
        int s = (b & 7) * (nwg >> 3) + (b >> 3);
        bxi = s % gx; byi = s / gx;
    }

    int tid  = threadIdx.x;
    int lane = tid & 63;
    int w    = tid >> 6;
    int m0 = byi * 128, n0 = bxi * 128;
    int wr = w >> 1, wc = w & 1;

    f32x4 acc[4][4];
    #pragma unroll
    for (int i = 0; i < 4; ++i)
        #pragma unroll
        for (int j = 0; j < 4; ++j)
            acc[i][j] = (f32x4){0.f, 0.f, 0.f, 0.f};

    const int srow = (lane >> 3);
    const int scb  = ((lane & 7) * 16) ^ (srow << 4);

    for (int kt = 0; kt < K; kt += 64) {
        __syncthreads();
        #pragma unroll
        for (int q = 0; q < 4; ++q) {
            int r = w * 32 + q * 8 + srow;
            const char* ga = (const char*)A + ((size_t)(m0 + r) * K + kt) * 2 + scb;
            const char* gb = (const char*)B + ((size_t)(n0 + r) * K + kt) * 2 + scb;
            __builtin_amdgcn_global_load_lds(
                (const __attribute__((address_space(1))) void*)ga,
                (__attribute__((address_space(3))) void*)((char*)As + (w * 32 + q * 8) * 128),
                16, 0, 0);
            __builtin_amdgcn_global_load_lds(
                (const __attribute__((address_space(1))) void*)gb,
                (__attribute__((address_space(3))) void*)((char*)Bs + (w * 32 + q * 8) * 128),
                16, 0, 0);
        }
        __syncthreads();

        #pragma unroll
        for (int kk = 0; kk < 2; ++kk) {
            int kb = kk * 64 + (lane >> 4) * 16;
            s16x8 af[4], bfr[4];
            #pragma unroll
            for (int mi = 0; mi < 4; ++mi) {
                int r = wr * 64 + mi * 16 + (lane & 15);
                af[mi] = *(const s16x8*)((const char*)As + r * 128 + (kb ^ ((r & 7) << 4)));
            }
            #pragma unroll
            for (int ni = 0; ni < 4; ++ni) {
                int r = wc * 64 + ni * 16 + (lane & 15);
                bfr[ni] = *(const s16x8*)((const char*)Bs + r * 128 + (kb ^ ((r & 7) << 4)));
            }
            #pragma unroll
            for (int mi = 0; mi < 4; ++mi)
                #pragma unroll
                for (int ni = 0; ni < 4; ++ni)
                    acc[mi][ni] = __builtin_amdgcn_mfma_f32_16x16x32_bf16(
                        af[mi], bfr[ni], acc[mi][ni], 0, 0, 0);
        }
    }

    int base = n0 >> 9;
    float* C;
    int ldc, cb;
    if (base == 0)      { C = Cq; ldc = 512; cb = 0; }
    else if (base == 1) { C = Ck; ldc = 512; cb = 512; }
    else if (base == 2) { C = Cv; ldc = 512; cb = 1024; }
    else                { C = Ct; ldc = 256; cb = 1536; }

    #pragma unroll
    for (int mi = 0; mi < 4; ++mi)
        #pragma unroll
        for (int ni = 0; ni < 4; ++ni) {
            int col = n0 + wc * 64 + ni * 16 + (lane & 15) - cb;
            int rb  = m0 + wr * 64 + mi * 16 + (lane >> 4) * 4;
            #pragma unroll
            for (int j = 0; j < 4; ++j)
                C[(size_t)(rb + j) * ldc + col] = acc[mi][ni][j];
        }
}

// ---------------------------------------------------------------------------
// Split-bf16 MFMA GEMM, 3-way z (used for Wo). XCD-chunked swizzle.
// ---------------------------------------------------------------------------
__global__ __launch_bounds__(256) void gemm_mfma(
    const unsigned short* __restrict__ A0, const unsigned short* __restrict__ A1,
    const unsigned short* __restrict__ A2,
    const unsigned short* __restrict__ B0, const unsigned short* __restrict__ B1,
    const unsigned short* __restrict__ B2,
    float* __restrict__ C0, float* __restrict__ C1, float* __restrict__ C2,
    int M, int N, int K)
{
    const unsigned short* A = (blockIdx.z == 0) ? A0 : (blockIdx.z == 1) ? A1 : A2;
    const unsigned short* B = (blockIdx.z == 0) ? B0 : (blockIdx.z == 1) ? B1 : B2;
    float*                C = (blockIdx.z == 0) ? C0 : (blockIdx.z == 1) ? C1 : C2;

    __shared__ __align__(16) unsigned short sm[2 * 128 * 64];
    unsigned short* As = sm;
    unsigned short* Bs = sm + 128 * 64;

    int bxi = blockIdx.x, byi = blockIdx.y;
    {
        int gx = gridDim.x, nwg = gx * gridDim.y;
        if ((nwg & 7) == 0) {
            int b = byi * gx + bxi;
            int s = (b & 7) * (nwg >> 3) + (b >> 3);
            bxi = s % gx; byi = s / gx;
        }
    }

    int tid  = threadIdx.x;
    int lane = tid & 63;
    int w    = tid >> 6;
    int m0 = byi * 128, n0 = bxi * 128;
    int wr = w >> 1, wc = w & 1;

    f32x4 acc[4][4];
    #pragma unroll
    for (int i = 0; i < 4; ++i)
        #pragma unroll
        for (int j = 0; j < 4; ++j)
            acc[i][j] = (f32x4){0.f, 0.f, 0.f, 0.f};

    const int srow = (lane >> 3);
    const int scb  = ((lane & 7) * 16) ^ (srow << 4);

    for (int kt = 0; kt < K; kt += 64) {
        __syncthreads();
        #pragma unroll
        for (int q = 0; q < 4; ++q) {
            int r = w * 32 + q * 8 + srow;
            const char* ga = (const char*)A + ((size_t)(m0 + r) * K + kt) * 2 + scb;
            const char* gb = (const char*)B + ((size_t)(n0 + r) * K + kt) * 2 + scb;
            __builtin_amdgcn_global_load_lds(
                (const __attribute__((address_space(1))) void*)ga,
                (__attribute__((address_space(3))) void*)((char*)As + (w * 32 + q * 8) * 128),
                16, 0, 0);
            __builtin_amdgcn_global_load_lds(
                (const __attribute__((address_space(1))) void*)gb,
                (__attribute__((address_space(3))) void*)((char*)Bs + (w * 32 + q * 8) * 128),
                16, 0, 0);
        }
        __syncthreads();

        #pragma unroll
        for (int kk = 0; kk < 2; ++kk) {
            int kb = kk * 64 + (lane >> 4) * 16;
            s16x8 af[4], bfr[4];
            #pragma unroll
            for (int mi = 0; mi < 4; ++mi) {
                int r = wr * 64 + mi * 16 + (lane & 15);
                af[mi] = *(const s16x8*)((const char*)As + r * 128 + (kb ^ ((r & 7) << 4)));
            }
            #pragma unroll
            for (int ni = 0; ni < 4; ++ni) {
                int r = wc * 64 + ni * 16 + (lane & 15);
                bfr[ni] = *(const s16x8*)((const char*)Bs + r * 128 + (kb ^ ((r & 7) << 4)));
            }
            #pragma unroll
            for (int mi = 0; mi < 4; ++mi)
                #pragma unroll
                for (int ni = 0; ni < 4; ++ni)
                    acc[mi][ni] = __builtin_amdgcn_mfma_f32_16x16x32_bf16(
                        af[mi], bfr[ni], acc[mi][ni], 0, 0, 0);
        }
    }

    #pragma unroll
    for (int mi = 0; mi < 4; ++mi)
        #pragma unroll
        for (int ni = 0; ni < 4; ++ni) {
            int col = n0 + wc * 64 + ni * 16 + (lane & 15);
            int rb  = m0 + wr * 64 + mi * 16 + (lane >> 4) * 4;
            #pragma unroll
            for (int j = 0; j < 4; ++j)
                C[(size_t)(rb + j) * N + col] = acc[mi][ni][j];
        }
}

// ---------------------------------------------------------------------------
// Split-bf16 MFMA GEMM, 5-way z with per-z K (192,192,192,64,64).
// z: 0=q2 1=k2 2=gbuf (LoRA-b) 3=gk1 4=gk2 (gate-b). N=512 for all.
// ---------------------------------------------------------------------------
__global__ __launch_bounds__(256) void gemm_mfma5(
    const unsigned short* __restrict__ A0, const unsigned short* __restrict__ A1,
    const unsigned short* __restrict__ A2, const unsigned short* __restrict__ A3,
    const unsigned short* __restrict__ A4,
    const unsigned short* __restrict__ B0, const unsigned short* __restrict__ B1,
    const unsigned short* __restrict__ B2, const unsigned short* __restrict__ B3,
    const unsigned short* __restrict__ B4,
    float* __restrict__ C0, float* __restrict__ C1, float* __restrict__ C2,
    float* __restrict__ C3, float* __restrict__ C4, int M, int N)
{
    int z = blockIdx.z;
    const unsigned short* A = (z == 0) ? A0 : (z == 1) ? A1 : (z == 2) ? A2 : (z == 3) ? A3 : A4;
    const unsigned short* B = (z == 0) ? B0 : (z == 1) ? B1 : (z == 2) ? B2 : (z == 3) ? B3 : B4;
    float*                C = (z == 0) ? C0 : (z == 1) ? C1 : (z == 2) ? C2 : (z == 3) ? C3 : C4;
    int K = (z < 3) ? 192 : 64;

    __shared__ __align__(16) unsigned short sm[2 * 128 * 64];
    unsigned short* As = sm;
    unsigned short* Bs = sm + 128 * 64;

    int bxi = blockIdx.x, byi = blockIdx.y;
    {
        int gx = gridDim.x, nwg = gx * gridDim.y;
        if ((nwg & 7) == 0) {
            int b = byi * gx + bxi;
            int s = (b & 7) * (nwg >> 3) + (b >> 3);
            bxi = s % gx; byi = s / gx;
        }
    }

    int tid  = threadIdx.x;
    int lane = tid & 63;
    int w    = tid >> 6;
    int m0 = byi * 128, n0 = bxi * 128;
    int wr = w >> 1, wc = w & 1;

    f32x4 acc[4][4];
    #pragma unroll
    for (int i = 0; i < 4; ++i)
        #pragma unroll
        for (int j = 0; j < 4; ++j)
            acc[i][j] = (f32x4){0.f, 0.f, 0.f, 0.f};

    const int srow = (lane >> 3);
    const int scb  = ((lane & 7) * 16) ^ (srow << 4);

    for (int kt = 0; kt < K; kt += 64) {
        __syncthreads();
        #pragma unroll
        for (int q = 0; q < 4; ++q) {
            int r = w * 32 + q * 8 + srow;
            const char* ga = (const char*)A + ((size_t)(m0 + r) * K + kt) * 2 + scb;
            const char* gb = (const char*)B + ((size_t)(n0 + r) * K + kt) * 2 + scb;
            __builtin_amdgcn_global_load_lds(
                (const __attribute__((address_space(1))) void*)ga,
                (__attribute__((address_space(3))) void*)((char*)As + (w * 32 + q * 8) * 128),
                16, 0, 0);
            __builtin_amdgcn_global_load_lds(
                (const __attribute__((address_space(1))) void*)gb,
                (__attribute__((address_space(3))) void*)((char*)Bs + (w * 32 + q * 8) * 128),
                16, 0, 0);
        }
        __syncthreads();

        #pragma unroll
        for (int kk = 0; kk < 2; ++kk) {
            int kb = kk * 64 + (lane >> 4) * 16;
            s16x8 af[4], bfr[4];
            #pragma unroll
            for (int mi = 0; mi < 4; ++mi) {
                int r = wr * 64 + mi * 16 + (lane & 15);
                af[mi] = *(const s16x8*)((const char*)As + r * 128 + (kb ^ ((r & 7) << 4)));
            }
            #pragma unroll
            for (int ni = 0; ni < 4; ++ni) {
                int r = wc * 64 + ni * 16 + (lane & 15);
                bfr[ni] = *(const s16x8*)((const char*)Bs + r * 128 + (kb ^ ((r & 7) << 4)));
            }
            #pragma unroll
            for (int mi = 0; mi < 4; ++mi)
                #pragma unroll
                for (int ni = 0; ni < 4; ++ni)
                    acc[mi][ni] = __builtin_amdgcn_mfma_f32_16x16x32_bf16(
                        af[mi], bfr[ni], acc[mi][ni], 0, 0, 0);
        }
    }

    #pragma unroll
    for (int mi = 0; mi < 4; ++mi)
        #pragma unroll
        for (int ni = 0; ni < 4; ++ni) {
            int col = n0 + wc * 64 + ni * 16 + (lane & 15);
            int rb  = m0 + wr * 64 + mi * 16 + (lane >> 4) * 4;
            #pragma unroll
            for (int j = 0; j < 4; ++j)
                C[(size_t)(rb + j) * N + col] = acc[mi][ni][j];
        }
}

// ---------------------------------------------------------------------------
// Unpack tcat [LL][256]: LoRA-a -> split-bf16 [LL][192]; gate-a -> split-bf16
// [LL][64] (48 used + 16 zero pad); router -> elog f32.
// ---------------------------------------------------------------------------
__global__ void unpack_cat(const float* __restrict__ tcat,
                           unsigned short* __restrict__ tqab2,
                           unsigned short* __restrict__ tkab2,
                           unsigned short* __restrict__ tgab2,
                           unsigned short* __restrict__ tg1s2,
                           unsigned short* __restrict__ tg2s2,
                           float* __restrict__ elog)
{
    int m = blockIdx.x;
    int c = threadIdx.x;
    float vx = tcat[(size_t)m * 256 + c];
    if (c < 192) {
        unsigned short h, l;
        split2(vx, h, l);
        unsigned short* dst = (c < 64) ? tqab2 : (c < 128) ? tkab2 : tgab2;
        int cc = c & 63;
        size_t ro = (size_t)m * 192;
        dst[ro + cc]       = h;
        dst[ro + 64 + cc]  = l;
        dst[ro + 128 + cc] = h;
    } else if (c < 224) {
        unsigned short h, l;
        split2(vx, h, l);
        unsigned short* dst = (c < 208) ? tg1s2 : tg2s2;
        int cc = (c - 192) & 15;
        size_t ro = (size_t)m * 64;
        dst[ro + cc]      = h;
        dst[ro + 16 + cc] = l;
        dst[ro + 32 + cc] = h;
        dst[ro + 48 + cc] = 0;
    } else if (c < 228) {
        elog[(size_t)m * 4 + (c - 224)] = vx;
    }
}

// ---------------------------------------------------------------------------
__device__ inline float logsig(float x) {
    return fminf(x, 0.f) - log1pf(expf(-fabsf(x)));
}

__global__ void elementwise_pre(float* __restrict__ q1, float* __restrict__ q2,
                                float* __restrict__ k2, float* __restrict__ gk1,
                                float* __restrict__ gk2,
                                const float* __restrict__ bg1, const float* __restrict__ bg2,
                                const float* __restrict__ elog, float* __restrict__ rw)
{
    int l = blockIdx.x;
    int tid = threadIdx.x;
    int w = tid >> 6, lane = tid & 63;
    int idx = l * KD_ + (w << 6) + lane;

    q1[idx] *= 0.125f;
    q2[idx] *= 0.125f;

    float kv = k2[idx];
    float m = kv;
    for (int s = 32; s >= 1; s >>= 1) m = fmaxf(m, __shfl_xor(m, s, 64));
    float ev = expf(kv - m);
    float ssum = ev;
    for (int s = 32; s >= 1; s >>= 1) ssum += __shfl_xor(ssum, s, 64);
    k2[idx] = ev / ssum;

    int bi = (w << 6) + lane;
    gk1[idx] = logsig(gk1[idx] + bg1[bi]) * (1.f / 16.f);
    gk2[idx] = logsig(gk2[idx] + bg2[bi]) * (1.f / 16.f);

    if (tid == 0) {
        float xs[4];
        float mm = -1e30f;
        for (int j = 0; j < 4; ++j) { xs[j] = elog[l * 4 + j]; mm = fmaxf(mm, xs[j]); }
        float s4 = 0.f;
        for (int j = 0; j < 4; ++j) { xs[j] = expf(xs[j] - mm); s4 += xs[j]; }
        for (int j = 0; j < 4; ++j) xs[j] /= s4;
        int arg = 0; float best = xs[0];
        for (int j = 1; j < 4; ++j) if (xs[j] > best) { best = xs[j]; arg = j; }
        for (int j = 0; j < 4; ++j) rw[l * 4 + j] = (j == arg) ? xs[j] : 0.f;
    }
}

// ---------------------------------------------------------------------------
// Phase 1: chunk_kv + decay via split-bf16 MFMA. XCD-chunked swizzle over
// (p,h,c) so blocks sharing a chunk's rows land on the same XCD.
// ---------------------------------------------------------------------------
__global__ void gla_kv(const float* __restrict__ k1, const float* __restrict__ k2,
                       const float* __restrict__ gk1, const float* __restrict__ gk2,
                       const float* __restrict__ v, const float* __restrict__ rw,
                       float* __restrict__ kv_all, float* __restrict__ decay_all)
{
    int flat = (blockIdx.z * 8 + blockIdx.y) * 5 + blockIdx.x;
    int sfl = (flat & 7) * 320 + (flat >> 3);
    int p = sfl % 5, h = (sfl / 5) & 7, c = sfl / 40;

    const float* kp = (p == 0) ? k1 : k2;
    const float* gp = (p == 0) ? gk1 : gk2;

    __shared__ __align__(16) unsigned short kgT[64][200];  // [d][hi|lo|hi along t]
    __shared__ __align__(16) unsigned short vT[64][200];   // [e][hi|hi|lo along t]
    __shared__ float glast[64];
    __shared__ float wrow[64];
    __shared__ float segsum[4][64];

    int tid = threadIdx.x;
    int lane = tid & 63, w = tid >> 6;
    int d = lane, seg = w;

    float gkv[16], kvv[16], vv_[16];
    #pragma unroll
    for (int i = 0; i < 16; ++i) {
        size_t base = (size_t)(c * 64 + seg * 16 + i) * KD_ + (h << 6) + d;
        gkv[i] = gp[base];
        kvv[i] = kp[base];
        vv_[i] = v[base];
    }
    if (tid < 64) {
        int lg = c * 64 + tid;
        wrow[tid] = (p == 0) ? 1.f : rw[lg * 4 + (p - 1)];
    }
    __syncthreads();

    {
        float s = 0.f;
        #pragma unroll
        for (int i = 0; i < 16; ++i) {
            int t = seg * 16 + i;
            float xg = gkv[i];
            if (p > 0 && !(wrow[t] > 0.f)) xg = 0.f;
            s += xg;
            gkv[i] = s;
        }
        segsum[seg][d] = s;
    }
    __syncthreads();
    {
        float off = 0.f, tot = 0.f;
        #pragma unroll
        for (int ss = 0; ss < 4; ++ss) {
            float x = segsum[ss][d];
            tot += x;
            if (ss < seg) off += x;
        }
        if (seg == 0) glast[d] = tot;
        #pragma unroll
        for (int i = 0; i < 16; ++i) {
            int t = seg * 16 + i;
            float g = off + gkv[i];
            float kgval = kvv[i] * wrow[t] * expf(-g);
            unsigned short hh, ll;
            split2(kgval, hh, ll);
            kgT[d][t] = hh; kgT[d][64 + t] = ll; kgT[d][128 + t] = hh;
            split2(vv_[i], hh, ll);
            vT[d][t] = hh; vT[d][64 + t] = hh; vT[d][128 + t] = ll;
        }
    }
    __syncthreads();

    size_t base = (size_t)((c * 8 + h) * 5 + p) * 4096;
    int ar = 16 * w + (lane & 15);
    int kb = (lane >> 4) * 16;
    float dec_[4];
    #pragma unroll
    for (int j = 0; j < 4; ++j) dec_[j] = expf(glast[16 * w + (lane >> 4) * 4 + j]);

    #pragma unroll
    for (int ni = 0; ni < 4; ++ni) {
        f32x4 acc = (f32x4){0.f, 0.f, 0.f, 0.f};
        int br = 16 * ni + (lane & 15);
        #pragma unroll
        for (int kk = 0; kk < 6; ++kk) {
            s16x8 af = *(const s16x8*)((const char*)&kgT[ar][0] + kk * 64 + kb);
            s16x8 bf = *(const s16x8*)((const char*)&vT[br][0] + kk * 64 + kb);
            acc = __builtin_amdgcn_mfma_f32_16x16x32_bf16(af, bf, acc, 0, 0, 0);
        }
        #pragma unroll
        for (int j = 0; j < 4; ++j) {
            int dd = 16 * w + (lane >> 4) * 4 + j;
            kv_all[base + dd * 64 + 16 * ni + (lane & 15)] = acc[j] * dec_[j];
        }
    }
    if (tid < 64) decay_all[(size_t)((c * 8 + h) * 5 + p) * 64 + tid] = expf(glast[tid]);
}

// ---------------------------------------------------------------------------
// Inter-chunk state scan: elementwise, in place over kv_all (f32).
// ---------------------------------------------------------------------------
__global__ void gla_state_scan(float* __restrict__ kv, const float* __restrict__ decay)
{
    int gid = blockIdx.x * 256 + threadIdx.x;
    int sub = gid >> 6;
    const size_t stride = 8 * 5 * 64 * 64;
    float S = 0.f;
    float kvv = kv[gid];
    for (int c = 0; c < 64; ++c) {
        size_t o = (size_t)c * stride + gid;
        float nxt = (c < 63) ? kv[o + stride] : 0.f;
        float dec = decay[c * 2560 + sub];
        kv[o] = S;
        S = fmaf(dec, S, kvv);
        kvv = nxt;
    }
}

// ---------------------------------------------------------------------------
// Phase 2: per-pass output via bf16 MFMA. XCD-chunked swizzle over (p,h,c).
// ---------------------------------------------------------------------------
__global__ void gla_o(const float* __restrict__ q1, const float* __restrict__ q2,
                      const float* __restrict__ k1, const float* __restrict__ k2,
                      const float* __restrict__ gk1, const float* __restrict__ gk2,
                      const float* __restrict__ v, const float* __restrict__ rw,
                      const float* __restrict__ Spre,
                      float* __restrict__ o_dense, float* __restrict__ o_sparse)
{
    int flat = (blockIdx.z * 8 + blockIdx.y) * 5 + blockIdx.x;
    int sfl = (flat & 7) * 320 + (flat >> 3);
    int p = sfl % 5, h = (sfl / 5) & 7, c = sfl / 40;

    const float* qp = (p == 0) ? q1 : q2;
    const float* kp = (p == 0) ? k1 : k2;
    const float* gp = (p == 0) ? gk1 : gk2;

    __shared__ __align__(16) unsigned short qg_bf[64][72];  // [t][d]
    __shared__ __align__(16) unsigned short kg_bf[64][72];  // [s][d]
    __shared__ __align__(16) unsigned short A_bf[64][72];   // [t][s]
    __shared__ __align__(16) unsigned short vT_bf[64][72];  // [e][s]
    __shared__ __align__(16) unsigned short ST_bf[64][72];  // [e][d]
    __shared__ float wrow[64];
    __shared__ float segsum[4][64];

    int tid = threadIdx.x;
    int lane = tid & 63, w = tid >> 6;
    int d = lane, seg = w;

    {
        float gkv[16], qv[16], kvv[16];
        #pragma unroll
        for (int i = 0; i < 16; ++i) {
            size_t base = (size_t)(c * 64 + seg * 16 + i) * KD_ + (h << 6) + d;
            gkv[i] = gp[base];
            qv[i]  = qp[base];
            kvv[i] = kp[base];
        }
        if (tid < 64) {
            int lg = c * 64 + tid;
            wrow[tid] = (p == 0) ? 1.f : rw[lg * 4 + (p - 1)];
        }
        __syncthreads();

        float s = 0.f;
        #pragma unroll
        for (int i = 0; i < 16; ++i) {
            int t = seg * 16 + i;
            float xg = gkv[i];
            if (p > 0 && !(wrow[t] > 0.f)) xg = 0.f;
            s += xg;
            gkv[i] = s;
        }
        segsum[seg][d] = s;
        __syncthreads();

        float off = 0.f;
        for (int ss = 0; ss < seg; ++ss) off += segsum[ss][d];
        #pragma unroll
        for (int i = 0; i < 16; ++i) {
            int t = seg * 16 + i;
            float g = off + gkv[i];
            float wv = wrow[t];
            qg_bf[t][d] = f2bf(qv[i] * wv * expf(g));
            kg_bf[t][d] = f2bf(kvv[i] * wv * expf(-g));
        }
    }

    {
        size_t sbase = (size_t)((c * 8 + h) * 5 + p) * 4096;
        float Sv[16], vv_[16];
        #pragma unroll
        for (int i = 0; i < 16; ++i) Sv[i] = Spre[sbase + tid + (i << 8)];
        #pragma unroll
        for (int i = 0; i < 16; ++i)
            vv_[i] = v[(size_t)(c * 64 + seg * 16 + i) * KD_ + (h << 6) + d];
        #pragma unroll
        for (int i = 0; i < 16; ++i) ST_bf[d][4 * i + seg] = f2bf(Sv[i]);
        #pragma unroll
        for (int i = 0; i < 16; ++i) vT_bf[d][seg * 16 + i] = f2bf(vv_[i]);
    }
    __syncthreads();

    int am = 16 * w + (lane & 15);
    int kb = (lane >> 4) * 16;

    #pragma unroll
    for (int ni = 0; ni < 4; ++ni) {
        f32x4 acc = (f32x4){0.f, 0.f, 0.f, 0.f};
        if (ni <= w) {
            int br = 16 * ni + (lane & 15);
            #pragma unroll
            for (int kk = 0; kk < 2; ++kk) {
                s16x8 af = *(const s16x8*)((const char*)&qg_bf[am][0] + kk * 64 + kb);
                s16x8 bf = *(const s16x8*)((const char*)&kg_bf[br][0] + kk * 64 + kb);
                acc = __builtin_amdgcn_mfma_f32_16x16x32_bf16(af, bf, acc, 0, 0, 0);
            }
        }
        #pragma unroll
        for (int j = 0; j < 4; ++j) {
            int t = 16 * w + (lane >> 4) * 4 + j;
            int s = 16 * ni + (lane & 15);
            A_bf[t][s] = (s <= t) ? f2bf(acc[j]) : (unsigned short)0;
        }
    }
    __syncthreads();

    #pragma unroll
    for (int ni = 0; ni < 4; ++ni) {
        f32x4 acc = (f32x4){0.f, 0.f, 0.f, 0.f};
        int br = 16 * ni + (lane & 15);
        #pragma unroll
        for (int kk = 0; kk < 2; ++kk) {
            s16x8 af = *(const s16x8*)((const char*)&qg_bf[am][0] + kk * 64 + kb);
            s16x8 bf = *(const s16x8*)((const char*)&ST_bf[br][0] + kk * 64 + kb);
            acc = __builtin_amdgcn_mfma_f32_16x16x32_bf16(af, bf, acc, 0, 0, 0);
        }
        #pragma unroll
        for (int kk = 0; kk < 2; ++kk) {
            s16x8 af = *(const s16x8*)((const char*)&A_bf[am][0] + kk * 64 + kb);
            s16x8 bf = *(const s16x8*)((const char*)&vT_bf[br][0] + kk * 64 + kb);
            acc = __builtin_amdgcn_mfma_f32_16x16x32_bf16(af, bf, acc, 0, 0, 0);
        }
        #pragma unroll
        for (int j = 0; j < 4; ++j) {
            int t = 16 * w + (lane >> 4) * 4 + j;
            int e = 16 * ni + (lane & 15);
            size_t idx = (size_t)(c * 64 + t) * KD_ + (h << 6) + e;
            if (p == 0)                 o_dense[idx]  = acc[j];
            else if (wrow[t] > 0.f)     o_sparse[idx] = acc[j];
        }
    }
}

// ---------------------------------------------------------------------------
// Post: sum dense+sparse, RMS-norm, * norm_w, * silu(g); emit split-bf16 A.
// ---------------------------------------------------------------------------
__global__ void postnorm(const float* __restrict__ o_dense, const float* __restrict__ o_sparse,
                         const float* __restrict__ gbuf,
                         const float* __restrict__ norm_w, unsigned short* __restrict__ og2)
{
    int l = blockIdx.x;
    int tid = threadIdx.x;
    int w = tid >> 6, lane = tid & 63;
    int bi = (w << 6) + lane;
    int idx = l * KD_ + bi;
    float o = o_dense[idx] + o_sparse[idx];
    float ss = o * o;
    for (int s = 32; s >= 1; s >>= 1) ss += __shfl_xor(ss, s, 64);
    float r = rsqrtf(ss * (1.f / 64.f) + 1e-5f);
    float val = o * r * norm_w[lane];
    float gv = gbuf[idx];
    val *= gv / (1.f + expf(-gv));
    unsigned short h, lo;
    split2(val, h, lo);
    size_t ro = (size_t)l * (3 * KD_) + bi;
    og2[ro]           = h;
    og2[ro + KD_]     = lo;
    og2[ro + 2 * KD_] = h;
}

// ---------------------------------------------------------------------------
extern "C" void kernel_launch(void* const* d_in, const int* in_sizes, int n_in,
                              void* d_out, int out_size, void* d_ws, size_t ws_size,
                              hipStream_t stream)
{
    const float* x    = (const float*)d_in[0];
    const float* Wq   = (const float*)d_in[1];
    const float* Wk   = (const float*)d_in[2];
    const float* Wv   = (const float*)d_in[3];
    const float* Wqa  = (const float*)d_in[4];
    const float* Wqb  = (const float*)d_in[5];
    const float* Wka  = (const float*)d_in[6];
    const float* Wkb  = (const float*)d_in[7];
    const float* Wg1a = (const float*)d_in[8];
    const float* Wg1b = (const float*)d_in[9];
    const float* bg1  = (const float*)d_in[10];
    const float* Wg2a = (const float*)d_in[11];
    const float* Wg2b = (const float*)d_in[12];
    const float* bg2  = (const float*)d_in[13];
    const float* We   = (const float*)d_in[14];
    const float* Wga  = (const float*)d_in[15];
    const float* Wgb  = (const float*)d_in[16];
    const float* normw= (const float*)d_in[17];
    const float* Wo   = (const float*)d_in[18];

    float* ws = (float*)d_ws;
    const size_t LKD = (size_t)LL * KD_;   // 2M floats
    float* q1   = ws;
    float* k1   = q1 + LKD;
    float* v    = k1 + LKD;
    float* q2   = v  + LKD;
    float* k2   = q2 + LKD;
    float* gk1  = k2 + LKD;
    float* gk2  = gk1 + LKD;
    float* o_dense  = gk2 + LKD;
    float* o_sparse = o_dense + LKD;
    float* gbuf = o_sparse + LKD;
    float* elog = gbuf + LKD;                  // 4096*4
    float* rw   = elog + (size_t)LL * 4;
    float* kv_all    = rw + (size_t)LL * 4;                    // 10.49M f32
    float* decay_all = kv_all + (size_t)64 * 8 * 5 * 64 * 64;  // 163840 f32

    unsigned short* bp = (unsigned short*)(decay_all + 163840);
    unsigned short* WallT2 = bp; bp += (size_t)1792 * 3072;    // [Wq|Wk|Wv|Wcat]
    unsigned short* WoT2   = bp; bp += (size_t)1024 * 1536;
    unsigned short* WqbT2  = bp; bp += (size_t)512 * 192;
    unsigned short* WkbT2  = bp; bp += (size_t)512 * 192;
    unsigned short* WgbT2  = bp; bp += (size_t)512 * 192;
    unsigned short* Wg1bT2 = bp; bp += (size_t)512 * 64;
    unsigned short* Wg2bT2 = bp; bp += (size_t)512 * 64;
    unsigned short* tqab2  = bp; bp += (size_t)LL * 192;
    unsigned short* tkab2  = bp; bp += (size_t)LL * 192;
    unsigned short* tgab2  = bp; bp += (size_t)LL * 192;
    unsigned short* tg1s2  = bp; bp += (size_t)LL * 64;
    unsigned short* tg2s2  = bp; bp += (size_t)LL * 64;
    float* tcat = (float*)bp;                                  // 4096*256 f32

    // time-multiplexed aliases of kv_all (disjoint lifetimes):
    unsigned short* xb2 = (unsigned short*)kv_all;   // [4096][3072]; dead before gla_kv
    unsigned short* og2 = (unsigned short*)kv_all;   // [4096][1536]; live after gla_o

    dim3 blk(256);
    dim3 tblk(32, 8);

    // ---- conversions: x split + ALL weights in one launch ----
    cvt_splitA<<<dim3((LL * 1024 + 255) / 256), blk, 0, stream>>>(x, xb2, LL * 1024, 10);
    hipMemsetAsync(WallT2 + (size_t)1764 * 3072, 0, (size_t)(1792 - 1764) * 3072 * 2, stream);
    cvt_weights_all<<<dim3(32, 32, 15), tblk, 0, stream>>>(
        Wq, Wk, Wv, Wqa, Wka, Wga, Wg1a, Wg2a, We, Wo, Wqb, Wkb, Wgb, Wg1b, Wg2b,
        WallT2, WoT2, WqbT2, WkbT2, WgbT2, Wg1bT2, Wg2bT2);

    // ---- mega GEMM: QKV + LoRA-a + gate-a + router ----
    gemm_qkvcat<<<dim3(14, 32), blk, 0, stream>>>(xb2, WallT2, q1, k1, v, tcat, LL, 3072);
    unpack_cat<<<dim3(LL), blk, 0, stream>>>(tcat, tqab2, tkab2, tgab2, tg1s2, tg2s2, elog);

    // ---- LoRA-b q2,k2,gbuf + gate-b gk1,gk2 (split MFMA, per-z K) ----
    gemm_mfma5<<<dim3(4, 32, 5), blk, 0, stream>>>(
        tqab2, tkab2, tgab2, tg1s2, tg2s2,
        WqbT2, WkbT2, WgbT2, Wg1bT2, Wg2bT2,
        q2, k2, gbuf, gk1, gk2, LL, KD_);

    elementwise_pre<<<LL, 512, 0, stream>>>(q1, q2, k2, gk1, gk2, bg1, bg2, elog, rw);

    // ---- GLA: kv -> scan -> o ----
    gla_kv<<<dim3(5, 8, 64), blk, 0, stream>>>(k1, k2, gk1, gk2, v, rw, kv_all, decay_all);
    gla_state_scan<<<dim3(640), blk, 0, stream>>>(kv_all, decay_all);
    gla_o<<<dim3(5, 8, 64), blk, 0, stream>>>(q1, q2, k1, k2, gk1, gk2, v, rw,
                                              kv_all, o_dense, o_sparse);

    postnorm<<<LL, 512, 0, stream>>>(o_dense, o_sparse, gbuf, normw, og2);

    // ---- output projection (split MFMA, K'=1536) ----
    gemm_mfma<<<dim3(8, 32, 1), blk, 0, stream>>>(og2, og2, og2, WoT2, WoT2, WoT2,
                                                  (float*)d_out, (float*)d_out, (float*)d_out,
                                                  LL, 1024, 1536);
}

// Round 13
// 231.183 us; speedup vs baseline: 12.2990x; 1.0044x over previous
//
#include <hip/hip_runtime.h>
#include <math.h>

#define LL   4096
#define HH   8
#define DK_  64
#define DV_  64
#define KD_  512
#define NEXP 4

typedef __attribute__((ext_vector_type(8))) short  s16x8;
typedef __attribute__((ext_vector_type(4))) float  f32x4;

__device__ __forceinline__ unsigned short f2bf(float f) {   // RNE f32->bf16
    unsigned u = __float_as_uint(f);
    u += 0x7FFFu + ((u >> 16) & 1u);
    return (unsigned short)(u >> 16);
}

__device__ __forceinline__ void split2(float v, unsigned short& h, unsigned short& l) {
    h = f2bf(v);
    float hf = __uint_as_float((unsigned)h << 16);
    l = f2bf(v - hf);
}

// ---------------------------------------------------------------------------
// f32 [M][K] -> split-bf16 A layout [M][3K] = [hi | lo | hi]. K = 2^kshift.
// ---------------------------------------------------------------------------
__global__ void cvt_splitA(const float* __restrict__ in, unsigned short* __restrict__ out,
                           int n, int kshift)
{
    int i = blockIdx.x * 256 + threadIdx.x;
    if (i >= n) return;
    unsigned short h, l;
    split2(in[i], h, l);
    int K = 1 << kshift;
    int m = i >> kshift, k = i & (K - 1);
    size_t ro = (size_t)m * 3 * K;
    out[ro + k]         = h;
    out[ro + K + k]     = l;
    out[ro + 2 * K + k] = h;
}

// ---------------------------------------------------------------------------
// ALL weight conversions in one launch. z selects the weight. Each does
// f32 [K][N] -> split-bf16 B layout [N][ld] = [hi|hi|lo] (+zero pad for K=16).
// Grid (32, 32, 15), blk (32,8); blocks outside a weight's range exit.
// ---------------------------------------------------------------------------
__global__ void cvt_weights_all(
    const float* __restrict__ Wq,  const float* __restrict__ Wk,  const float* __restrict__ Wv,
    const float* __restrict__ Wqa, const float* __restrict__ Wka, const float* __restrict__ Wga,
    const float* __restrict__ Wg1a,const float* __restrict__ Wg2a,const float* __restrict__ We,
    const float* __restrict__ Wo,  const float* __restrict__ Wqb, const float* __restrict__ Wkb,
    const float* __restrict__ Wgb, const float* __restrict__ Wg1b,const float* __restrict__ Wg2b,
    unsigned short* __restrict__ WallT2, unsigned short* __restrict__ WoT2,
    unsigned short* __restrict__ WqbT2,  unsigned short* __restrict__ WkbT2,
    unsigned short* __restrict__ WgbT2,  unsigned short* __restrict__ Wg1bT2,
    unsigned short* __restrict__ Wg2bT2)
{
    int z = blockIdx.z;
    const float* W; unsigned short* WT; int K, N, ldr, pad = 0;
    switch (z) {
        case 0:  W = Wq;   WT = WallT2;                       K = 1024; N = 512;  ldr = 3072; break;
        case 1:  W = Wk;   WT = WallT2 + (size_t)512 * 3072;  K = 1024; N = 512;  ldr = 3072; break;
        case 2:  W = Wv;   WT = WallT2 + (size_t)1024 * 3072; K = 1024; N = 512;  ldr = 3072; break;
        case 3:  W = Wqa;  WT = WallT2 + (size_t)1536 * 3072; K = 1024; N = 64;   ldr = 3072; break;
        case 4:  W = Wka;  WT = WallT2 + (size_t)1600 * 3072; K = 1024; N = 64;   ldr = 3072; break;
        case 5:  W = Wga;  WT = WallT2 + (size_t)1664 * 3072; K = 1024; N = 64;   ldr = 3072; break;
        case 6:  W = Wg1a; WT = WallT2 + (size_t)1728 * 3072; K = 1024; N = 16;   ldr = 3072; break;
        case 7:  W = Wg2a; WT = WallT2 + (size_t)1744 * 3072; K = 1024; N = 16;   ldr = 3072; break;
        case 8:  W = We;   WT = WallT2 + (size_t)1760 * 3072; K = 1024; N = 4;    ldr = 3072; break;
        case 9:  W = Wo;   WT = WoT2;   K = 512; N = 1024; ldr = 1536; break;
        case 10: W = Wqb;  WT = WqbT2;  K = 64;  N = 512;  ldr = 192;  break;
        case 11: W = Wkb;  WT = WkbT2;  K = 64;  N = 512;  ldr = 192;  break;
        case 12: W = Wgb;  WT = WgbT2;  K = 64;  N = 512;  ldr = 192;  break;
        case 13: W = Wg1b; WT = Wg1bT2; K = 16;  N = 512;  ldr = 64; pad = 1; break;
        default: W = Wg2b; WT = Wg2bT2; K = 16;  N = 512;  ldr = 64; pad = 1; break;
    }
    int bx = blockIdx.x * 32, by = blockIdx.y * 32;
    if (bx >= N || by >= K) return;

    __shared__ float t[32][33];
    int x = threadIdx.x, y = threadIdx.y;
    #pragma unroll
    for (int i = 0; i < 4; ++i) {
        int kk = by + y + 8 * i;
        t[y + 8 * i][x] = (bx + x < N && kk < K) ? W[(size_t)kk * N + bx + x] : 0.f;
    }
    __syncthreads();
    #pragma unroll
    for (int i = 0; i < 4; ++i) {
        int n = bx + y + 8 * i;
        int kidx = by + x;
        if (n < N && kidx < K) {
            unsigned short h, l;
            split2(t[x][y + 8 * i], h, l);
            size_t ro = (size_t)n * ldr + kidx;
            WT[ro]         = h;
            WT[ro + K]     = h;
            WT[ro + 2 * K] = l;
        }
        if (pad && n < N && x < 16)
            WT[(size_t)n * ldr + 3 * K + x] = 0;
    }
}

// ---------------------------------------------------------------------------
// Mega GEMM: [q1|k1|v|tcat] = x @ [Wq|Wk|Wv|Wcat]. XCD-chunked swizzle.
// ---------------------------------------------------------------------------
__global__ __launch_bounds__(256) void gemm_qkvcat(
    const unsigned short* __restrict__ A, const unsigned short* __restrict__ B,
    float* __restrict__ Cq, float* __restrict__ Ck, float* __restrict__ Cv,
    float* __restrict__ Ct, int M, int K)
{
    __shared__ __align__(16) unsigned short sm[2 * 128 * 64];
    unsigned short* As = sm;
    unsigned short* Bs = sm + 128 * 64;

    int bxi = blockIdx.x, byi = blockIdx.y;
    {
        int gx = gridDim.x, nwg = gx * gridDim.y;
        int b = byi * gx + bxi;
        int s = (b & 7) * (nwg >> 3) + (b >> 3);
        bxi = s % gx; byi = s / gx;
    }

    int tid  = threadIdx.x;
    int lane = tid & 63;
    int w    = tid >> 6;
    int m0 = byi * 128, n0 = bxi * 128;
    int wr = w >> 1, wc = w & 1;

    f32x4 acc[4][4];
    #pragma unroll
    for (int i = 0; i < 4; ++i)
        #pragma unroll
        for (int j = 0; j < 4; ++j)
            acc[i][j] = (f32x4){0.f, 0.f, 0.f, 0.f};

    const int srow = (lane >> 3);
    const int scb  = ((lane & 7) * 16) ^ (srow << 4);

    for (int kt = 0; kt < K; kt += 64) {
        __syncthreads();
        #pragma unroll
        for (int q = 0; q < 4; ++q) {
            int r = w * 32 + q * 8 + srow;
            const char* ga = (const char*)A + ((size_t)(m0 + r) * K + kt) * 2 + scb;
            const char* gb = (const char*)B + ((size_t)(n0 + r) * K + kt) * 2 + scb;
            __builtin_amdgcn_global_load_lds(
                (const __attribute__((address_space(1))) void*)ga,
                (__attribute__((address_space(3))) void*)((char*)As + (w * 32 + q * 8) * 128),
                16, 0, 0);
            __builtin_amdgcn_global_load_lds(
                (const __attribute__((address_space(1))) void*)gb,
                (__attribute__((address_space(3))) void*)((char*)Bs + (w * 32 + q * 8) * 128),
                16, 0, 0);
        }
        __syncthreads();

        #pragma unroll
        for (int kk = 0; kk < 2; ++kk) {
            int kb = kk * 64 + (lane >> 4) * 16;
            s16x8 af[4], bfr[4];
            #pragma unroll
            for (int mi = 0; mi < 4; ++mi) {
                int r = wr * 64 + mi * 16 + (lane & 15);
                af[mi] = *(const s16x8*)((const char*)As + r * 128 + (kb ^ ((r & 7) << 4)));
            }
            #pragma unroll
            for (int ni = 0; ni < 4; ++ni) {
                int r = wc * 64 + ni * 16 + (lane & 15);
                bfr[ni] = *(const s16x8*)((const char*)Bs + r * 128 + (kb ^ ((r & 7) << 4)));
            }
            #pragma unroll
            for (int mi = 0; mi < 4; ++mi)
                #pragma unroll
                for (int ni = 0; ni < 4; ++ni)
                    acc[mi][ni] = __builtin_amdgcn_mfma_f32_16x16x32_bf16(
                        af[mi], bfr[ni], acc[mi][ni], 0, 0, 0);
        }
    }

    int base = n0 >> 9;
    float* C;
    int ldc, cb;
    if (base == 0)      { C = Cq; ldc = 512; cb = 0; }
    else if (base == 1) { C = Ck; ldc = 512; cb = 512; }
    else if (base == 2) { C = Cv; ldc = 512; cb = 1024; }
    else                { C = Ct; ldc = 256; cb = 1536; }

    #pragma unroll
    for (int mi = 0; mi < 4; ++mi)
        #pragma unroll
        for (int ni = 0; ni < 4; ++ni) {
            int col = n0 + wc * 64 + ni * 16 + (lane & 15) - cb;
            int rb  = m0 + wr * 64 + mi * 16 + (lane >> 4) * 4;
            #pragma unroll
            for (int j = 0; j < 4; ++j)
                C[(size_t)(rb + j) * ldc + col] = acc[mi][ni][j];
        }
}

// ---------------------------------------------------------------------------
// Split-bf16 MFMA GEMM, 3-way z (used for Wo). XCD-chunked swizzle.
// ---------------------------------------------------------------------------
__global__ __launch_bounds__(256) void gemm_mfma(
    const unsigned short* __restrict__ A0, const unsigned short* __restrict__ A1,
    const unsigned short* __restrict__ A2,
    const unsigned short* __restrict__ B0, const unsigned short* __restrict__ B1,
    const unsigned short* __restrict__ B2,
    float* __restrict__ C0, float* __restrict__ C1, float* __restrict__ C2,
    int M, int N, int K)
{
    const unsigned short* A = (blockIdx.z == 0) ? A0 : (blockIdx.z == 1) ? A1 : A2;
    const unsigned short* B = (blockIdx.z == 0) ? B0 : (blockIdx.z == 1) ? B1 : B2;
    float*                C = (blockIdx.z == 0) ? C0 : (blockIdx.z == 1) ? C1 : C2;

    __shared__ __align__(16) unsigned short sm[2 * 128 * 64];
    unsigned short* As = sm;
    unsigned short* Bs = sm + 128 * 64;

    int bxi = blockIdx.x, byi = blockIdx.y;
    {
        int gx = gridDim.x, nwg = gx * gridDim.y;
        if ((nwg & 7) == 0) {
            int b = byi * gx + bxi;
            int s = (b & 7) * (nwg >> 3) + (b >> 3);
            bxi = s % gx; byi = s / gx;
        }
    }

    int tid  = threadIdx.x;
    int lane = tid & 63;
    int w    = tid >> 6;
    int m0 = byi * 128, n0 = bxi * 128;
    int wr = w >> 1, wc = w & 1;

    f32x4 acc[4][4];
    #pragma unroll
    for (int i = 0; i < 4; ++i)
        #pragma unroll
        for (int j = 0; j < 4; ++j)
            acc[i][j] = (f32x4){0.f, 0.f, 0.f, 0.f};

    const int srow = (lane >> 3);
    const int scb  = ((lane & 7) * 16) ^ (srow << 4);

    for (int kt = 0; kt < K; kt += 64) {
        __syncthreads();
        #pragma unroll
        for (int q = 0; q < 4; ++q) {
            int r = w * 32 + q * 8 + srow;
            const char* ga = (const char*)A + ((size_t)(m0 + r) * K + kt) * 2 + scb;
            const char* gb = (const char*)B + ((size_t)(n0 + r) * K + kt) * 2 + scb;
            __builtin_amdgcn_global_load_lds(
                (const __attribute__((address_space(1))) void*)ga,
                (__attribute__((address_space(3))) void*)((char*)As + (w * 32 + q * 8) * 128),
                16, 0, 0);
            __builtin_amdgcn_global_load_lds(
                (const __attribute__((address_space(1))) void*)gb,
                (__attribute__((address_space(3))) void*)((char*)Bs + (w * 32 + q * 8) * 128),
                16, 0, 0);
        }
        __syncthreads();

        #pragma unroll
        for (int kk = 0; kk < 2; ++kk) {
            int kb = kk * 64 + (lane >> 4) * 16;
            s16x8 af[4], bfr[4];
            #pragma unroll
            for (int mi = 0; mi < 4; ++mi) {
                int r = wr * 64 + mi * 16 + (lane & 15);
                af[mi] = *(const s16x8*)((const char*)As + r * 128 + (kb ^ ((r & 7) << 4)));
            }
            #pragma unroll
            for (int ni = 0; ni < 4; ++ni) {
                int r = wc * 64 + ni * 16 + (lane & 15);
                bfr[ni] = *(const s16x8*)((const char*)Bs + r * 128 + (kb ^ ((r & 7) << 4)));
            }
            #pragma unroll
            for (int mi = 0; mi < 4; ++mi)
                #pragma unroll
                for (int ni = 0; ni < 4; ++ni)
                    acc[mi][ni] = __builtin_amdgcn_mfma_f32_16x16x32_bf16(
                        af[mi], bfr[ni], acc[mi][ni], 0, 0, 0);
        }
    }

    #pragma unroll
    for (int mi = 0; mi < 4; ++mi)
        #pragma unroll
        for (int ni = 0; ni < 4; ++ni) {
            int col = n0 + wc * 64 + ni * 16 + (lane & 15);
            int rb  = m0 + wr * 64 + mi * 16 + (lane >> 4) * 4;
            #pragma unroll
            for (int j = 0; j < 4; ++j)
                C[(size_t)(rb + j) * N + col] = acc[mi][ni][j];
        }
}

// ---------------------------------------------------------------------------
// Split-bf16 MFMA GEMM, 5-way z with per-z K (192,192,192,64,64).
// z: 0=q2 1=k2 2=gbuf (LoRA-b) 3=gk1 4=gk2 (gate-b). N=512 for all.
// ---------------------------------------------------------------------------
__global__ __launch_bounds__(256) void gemm_mfma5(
    const unsigned short* __restrict__ A0, const unsigned short* __restrict__ A1,
    const unsigned short* __restrict__ A2, const unsigned short* __restrict__ A3,
    const unsigned short* __restrict__ A4,
    const unsigned short* __restrict__ B0, const unsigned short* __restrict__ B1,
    const unsigned short* __restrict__ B2, const unsigned short* __restrict__ B3,
    const unsigned short* __restrict__ B4,
    float* __restrict__ C0, float* __restrict__ C1, float* __restrict__ C2,
    float* __restrict__ C3, float* __restrict__ C4, int M, int N)
{
    int z = blockIdx.z;
    const unsigned short* A = (z == 0) ? A0 : (z == 1) ? A1 : (z == 2) ? A2 : (z == 3) ? A3 : A4;
    const unsigned short* B = (z == 0) ? B0 : (z == 1) ? B1 : (z == 2) ? B2 : (z == 3) ? B3 : B4;
    float*                C = (z == 0) ? C0 : (z == 1) ? C1 : (z == 2) ? C2 : (z == 3) ? C3 : C4;
    int K = (z < 3) ? 192 : 64;

    __shared__ __align__(16) unsigned short sm[2 * 128 * 64];
    unsigned short* As = sm;
    unsigned short* Bs = sm + 128 * 64;

    int bxi = blockIdx.x, byi = blockIdx.y;
    {
        int gx = gridDim.x, nwg = gx * gridDim.y;
        if ((nwg & 7) == 0) {
            int b = byi * gx + bxi;
            int s = (b & 7) * (nwg >> 3) + (b >> 3);
            bxi = s % gx; byi = s / gx;
        }
    }

    int tid  = threadIdx.x;
    int lane = tid & 63;
    int w    = tid >> 6;
    int m0 = byi * 128, n0 = bxi * 128;
    int wr = w >> 1, wc = w & 1;

    f32x4 acc[4][4];
    #pragma unroll
    for (int i = 0; i < 4; ++i)
        #pragma unroll
        for (int j = 0; j < 4; ++j)
            acc[i][j] = (f32x4){0.f, 0.f, 0.f, 0.f};

    const int srow = (lane >> 3);
    const int scb  = ((lane & 7) * 16) ^ (srow << 4);

    for (int kt = 0; kt < K; kt += 64) {
        __syncthreads();
        #pragma unroll
        for (int q = 0; q < 4; ++q) {
            int r = w * 32 + q * 8 + srow;
            const char* ga = (const char*)A + ((size_t)(m0 + r) * K + kt) * 2 + scb;
            const char* gb = (const char*)B + ((size_t)(n0 + r) * K + kt) * 2 + scb;
            __builtin_amdgcn_global_load_lds(
                (const __attribute__((address_space(1))) void*)ga,
                (__attribute__((address_space(3))) void*)((char*)As + (w * 32 + q * 8) * 128),
                16, 0, 0);
            __builtin_amdgcn_global_load_lds(
                (const __attribute__((address_space(1))) void*)gb,
                (__attribute__((address_space(3))) void*)((char*)Bs + (w * 32 + q * 8) * 128),
                16, 0, 0);
        }
        __syncthreads();

        #pragma unroll
        for (int kk = 0; kk < 2; ++kk) {
            int kb = kk * 64 + (lane >> 4) * 16;
            s16x8 af[4], bfr[4];
            #pragma unroll
            for (int mi = 0; mi < 4; ++mi) {
                int r = wr * 64 + mi * 16 + (lane & 15);
                af[mi] = *(const s16x8*)((const char*)As + r * 128 + (kb ^ ((r & 7) << 4)));
            }
            #pragma unroll
            for (int ni = 0; ni < 4; ++ni) {
                int r = wc * 64 + ni * 16 + (lane & 15);
                bfr[ni] = *(const s16x8*)((const char*)Bs + r * 128 + (kb ^ ((r & 7) << 4)));
            }
            #pragma unroll
            for (int mi = 0; mi < 4; ++mi)
                #pragma unroll
                for (int ni = 0; ni < 4; ++ni)
                    acc[mi][ni] = __builtin_amdgcn_mfma_f32_16x16x32_bf16(
                        af[mi], bfr[ni], acc[mi][ni], 0, 0, 0);
        }
    }

    #pragma unroll
    for (int mi = 0; mi < 4; ++mi)
        #pragma unroll
        for (int ni = 0; ni < 4; ++ni) {
            int col = n0 + wc * 64 + ni * 16 + (lane & 15);
            int rb  = m0 + wr * 64 + mi * 16 + (lane >> 4) * 4;
            #pragma unroll
            for (int j = 0; j < 4; ++j)
                C[(size_t)(rb + j) * N + col] = acc[mi][ni][j];
        }
}

// ---------------------------------------------------------------------------
// Unpack tcat [LL][256]: LoRA-a -> split-bf16 [LL][192]; gate-a -> split-bf16
// [LL][64] (48 used + 16 zero pad); router -> elog f32.
// ---------------------------------------------------------------------------
__global__ void unpack_cat(const float* __restrict__ tcat,
                           unsigned short* __restrict__ tqab2,
                           unsigned short* __restrict__ tkab2,
                           unsigned short* __restrict__ tgab2,
                           unsigned short* __restrict__ tg1s2,
                           unsigned short* __restrict__ tg2s2,
                           float* __restrict__ elog)
{
    int m = blockIdx.x;
    int c = threadIdx.x;
    float vx = tcat[(size_t)m * 256 + c];
    if (c < 192) {
        unsigned short h, l;
        split2(vx, h, l);
        unsigned short* dst = (c < 64) ? tqab2 : (c < 128) ? tkab2 : tgab2;
        int cc = c & 63;
        size_t ro = (size_t)m * 192;
        dst[ro + cc]       = h;
        dst[ro + 64 + cc]  = l;
        dst[ro + 128 + cc] = h;
    } else if (c < 224) {
        unsigned short h, l;
        split2(vx, h, l);
        unsigned short* dst = (c < 208) ? tg1s2 : tg2s2;
        int cc = (c - 192) & 15;
        size_t ro = (size_t)m * 64;
        dst[ro + cc]      = h;
        dst[ro + 16 + cc] = l;
        dst[ro + 32 + cc] = h;
        dst[ro + 48 + cc] = 0;
    } else if (c < 228) {
        elog[(size_t)m * 4 + (c - 224)] = vx;
    }
}

// ---------------------------------------------------------------------------
__device__ inline float logsig(float x) {
    return fminf(x, 0.f) - log1pf(expf(-fabsf(x)));
}

__global__ void elementwise_pre(float* __restrict__ q1, float* __restrict__ q2,
                                float* __restrict__ k2, float* __restrict__ gk1,
                                float* __restrict__ gk2,
                                const float* __restrict__ bg1, const float* __restrict__ bg2,
                                const float* __restrict__ elog, float* __restrict__ rw)
{
    int l = blockIdx.x;
    int tid = threadIdx.x;
    int w = tid >> 6, lane = tid & 63;
    int idx = l * KD_ + (w << 6) + lane;

    q1[idx] *= 0.125f;
    q2[idx] *= 0.125f;

    float kv = k2[idx];
    float m = kv;
    for (int s = 32; s >= 1; s >>= 1) m = fmaxf(m, __shfl_xor(m, s, 64));
    float ev = expf(kv - m);
    float ssum = ev;
    for (int s = 32; s >= 1; s >>= 1) ssum += __shfl_xor(ssum, s, 64);
    k2[idx] = ev / ssum;

    int bi = (w << 6) + lane;
    gk1[idx] = logsig(gk1[idx] + bg1[bi]) * (1.f / 16.f);
    gk2[idx] = logsig(gk2[idx] + bg2[bi]) * (1.f / 16.f);

    if (tid == 0) {
        float xs[4];
        float mm = -1e30f;
        for (int j = 0; j < 4; ++j) { xs[j] = elog[l * 4 + j]; mm = fmaxf(mm, xs[j]); }
        float s4 = 0.f;
        for (int j = 0; j < 4; ++j) { xs[j] = expf(xs[j] - mm); s4 += xs[j]; }
        for (int j = 0; j < 4; ++j) xs[j] /= s4;
        int arg = 0; float best = xs[0];
        for (int j = 1; j < 4; ++j) if (xs[j] > best) { best = xs[j]; arg = j; }
        for (int j = 0; j < 4; ++j) rw[l * 4 + j] = (j == arg) ? xs[j] : 0.f;
    }
}

// ---------------------------------------------------------------------------
// Phase 1: chunk_kv + decay via split-bf16 MFMA. XCD-chunked swizzle over
// (p,h,c) so blocks sharing a chunk's rows land on the same XCD.
// ---------------------------------------------------------------------------
__global__ void gla_kv(const float* __restrict__ k1, const float* __restrict__ k2,
                       const float* __restrict__ gk1, const float* __restrict__ gk2,
                       const float* __restrict__ v, const float* __restrict__ rw,
                       float* __restrict__ kv_all, float* __restrict__ decay_all)
{
    int flat = (blockIdx.z * 8 + blockIdx.y) * 5 + blockIdx.x;
    int sfl = (flat & 7) * 320 + (flat >> 3);
    int p = sfl % 5, h = (sfl / 5) & 7, c = sfl / 40;

    const float* kp = (p == 0) ? k1 : k2;
    const float* gp = (p == 0) ? gk1 : gk2;

    __shared__ __align__(16) unsigned short kgT[64][200];  // [d][hi|lo|hi along t]
    __shared__ __align__(16) unsigned short vT[64][200];   // [e][hi|hi|lo along t]
    __shared__ float glast[64];
    __shared__ float wrow[64];
    __shared__ float segsum[4][64];

    int tid = threadIdx.x;
    int lane = tid & 63, w = tid >> 6;
    int d = lane, seg = w;

    float gkv[16], kvv[16], vv_[16];
    #pragma unroll
    for (int i = 0; i < 16; ++i) {
        size_t base = (size_t)(c * 64 + seg * 16 + i) * KD_ + (h << 6) + d;
        gkv[i] = gp[base];
        kvv[i] = kp[base];
        vv_[i] = v[base];
    }
    if (tid < 64) {
        int lg = c * 64 + tid;
        wrow[tid] = (p == 0) ? 1.f : rw[lg * 4 + (p - 1)];
    }
    __syncthreads();

    {
        float s = 0.f;
        #pragma unroll
        for (int i = 0; i < 16; ++i) {
            int t = seg * 16 + i;
            float xg = gkv[i];
            if (p > 0 && !(wrow[t] > 0.f)) xg = 0.f;
            s += xg;
            gkv[i] = s;
        }
        segsum[seg][d] = s;
    }
    __syncthreads();
    {
        float off = 0.f, tot = 0.f;
        #pragma unroll
        for (int ss = 0; ss < 4; ++ss) {
            float x = segsum[ss][d];
            tot += x;
            if (ss < seg) off += x;
        }
        if (seg == 0) glast[d] = tot;
        #pragma unroll
        for (int i = 0; i < 16; ++i) {
            int t = seg * 16 + i;
            float g = off + gkv[i];
            float kgval = kvv[i] * wrow[t] * expf(-g);
            unsigned short hh, ll;
            split2(kgval, hh, ll);
            kgT[d][t] = hh; kgT[d][64 + t] = ll; kgT[d][128 + t] = hh;
            split2(vv_[i], hh, ll);
            vT[d][t] = hh; vT[d][64 + t] = hh; vT[d][128 + t] = ll;
        }
    }
    __syncthreads();

    size_t base = (size_t)((c * 8 + h) * 5 + p) * 4096;
    int ar = 16 * w + (lane & 15);
    int kb = (lane >> 4) * 16;
    float dec_[4];
    #pragma unroll
    for (int j = 0; j < 4; ++j) dec_[j] = expf(glast[16 * w + (lane >> 4) * 4 + j]);

    #pragma unroll
    for (int ni = 0; ni < 4; ++ni) {
        f32x4 acc = (f32x4){0.f, 0.f, 0.f, 0.f};
        int br = 16 * ni + (lane & 15);
        #pragma unroll
        for (int kk = 0; kk < 6; ++kk) {
            s16x8 af = *(const s16x8*)((const char*)&kgT[ar][0] + kk * 64 + kb);
            s16x8 bf = *(const s16x8*)((const char*)&vT[br][0] + kk * 64 + kb);
            acc = __builtin_amdgcn_mfma_f32_16x16x32_bf16(af, bf, acc, 0, 0, 0);
        }
        #pragma unroll
        for (int j = 0; j < 4; ++j) {
            int dd = 16 * w + (lane >> 4) * 4 + j;
            kv_all[base + dd * 64 + 16 * ni + (lane & 15)] = acc[j] * dec_[j];
        }
    }
    if (tid < 64) decay_all[(size_t)((c * 8 + h) * 5 + p) * 64 + tid] = expf(glast[tid]);
}

// ---------------------------------------------------------------------------
// Inter-chunk state scan: elementwise, in place over kv_all (f32).
// ---------------------------------------------------------------------------
__global__ void gla_state_scan(float* __restrict__ kv, const float* __restrict__ decay)
{
    int gid = blockIdx.x * 256 + threadIdx.x;
    int sub = gid >> 6;
    const size_t stride = 8 * 5 * 64 * 64;
    float S = 0.f;
    float kvv = kv[gid];
    for (int c = 0; c < 64; ++c) {
        size_t o = (size_t)c * stride + gid;
        float nxt = (c < 63) ? kv[o + stride] : 0.f;
        float dec = decay[c * 2560 + sub];
        kv[o] = S;
        S = fmaf(dec, S, kvv);
        kvv = nxt;
    }
}

// ---------------------------------------------------------------------------
// Phase 2: per-pass output via bf16 MFMA. XCD-chunked swizzle over (p,h,c).
// ---------------------------------------------------------------------------
__global__ void gla_o(const float* __restrict__ q1, const float* __restrict__ q2,
                      const float* __restrict__ k1, const float* __restrict__ k2,
                      const float* __restrict__ gk1, const float* __restrict__ gk2,
                      const float* __restrict__ v, const float* __restrict__ rw,
                      const float* __restrict__ Spre,
                      float* __restrict__ o_dense, float* __restrict__ o_sparse)
{
    int flat = (blockIdx.z * 8 + blockIdx.y) * 5 + blockIdx.x;
    int sfl = (flat & 7) * 320 + (flat >> 3);
    int p = sfl % 5, h = (sfl / 5) & 7, c = sfl / 40;

    const float* qp = (p == 0) ? q1 : q2;
    const float* kp = (p == 0) ? k1 : k2;
    const float* gp = (p == 0) ? gk1 : gk2;

    __shared__ __align__(16) unsigned short qg_bf[64][72];  // [t][d]
    __shared__ __align__(16) unsigned short kg_bf[64][72];  // [s][d]
    __shared__ __align__(16) unsigned short A_bf[64][72];   // [t][s]
    __shared__ __align__(16) unsigned short vT_bf[64][72];  // [e][s]
    __shared__ __align__(16) unsigned short ST_bf[64][72];  // [e][d]
    __shared__ float wrow[64];
    __shared__ float segsum[4][64];

    int tid = threadIdx.x;
    int lane = tid & 63, w = tid >> 6;
    int d = lane, seg = w;

    {
        float gkv[16], qv[16], kvv[16];
        #pragma unroll
        for (int i = 0; i < 16; ++i) {
            size_t base = (size_t)(c * 64 + seg * 16 + i) * KD_ + (h << 6) + d;
            gkv[i] = gp[base];
            qv[i]  = qp[base];
            kvv[i] = kp[base];
        }
        if (tid < 64) {
            int lg = c * 64 + tid;
            wrow[tid] = (p == 0) ? 1.f : rw[lg * 4 + (p - 1)];
        }
        __syncthreads();

        float s = 0.f;
        #pragma unroll
        for (int i = 0; i < 16; ++i) {
            int t = seg * 16 + i;
            float xg = gkv[i];
            if (p > 0 && !(wrow[t] > 0.f)) xg = 0.f;
            s += xg;
            gkv[i] = s;
        }
        segsum[seg][d] = s;
        __syncthreads();

        float off = 0.f;
        for (int ss = 0; ss < seg; ++ss) off += segsum[ss][d];
        #pragma unroll
        for (int i = 0; i < 16; ++i) {
            int t = seg * 16 + i;
            float g = off + gkv[i];
            float wv = wrow[t];
            qg_bf[t][d] = f2bf(qv[i] * wv * expf(g));
            kg_bf[t][d] = f2bf(kvv[i] * wv * expf(-g));
        }
    }

    {
        size_t sbase = (size_t)((c * 8 + h) * 5 + p) * 4096;
        float Sv[16], vv_[16];
        #pragma unroll
        for (int i = 0; i < 16; ++i) Sv[i] = Spre[sbase + tid + (i << 8)];
        #pragma unroll
        for (int i = 0; i < 16; ++i)
            vv_[i] = v[(size_t)(c * 64 + seg * 16 + i) * KD_ + (h << 6) + d];
        #pragma unroll
        for (int i = 0; i < 16; ++i) ST_bf[d][4 * i + seg] = f2bf(Sv[i]);
        #pragma unroll
        for (int i = 0; i < 16; ++i) vT_bf[d][seg * 16 + i] = f2bf(vv_[i]);
    }
    __syncthreads();

    int am = 16 * w + (lane & 15);
    int kb = (lane >> 4) * 16;

    #pragma unroll
    for (int ni = 0; ni < 4; ++ni) {
        f32x4 acc = (f32x4){0.f, 0.f, 0.f, 0.f};
        if (ni <= w) {
            int br = 16 * ni + (lane & 15);
            #pragma unroll
            for (int kk = 0; kk < 2; ++kk) {
                s16x8 af = *(const s16x8*)((const char*)&qg_bf[am][0] + kk * 64 + kb);
                s16x8 bf = *(const s16x8*)((const char*)&kg_bf[br][0] + kk * 64 + kb);
                acc = __builtin_amdgcn_mfma_f32_16x16x32_bf16(af, bf, acc, 0, 0, 0);
            }
        }
        #pragma unroll
        for (int j = 0; j < 4; ++j) {
            int t = 16 * w + (lane >> 4) * 4 + j;
            int s = 16 * ni + (lane & 15);
            A_bf[t][s] = (s <= t) ? f2bf(acc[j]) : (unsigned short)0;
        }
    }
    __syncthreads();

    #pragma unroll
    for (int ni = 0; ni < 4; ++ni) {
        f32x4 acc = (f32x4){0.f, 0.f, 0.f, 0.f};
        int br = 16 * ni + (lane & 15);
        #pragma unroll
        for (int kk = 0; kk < 2; ++kk) {
            s16x8 af = *(const s16x8*)((const char*)&qg_bf[am][0] + kk * 64 + kb);
            s16x8 bf = *(const s16x8*)((const char*)&ST_bf[br][0] + kk * 64 + kb);
            acc = __builtin_amdgcn_mfma_f32_16x16x32_bf16(af, bf, acc, 0, 0, 0);
        }
        #pragma unroll
        for (int kk = 0; kk < 2; ++kk) {
            s16x8 af = *(const s16x8*)((const char*)&A_bf[am][0] + kk * 64 + kb);
            s16x8 bf = *(const s16x8*)((const char*)&vT_bf[br][0] + kk * 64 + kb);
            acc = __builtin_amdgcn_mfma_f32_16x16x32_bf16(af, bf, acc, 0, 0, 0);
        }
        #pragma unroll
        for (int j = 0; j < 4; ++j) {
            int t = 16 * w + (lane >> 4) * 4 + j;
            int e = 16 * ni + (lane & 15);
            size_t idx = (size_t)(c * 64 + t) * KD_ + (h << 6) + e;
            if (p == 0)                 o_dense[idx]  = acc[j];
            else if (wrow[t] > 0.f)     o_sparse[idx] = acc[j];
        }
    }
}

// ---------------------------------------------------------------------------
// Post: sum dense+sparse, RMS-norm, * norm_w, * silu(g); emit split-bf16 A.
// ---------------------------------------------------------------------------
__global__ void postnorm(const float* __restrict__ o_dense, const float* __restrict__ o_sparse,
                         const float* __restrict__ gbuf,
                         const float* __restrict__ norm_w, unsigned short* __restrict__ og2)
{
    int l = blockIdx.x;
    int tid = threadIdx.x;
    int w = tid >> 6, lane = tid & 63;
    int bi = (w << 6) + lane;
    int idx = l * KD_ + bi;
    float o = o_dense[idx] + o_sparse[idx];
    float ss = o * o;
    for (int s = 32; s >= 1; s >>= 1) ss += __shfl_xor(ss, s, 64);
    float r = rsqrtf(ss * (1.f / 64.f) + 1e-5f);
    float val = o * r * norm_w[lane];
    float gv = gbuf[idx];
    val *= gv / (1.f + expf(-gv));
    unsigned short h, lo;
    split2(val, h, lo);
    size_t ro = (size_t)l * (3 * KD_) + bi;
    og2[ro]           = h;
    og2[ro + KD_]     = lo;
    og2[ro + 2 * KD_] = h;
}

// ---------------------------------------------------------------------------
extern "C" void kernel_launch(void* const* d_in, const int* in_sizes, int n_in,
                              void* d_out, int out_size, void* d_ws, size_t ws_size,
                              hipStream_t stream)
{
    const float* x    = (const float*)d_in[0];
    const float* Wq   = (const float*)d_in[1];
    const float* Wk   = (const float*)d_in[2];
    const float* Wv   = (const float*)d_in[3];
    const float* Wqa  = (const float*)d_in[4];
    const float* Wqb  = (const float*)d_in[5];
    const float* Wka  = (const float*)d_in[6];
    const float* Wkb  = (const float*)d_in[7];
    const float* Wg1a = (const float*)d_in[8];
    const float* Wg1b = (const float*)d_in[9];
    const float* bg1  = (const float*)d_in[10];
    const float* Wg2a = (const float*)d_in[11];
    const float* Wg2b = (const float*)d_in[12];
    const float* bg2  = (const float*)d_in[13];
    const float* We   = (const float*)d_in[14];
    const float* Wga  = (const float*)d_in[15];
    const float* Wgb  = (const float*)d_in[16];
    const float* normw= (const float*)d_in[17];
    const float* Wo   = (const float*)d_in[18];

    float* ws = (float*)d_ws;
    const size_t LKD = (size_t)LL * KD_;   // 2M floats
    float* q1   = ws;
    float* k1   = q1 + LKD;
    float* v    = k1 + LKD;
    float* q2   = v  + LKD;
    float* k2   = q2 + LKD;
    float* gk1  = k2 + LKD;
    float* gk2  = gk1 + LKD;
    float* o_dense  = gk2 + LKD;
    float* o_sparse = o_dense + LKD;
    float* gbuf = o_sparse + LKD;
    float* elog = gbuf + LKD;                  // 4096*4
    float* rw   = elog + (size_t)LL * 4;
    float* kv_all    = rw + (size_t)LL * 4;                    // 10.49M f32
    float* decay_all = kv_all + (size_t)64 * 8 * 5 * 64 * 64;  // 163840 f32

    unsigned short* bp = (unsigned short*)(decay_all + 163840);
    unsigned short* WallT2 = bp; bp += (size_t)1792 * 3072;    // [Wq|Wk|Wv|Wcat]
    unsigned short* WoT2   = bp; bp += (size_t)1024 * 1536;
    unsigned short* WqbT2  = bp; bp += (size_t)512 * 192;
    unsigned short* WkbT2  = bp; bp += (size_t)512 * 192;
    unsigned short* WgbT2  = bp; bp += (size_t)512 * 192;
    unsigned short* Wg1bT2 = bp; bp += (size_t)512 * 64;
    unsigned short* Wg2bT2 = bp; bp += (size_t)512 * 64;
    unsigned short* tqab2  = bp; bp += (size_t)LL * 192;
    unsigned short* tkab2  = bp; bp += (size_t)LL * 192;
    unsigned short* tgab2  = bp; bp += (size_t)LL * 192;
    unsigned short* tg1s2  = bp; bp += (size_t)LL * 64;
    unsigned short* tg2s2  = bp; bp += (size_t)LL * 64;
    float* tcat = (float*)bp;                                  // 4096*256 f32

    // time-multiplexed aliases of kv_all (disjoint lifetimes):
    unsigned short* xb2 = (unsigned short*)kv_all;   // [4096][3072]; dead before gla_kv
    unsigned short* og2 = (unsigned short*)kv_all;   // [4096][1536]; live after gla_o

    dim3 blk(256);
    dim3 tblk(32, 8);

    // ---- conversions: x split + ALL weights in one launch ----
    cvt_splitA<<<dim3((LL * 1024 + 255) / 256), blk, 0, stream>>>(x, xb2, LL * 1024, 10);
    hipMemsetAsync(WallT2 + (size_t)1764 * 3072, 0, (size_t)(1792 - 1764) * 3072 * 2, stream);
    cvt_weights_all<<<dim3(32, 32, 15), tblk, 0, stream>>>(
        Wq, Wk, Wv, Wqa, Wka, Wga, Wg1a, Wg2a, We, Wo, Wqb, Wkb, Wgb, Wg1b, Wg2b,
        WallT2, WoT2, WqbT2, WkbT2, WgbT2, Wg1bT2, Wg2bT2);

    // ---- mega GEMM: QKV + LoRA-a + gate-a + router ----
    gemm_qkvcat<<<dim3(14, 32), blk, 0, stream>>>(xb2, WallT2, q1, k1, v, tcat, LL, 3072);
    unpack_cat<<<dim3(LL), blk, 0, stream>>>(tcat, tqab2, tkab2, tgab2, tg1s2, tg2s2, elog);

    // ---- LoRA-b q2,k2,gbuf + gate-b gk1,gk2 (split MFMA, per-z K) ----
    gemm_mfma5<<<dim3(4, 32, 5), blk, 0, stream>>>(
        tqab2, tkab2, tgab2, tg1s2, tg2s2,
        WqbT2, WkbT2, WgbT2, Wg1bT2, Wg2bT2,
        q2, k2, gbuf, gk1, gk2, LL, KD_);

    elementwise_pre<<<LL, 512, 0, stream>>>(q1, q2, k2, gk1, gk2, bg1, bg2, elog, rw);

    // ---- GLA: kv -> scan -> o ----
    gla_kv<<<dim3(5, 8, 64), blk, 0, stream>>>(k1, k2, gk1, gk2, v, rw, kv_all, decay_all);
    gla_state_scan<<<dim3(640), blk, 0, stream>>>(kv_all, decay_all);
    gla_o<<<dim3(5, 8, 64), blk, 0, stream>>>(q1, q2, k1, k2, gk1, gk2, v, rw,
                                              kv_all, o_dense, o_sparse);

    postnorm<<<LL, 512, 0, stream>>>(o_dense, o_sparse, gbuf, normw, og2);

    // ---- output projection (split MFMA, K'=1536) ----
    gemm_mfma<<<dim3(8, 32, 1), blk, 0, stream>>>(og2, og2, og2, WoT2, WoT2, WoT2,
                                                  (float*)d_out, (float*)d_out, (float*)d_out,
                                                  LL, 1024, 1536);
}